// Round 8
// baseline (446.644 us; speedup 1.0000x reference)
//
#include <hip/hip_runtime.h>
#include <stdint.h>
#include <stddef.h>

// ---------------------------------------------------------------------------
// EncoderImageAggr: bf16-MFMA pipeline for MI355X (gfx950)
// B=256 L=64 IMG_DIM=2048 D=1024 H=8 DH=128. All GEMMs are C = A @ W^T.
// Round 8: fc2/out/ff1/ff2 moved to a 128x128 4-wave 16KB-LDS kernel
// (~3 blocks/CU): 528 live blocks stream across all 256 CUs instead of
// 132 x 1-block/CU (half machine idle). qkv keeps gemm256 (2 full passes).
// ---------------------------------------------------------------------------

typedef short s16x8 __attribute__((ext_vector_type(8)));
typedef short s16x4 __attribute__((ext_vector_type(4)));
typedef float f32x4 __attribute__((ext_vector_type(4)));

#define LN_EPSF 1e-5f
#define BN_EPSF 1e-5f

__device__ __forceinline__ short f2bf(float f) {
  union { float f; uint32_t u; } x; x.f = f;
  uint32_t r = x.u + 0x7fffu + ((x.u >> 16) & 1u);   // RNE
  return (short)(r >> 16);
}
__device__ __forceinline__ float bf2f(short s) {
  union { uint32_t u; float f; } x; x.u = ((uint32_t)(uint16_t)s) << 16;
  return x.f;
}

typedef const __attribute__((address_space(1))) short glb_s16_t;
typedef __attribute__((address_space(3))) short lds_s16_t;

__device__ __forceinline__ void stage16(const short* g, short* l) {
  __builtin_amdgcn_global_load_lds((glb_s16_t*)g, (lds_s16_t*)l, 16, 0, 0);
}

// involution swizzle for [256][32]-bf16 (64B-row) LDS half-slots (round-3,
// measured 0 bank conflicts)
__device__ __forceinline__ int swz(int off) {
  return off ^ (((off >> 7) & 3) << 4);
}

enum { EPI_PLAIN = 0, EPI_FF1 = 3, EPI_RES = 4 };

// ---------------------------------------------------------------------------
// prefix-sum of lens -> cum (exclusive), hdr = {Mc, Mc_pad}; zero tokmap
// ---------------------------------------------------------------------------
__global__ __launch_bounds__(256)
void prefix_kernel(const int* __restrict__ lens, int* __restrict__ cum,
                   int* __restrict__ hdr, int* __restrict__ tokmap) {
  __shared__ int wsum[4];
  const int tid = threadIdx.x, lane = tid & 63, wave = tid >> 6;
  const int mylen = lens[tid];
  int v = mylen;
#pragma unroll
  for (int o = 1; o < 64; o <<= 1) {
    int t = __shfl_up(v, o);
    if (lane >= o) v += t;
  }
  if (lane == 63) wsum[wave] = v;
  __syncthreads();
  int add = 0;
#pragma unroll
  for (int w2 = 0; w2 < 4; ++w2) if (w2 < wave) add += wsum[w2];
  const int incl = v + add;
  cum[tid] = incl - mylen;
  if (tid == 255) {
    hdr[0] = incl;                       // Mc
    hdr[1] = (incl + 255) & ~255;        // Mc_pad (multiple of 256)
  }
  for (int i = tid; i < 16384; i += 256) tokmap[i] = 0;
}

__global__ __launch_bounds__(64)
void tokmap_kernel(const int* __restrict__ lens, const int* __restrict__ cum,
                   int* __restrict__ tokmap) {
  const int b = blockIdx.x, l = threadIdx.x;
  if (l < lens[b]) tokmap[cum[b] + l] = b * 64 + l;
}

// ---------------------------------------------------------------------------
// gathered fp32 -> bf16 convert of valid image rows (compacted)
// ---------------------------------------------------------------------------
__global__ __launch_bounds__(256)
void cvt_gather_kernel(const float* __restrict__ img,
                       const int* __restrict__ tokmap,
                       const int* __restrict__ hdr, short* __restrict__ out) {
  const int n4 = hdr[1] << 9;                    // Mc_pad * 512 float4s
  const int stride = gridDim.x * 256;
  for (int i = blockIdx.x * 256 + threadIdx.x; i < n4; i += stride) {
    const int row = i >> 9, col = i & 511;
    float4 v = ((const float4*)img)[(size_t)tokmap[row] * 512 + col];
    s16x4 h; h[0] = f2bf(v.x); h[1] = f2bf(v.y); h[2] = f2bf(v.z); h[3] = f2bf(v.w);
    ((s16x4*)out)[i] = h;
  }
}

struct CvtArgs { const float* src[6]; short* dst[6]; int n4[6]; };

__global__ __launch_bounds__(256)
void cvt6_kernel(CvtArgs a) {
#pragma unroll
  for (int s = 0; s < 6; ++s) {
    const int n = a.n4[s];
    const float4* in = (const float4*)a.src[s];
    s16x4* outp = (s16x4*)a.dst[s];
    for (int i = blockIdx.x * 256 + threadIdx.x; i < n; i += gridDim.x * 256) {
      float4 v = in[i];
      s16x4 h; h[0] = f2bf(v.x); h[1] = f2bf(v.y); h[2] = f2bf(v.z); h[3] = f2bf(v.w);
      outp[i] = h;
    }
  }
}

// ---------------------------------------------------------------------------
// 256x256 pipelined GEMM (round-3 schedule) — used for qkv only.
// Live count nwork = (Mc_pad/256)*gx; bijective chunked XCD swizzle.
// ---------------------------------------------------------------------------
template<int EPI>
__global__ __launch_bounds__(512, 2)
void gemm256(const short* __restrict__ A, const short* __restrict__ Bw,
             const float* __restrict__ bias, const short* __restrict__ res16,
             const int* __restrict__ hdr,
             float* __restrict__ out32, short* __restrict__ out16,
             int M, int N, int K) {
  extern __shared__ char smem[];                 // 131072 B: A slots, then B
  (void)M;
  const int tid  = threadIdx.x;
  const int lane = tid & 63;
  const int w    = tid >> 6;
  const int wr   = w >> 2;                       // 0..1
  const int wc   = w & 3;                        // 0..3
  const int lrow = lane & 15;
  const int cg   = lane >> 4;                    // 0..3
  const int NH   = K >> 5;                       // half-steps (K-slices of 32)
  const int gx   = gridDim.x;

  const int p = blockIdx.y * gx + blockIdx.x;
  const int nwork = (hdr[1] >> 8) * gx;          // live blocks
  if (p >= nwork) return;
  const int xcd = p & 7, off = p >> 3;
  const int q = nwork >> 3, r = nwork & 7;
  const int wg = (xcd < r ? xcd * (q + 1) : r * (q + 1) + (xcd - r) * q) + off;
  const int m0 = (wg / gx) * 256;
  const int n0 = (wg % gx) * 256;

  const int ldb = K * 2;
  size_t gA[2], gB[2];
#pragma unroll
  for (int j = 0; j < 2; ++j) {
    const int pp = tid * 16 + j * 8192;
    const int l = swz(pp);
    const int row = l >> 6, colb = l & 63;
    gA[j] = (size_t)(m0 + row) * ldb + colb;
    gB[j] = (size_t)(n0 + row) * ldb + colb;
  }
  const char* Ab = (const char*)A;
  const char* Bb = (const char*)Bw;
  char* ldsA = smem;
  char* ldsB = smem + 65536;
  const int wofs = w * 1024;

  auto stageApart = [&](int i) {
    const int rg = ((i & 3) << 14) + wofs;
    const int ko = i * 64;
    stage16((const short*)(Ab + gA[0] + ko), (short*)(ldsA + rg));
    stage16((const short*)(Ab + gA[1] + ko), (short*)(ldsA + rg + 8192));
  };
  auto stageBpart = [&](int i) {
    const int rg = ((i & 3) << 14) + wofs;
    const int ko = i * 64;
    stage16((const short*)(Bb + gB[0] + ko), (short*)(ldsB + rg));
    stage16((const short*)(Bb + gB[1] + ko), (short*)(ldsB + rg + 8192));
  };

  int offA[8], offB[4];
#pragma unroll
  for (int mf = 0; mf < 8; ++mf)
    offA[mf] = swz((wr * 128 + mf * 16 + lrow) * 64 + cg * 16);
#pragma unroll
  for (int nf = 0; nf < 4; ++nf)
    offB[nf] = swz((wc * 64 + nf * 16 + lrow) * 64 + cg * 16);

  f32x4 acc[8][4] = {};

  stageApart(0); stageBpart(0);
  stageApart(1); stageBpart(1);
  stageApart(2); stageBpart(2);
  asm volatile("s_waitcnt vmcnt(8)" ::: "memory");
  __builtin_amdgcn_s_barrier();
  __builtin_amdgcn_sched_barrier(0);
  s16x8 af_cur[4], bf_cur[4], af_nxt[4], bf_nxt[4], af2[4];
#pragma unroll
  for (int m = 0; m < 4; ++m) af_cur[m] = *(const s16x8*)(ldsA + offA[m]);
#pragma unroll
  for (int n = 0; n < 4; ++n) bf_cur[n] = *(const s16x8*)(ldsB + offB[n]);

  for (int i = 0; i < NH - 1; ++i) {
    const int si  = i & 3;
    const int si1 = (i + 1) & 3;
    const char* pA  = ldsA + (si  << 14);
    const char* pA1 = ldsA + (si1 << 14);
    const char* pB1 = ldsB + (si1 << 14);

    if (i + 2 < NH) { asm volatile("s_waitcnt vmcnt(4)" ::: "memory"); }
    else            { asm volatile("s_waitcnt vmcnt(0)" ::: "memory"); }
    __builtin_amdgcn_s_barrier();
    __builtin_amdgcn_sched_barrier(0);

#pragma unroll
    for (int m = 0; m < 4; ++m) af_nxt[m] = *(const s16x8*)(pA + offA[m + 4]);
#pragma unroll
    for (int n = 0; n < 4; ++n) bf_nxt[n] = *(const s16x8*)(pB1 + offB[n]);
    if (i + 3 < NH) stageApart(i + 3);
    asm volatile("s_waitcnt lgkmcnt(8)" ::: "memory");
    __builtin_amdgcn_sched_barrier(0);
    __builtin_amdgcn_s_setprio(1);
#pragma unroll
    for (int m = 0; m < 4; ++m)
#pragma unroll
      for (int n = 0; n < 4; ++n)
        acc[m][n] = __builtin_amdgcn_mfma_f32_16x16x32_bf16(af_cur[m], bf_cur[n], acc[m][n], 0, 0, 0);
    __builtin_amdgcn_s_setprio(0);

#pragma unroll
    for (int m = 0; m < 4; ++m) af2[m] = *(const s16x8*)(pA1 + offA[m]);
    if (i + 3 < NH) stageBpart(i + 3);
    asm volatile("s_waitcnt lgkmcnt(4)" ::: "memory");
    __builtin_amdgcn_sched_barrier(0);
    __builtin_amdgcn_s_setprio(1);
#pragma unroll
    for (int m = 0; m < 4; ++m)
#pragma unroll
      for (int n = 0; n < 4; ++n)
        acc[m + 4][n] = __builtin_amdgcn_mfma_f32_16x16x32_bf16(af_nxt[m], bf_cur[n], acc[m + 4][n], 0, 0, 0);
    __builtin_amdgcn_s_setprio(0);

#pragma unroll
    for (int m = 0; m < 4; ++m) af_cur[m] = af2[m];
#pragma unroll
    for (int n = 0; n < 4; ++n) bf_cur[n] = bf_nxt[n];
  }

  {
    const char* pA = ldsA + (((NH - 1) & 3) << 14);
    asm volatile("s_waitcnt vmcnt(0)" ::: "memory");
    __builtin_amdgcn_s_barrier();
    __builtin_amdgcn_sched_barrier(0);
#pragma unroll
    for (int m = 0; m < 4; ++m) af_nxt[m] = *(const s16x8*)(pA + offA[m + 4]);
    asm volatile("s_waitcnt lgkmcnt(4)" ::: "memory");
    __builtin_amdgcn_sched_barrier(0);
    __builtin_amdgcn_s_setprio(1);
#pragma unroll
    for (int m = 0; m < 4; ++m)
#pragma unroll
      for (int n = 0; n < 4; ++n)
        acc[m][n] = __builtin_amdgcn_mfma_f32_16x16x32_bf16(af_cur[m], bf_cur[n], acc[m][n], 0, 0, 0);
    __builtin_amdgcn_s_setprio(0);
    asm volatile("s_waitcnt lgkmcnt(0)" ::: "memory");
    __builtin_amdgcn_sched_barrier(0);
    __builtin_amdgcn_s_setprio(1);
#pragma unroll
    for (int m = 0; m < 4; ++m)
#pragma unroll
      for (int n = 0; n < 4; ++n)
        acc[m + 4][n] = __builtin_amdgcn_mfma_f32_16x16x32_bf16(af_nxt[m], bf_cur[n], acc[m + 4][n], 0, 0, 0);
    __builtin_amdgcn_s_setprio(0);
  }

  const int ecol0 = n0 + wc * 64 + lrow;
  float bz[4];
#pragma unroll
  for (int nf = 0; nf < 4; ++nf) bz[nf] = bias[ecol0 + nf * 16];
  const int erow0 = m0 + wr * 128 + (cg << 2);

#pragma unroll
  for (int mf = 0; mf < 8; ++mf) {
#pragma unroll
    for (int nf = 0; nf < 4; ++nf) {
#pragma unroll
      for (int r2 = 0; r2 < 4; ++r2) {
        const int row = erow0 + mf * 16 + r2;
        const size_t idx = (size_t)row * N + (ecol0 + nf * 16);
        const float v = acc[mf][nf][r2] + bz[nf];
        if constexpr (EPI == EPI_PLAIN) {
          out16[idx] = f2bf(v);
        } else if constexpr (EPI == EPI_FF1) {
          out16[idx] = f2bf(fmaxf(v, 0.f));
        } else {
          out32[idx] = v + bf2f(res16[idx]);
        }
      }
    }
  }
}

// ---------------------------------------------------------------------------
// 128x128 4-wave 16KB-LDS GEMM (m97 2-barrier pattern; ~3 blocks/CU) with
// fused epilogues — used for fc2/out/ff1/ff2. High occupancy streams the
// 528 live blocks across all CUs with cross-block stall overlap.
// ---------------------------------------------------------------------------
template<int EPI>
__global__ __launch_bounds__(256)
void gemm128(const short* __restrict__ A, const short* __restrict__ Bw,
             const float* __restrict__ bias, const short* __restrict__ res16,
             const int* __restrict__ hdr,
             float* __restrict__ out32, short* __restrict__ out16,
             int N, int K) {
  __shared__ short As[128 * 32];
  __shared__ short Bs[128 * 32];
  const int m0 = blockIdx.y * 128;
  if (m0 >= hdr[1]) return;
  const int tid  = threadIdx.x;
  const int lane = tid & 63;
  const int wave = tid >> 6;
  const int n0 = blockIdx.x * 128;
  const int wm = (wave >> 1) * 64;
  const int wn = (wave & 1) * 64;
  const int lrow = lane & 15;
  const int lk8  = (lane >> 4) * 8;

  f32x4 acc[4][4] = {};

  const int srow = wave * 16 + (lane >> 2);
  const int scol = (lane & 3) * 8;
  const short* gA = A  + (size_t)(m0 + srow) * K + scol;
  const short* gB = Bw + (size_t)(n0 + srow) * K + scol;
  short* lA = &As[(wave * 16) * 32];
  short* lB = &Bs[(wave * 16) * 32];
  const size_t half = (size_t)64 * K;

  for (int k0 = 0; k0 < K; k0 += 32) {
    stage16(gA + k0,        lA);
    stage16(gA + half + k0, lA + 64 * 32);
    stage16(gB + k0,        lB);
    stage16(gB + half + k0, lB + 64 * 32);
    __syncthreads();
    s16x8 af[4], bfr[4];
#pragma unroll
    for (int m = 0; m < 4; ++m)
      af[m] = *(const s16x8*)&As[(wm + m * 16 + lrow) * 32 + lk8];
#pragma unroll
    for (int n = 0; n < 4; ++n)
      bfr[n] = *(const s16x8*)&Bs[(wn + n * 16 + lrow) * 32 + lk8];
#pragma unroll
    for (int m = 0; m < 4; ++m)
#pragma unroll
      for (int n = 0; n < 4; ++n)
        acc[m][n] = __builtin_amdgcn_mfma_f32_16x16x32_bf16(af[m], bfr[n], acc[m][n], 0, 0, 0);
    __syncthreads();
  }

  const int erow = m0 + wm + ((lane >> 4) << 2);
  const int ecol = n0 + wn + lrow;
  float bz[4];
#pragma unroll
  for (int n = 0; n < 4; ++n) bz[n] = bias[ecol + n * 16];
#pragma unroll
  for (int m = 0; m < 4; ++m)
#pragma unroll
    for (int n = 0; n < 4; ++n)
#pragma unroll
      for (int r = 0; r < 4; ++r) {
        const size_t idx = (size_t)(erow + m * 16 + r) * N + (ecol + n * 16);
        const float v = acc[m][n][r] + bz[n];
        if constexpr (EPI == EPI_PLAIN) {
          out16[idx] = f2bf(v);
        } else if constexpr (EPI == EPI_FF1) {
          out16[idx] = f2bf(fmaxf(v, 0.f));
        } else {
          out32[idx] = v + bf2f(res16[idx]);
        }
      }
}

// ---------------------------------------------------------------------------
// 128x128 GEMM for fc1 (fused BN+ReLU epilogue), with compaction early-exit
// ---------------------------------------------------------------------------
__global__ __launch_bounds__(256)
void gemm_bt_h1(const short* __restrict__ A, const short* __restrict__ Bw,
                const float* __restrict__ bias,
                const float* __restrict__ bn_g, const float* __restrict__ bn_b,
                const float* __restrict__ bn_m, const float* __restrict__ bn_v,
                const int* __restrict__ hdr,
                short* __restrict__ out16, int M, int N, int K) {
  __shared__ short As[128 * 32];
  __shared__ short Bs[128 * 32];
  (void)M;
  const int m0 = blockIdx.y * 128;
  if (m0 >= hdr[1]) return;
  const int tid  = threadIdx.x;
  const int lane = tid & 63;
  const int wave = tid >> 6;
  const int n0 = blockIdx.x * 128;
  const int wm = (wave >> 1) * 64;
  const int wn = (wave & 1) * 64;
  const int lrow = lane & 15;
  const int lk8  = (lane >> 4) * 8;

  f32x4 acc[4][4] = {};

  const int srow = wave * 16 + (lane >> 2);
  const int scol = (lane & 3) * 8;
  const short* gA = A  + (size_t)(m0 + srow) * K + scol;
  const short* gB = Bw + (size_t)(n0 + srow) * K + scol;
  short* lA = &As[(wave * 16) * 32];
  short* lB = &Bs[(wave * 16) * 32];
  const size_t half = (size_t)64 * K;

  for (int k0 = 0; k0 < K; k0 += 32) {
    stage16(gA + k0,        lA);
    stage16(gA + half + k0, lA + 64 * 32);
    stage16(gB + k0,        lB);
    stage16(gB + half + k0, lB + 64 * 32);
    __syncthreads();
    s16x8 af[4], bfr[4];
#pragma unroll
    for (int m = 0; m < 4; ++m)
      af[m] = *(const s16x8*)&As[(wm + m * 16 + lrow) * 32 + lk8];
#pragma unroll
    for (int n = 0; n < 4; ++n)
      bfr[n] = *(const s16x8*)&Bs[(wn + n * 16 + lrow) * 32 + lk8];
#pragma unroll
    for (int m = 0; m < 4; ++m)
#pragma unroll
      for (int n = 0; n < 4; ++n)
        acc[m][n] = __builtin_amdgcn_mfma_f32_16x16x32_bf16(af[m], bfr[n], acc[m][n], 0, 0, 0);
    __syncthreads();
  }

  const int erow = m0 + wm + ((lane >> 4) << 2);
  const int ecol = n0 + wn + lrow;
  float sc[4], sh[4];
#pragma unroll
  for (int n = 0; n < 4; ++n) {
    const int c = ecol + n * 16;
    const float s = bn_g[c] * rsqrtf(bn_v[c] + BN_EPSF);
    sc[n] = s;
    sh[n] = (bias[c] - bn_m[c]) * s + bn_b[c];
  }
#pragma unroll
  for (int m = 0; m < 4; ++m)
#pragma unroll
    for (int n = 0; n < 4; ++n)
#pragma unroll
      for (int r = 0; r < 4; ++r) {
        const size_t idx = (size_t)(erow + m * 16 + r) * N + (ecol + n * 16);
        out16[idx] = f2bf(fmaxf(acc[m][n][r] * sc[n] + sh[n], 0.f));
      }
}

// ---------------------------------------------------------------------------
// top-2 mean per (b, d) over compacted bf16 emb rows
// ---------------------------------------------------------------------------
__global__ __launch_bounds__(256)
void topk_kernel(const short* __restrict__ emb16, const int* __restrict__ lens,
                 const int* __restrict__ cum, float* __restrict__ er) {
  const int b = blockIdx.x;
  const int len = lens[b];
  const size_t base = (size_t)cum[b] * 1024;
  const int tid = threadIdx.x;
#pragma unroll
  for (int j = 0; j < 4; ++j) {
    const int d = j * 256 + tid;
    float m1 = -3.0e38f, m2 = -3.0e38f;
    for (int l = 0; l < len; ++l) {
      const float v = bf2f(emb16[base + (size_t)l * 1024 + d]);
      if (v > m1) { m2 = m1; m1 = v; }
      else        { m2 = fmaxf(m2, v); }
    }
    er[(size_t)b * 1024 + d] = 0.5f * (m1 + m2);
  }
}

// ---------------------------------------------------------------------------
// Fused attention on compacted rows: one block per (b,h).
// ---------------------------------------------------------------------------
__global__ __launch_bounds__(256)
void attn_kernel(const short* __restrict__ qkv, const int* __restrict__ lens,
                 const int* __restrict__ cum, short* __restrict__ ctx) {
  __shared__ short Qs[64 * 128];
  __shared__ short Ks[64 * 128];
  __shared__ short Vt[128 * 64];
  const int tid  = threadIdx.x;
  const int lane = tid & 63;
  const int wave = tid >> 6;
  const int b = blockIdx.x >> 3;
  const int h = blockIdx.x & 7;
  const int len = lens[b];
  const int rb  = cum[b];
  const size_t qb = (size_t)rb * 3072 + h * 128;

  {
    const int rr = wave * 4 + (lane >> 4);
    const int cc = (lane & 15) * 8;
#pragma unroll
    for (int r = 0; r < 4; ++r) {
      stage16(qkv + qb +        (size_t)(r * 16 + rr) * 3072 + cc, &Qs[(r * 16 + wave * 4) * 128]);
      stage16(qkv + qb + 1024 + (size_t)(r * 16 + rr) * 3072 + cc, &Ks[(r * 16 + wave * 4) * 128]);
    }
  }
#pragma unroll
  for (int i = 0; i < 2; ++i) {
    const int c  = i * 256 + tid;
    const int lp = c >> 4;
    const int dg = c & 15;
    const short* src = qkv + qb + 2048 + (size_t)(2 * lp) * 3072 + dg * 8;
    s16x8 v0 = *(const s16x8*)src;
    s16x8 v1 = *(const s16x8*)(src + 3072);
    const bool ok0 = (2 * lp)     < len;
    const bool ok1 = (2 * lp + 1) < len;
#pragma unroll
    for (int j = 0; j < 8; ++j) {
      const uint32_t lo = ok0 ? (uint32_t)(uint16_t)v0[j] : 0u;
      const uint32_t hi = ok1 ? (uint32_t)(uint16_t)v1[j] : 0u;
      *(uint32_t*)&Vt[(dg * 8 + j) * 64 + 2 * lp] = lo | (hi << 16);
    }
  }
  __syncthreads();

  const int lrow = lane & 15;
  const int lk8  = (lane >> 4) * 8;

  f32x4 sacc[4] = {};
#pragma unroll
  for (int ks = 0; ks < 4; ++ks) {
    s16x8 aq = *(const s16x8*)&Qs[(wave * 16 + lrow) * 128 + ks * 32 + lk8];
#pragma unroll
    for (int n = 0; n < 4; ++n) {
      s16x8 bk = *(const s16x8*)&Ks[(n * 16 + lrow) * 128 + ks * 32 + lk8];
      sacc[n] = __builtin_amdgcn_mfma_f32_16x16x32_bf16(aq, bk, sacc[n], 0, 0, 0);
    }
  }

  const float scale = 0.08838834764831845f;
#pragma unroll
  for (int r = 0; r < 4; ++r) {
    float sv[4];
    float mx = -1e30f;
#pragma unroll
    for (int n = 0; n < 4; ++n) {
      float v = sacc[n][r] * scale;
      if (n * 16 + lrow >= len) v = -1e30f;
      sv[n] = v;
      mx = fmaxf(mx, v);
    }
    mx = fmaxf(mx, __shfl_xor(mx, 1));
    mx = fmaxf(mx, __shfl_xor(mx, 2));
    mx = fmaxf(mx, __shfl_xor(mx, 4));
    mx = fmaxf(mx, __shfl_xor(mx, 8));
    float pv[4], sum = 0.f;
#pragma unroll
    for (int n = 0; n < 4; ++n) { pv[n] = __expf(sv[n] - mx); sum += pv[n]; }
    sum += __shfl_xor(sum, 1);
    sum += __shfl_xor(sum, 2);
    sum += __shfl_xor(sum, 4);
    sum += __shfl_xor(sum, 8);
    const float inv = 1.f / sum;
    const int prow = wave * 16 + ((lane >> 4) << 2) + r;
#pragma unroll
    for (int n = 0; n < 4; ++n)
      Qs[prow * 128 + n * 16 + lrow] = f2bf(pv[n] * inv);
  }
  __syncthreads();

  f32x4 oacc[8] = {};
#pragma unroll
  for (int ks = 0; ks < 2; ++ks) {
    s16x8 ap = *(const s16x8*)&Qs[(wave * 16 + lrow) * 128 + ks * 32 + lk8];
#pragma unroll
    for (int n = 0; n < 8; ++n) {
      s16x8 bv = *(const s16x8*)&Vt[(n * 16 + lrow) * 64 + ks * 32 + lk8];
      oacc[n] = __builtin_amdgcn_mfma_f32_16x16x32_bf16(ap, bv, oacc[n], 0, 0, 0);
    }
  }
  const size_t ob = (size_t)rb * 1024 + h * 128;
#pragma unroll
  for (int n = 0; n < 8; ++n)
#pragma unroll
    for (int r = 0; r < 4; ++r) {
      const int row = wave * 16 + ((lane >> 4) << 2) + r;
      if (row < len)
        ctx[ob + (size_t)row * 1024 + n * 16 + lrow] = f2bf(oacc[n][r]);
    }
}

// ---------------------------------------------------------------------------
// LayerNorm over 1024 (LN1), one block per compacted row; writes bf16
// ---------------------------------------------------------------------------
__global__ __launch_bounds__(256)
void ln_kernel(const float* __restrict__ x, const float* __restrict__ gg,
               const float* __restrict__ bb, const int* __restrict__ hdr,
               short* __restrict__ y16) {
  if ((int)blockIdx.x >= hdr[1]) return;
  __shared__ float red[8];
  const int tid = threadIdx.x;
  const int lane = tid & 63;
  const int wave = tid >> 6;
  const size_t base = (size_t)blockIdx.x * 1024;
  float4 v = ((const float4*)(x + base))[tid];
  float s1 = v.x + v.y + v.z + v.w;
  float s2 = v.x * v.x + v.y * v.y + v.z * v.z + v.w * v.w;
#pragma unroll
  for (int o = 1; o < 64; o <<= 1) { s1 += __shfl_xor(s1, o); s2 += __shfl_xor(s2, o); }
  if (lane == 0) { red[wave] = s1; red[wave + 4] = s2; }
  __syncthreads();
  s1 = red[0] + red[1] + red[2] + red[3];
  s2 = red[4] + red[5] + red[6] + red[7];
  const float mu  = s1 * (1.f / 1024.f);
  const float var = fmaxf(s2 * (1.f / 1024.f) - mu * mu, 0.f);
  const float rs  = rsqrtf(var + LN_EPSF);
  float4 g4 = ((const float4*)gg)[tid];
  float4 b4 = ((const float4*)bb)[tid];
  s16x4 hh;
  hh[0] = f2bf((v.x - mu) * rs * g4.x + b4.x);
  hh[1] = f2bf((v.y - mu) * rs * g4.y + b4.y);
  hh[2] = f2bf((v.z - mu) * rs * g4.z + b4.z);
  hh[3] = f2bf((v.w - mu) * rs * g4.w + b4.w);
  ((s16x4*)(y16 + base))[tid] = hh;
}

// ---------------------------------------------------------------------------
// fused LN2 + avg-pool over compacted valid tokens + mix + L2 normalize
// ---------------------------------------------------------------------------
__global__ __launch_bounds__(256)
void ln2_final_kernel(const float* __restrict__ x, const float* __restrict__ gg,
                      const float* __restrict__ bb, const float* __restrict__ er,
                      const int* __restrict__ lens, const int* __restrict__ cum,
                      float* __restrict__ out) {
  __shared__ float part[4][1024];
  __shared__ float red[4];
  const int tid = threadIdx.x, lane = tid & 63, w = tid >> 6;
  const int b = blockIdx.x, len = lens[b];
  const size_t rb = (size_t)cum[b];
  float4 g4[4], b4[4];
#pragma unroll
  for (int k = 0; k < 4; ++k) {
    g4[k] = ((const float4*)gg)[k * 64 + lane];
    b4[k] = ((const float4*)bb)[k * 64 + lane];
  }
  float4 acc[4];
#pragma unroll
  for (int k = 0; k < 4; ++k) acc[k] = make_float4(0.f, 0.f, 0.f, 0.f);

  for (int l = w; l < len; l += 4) {
    const float4* row = (const float4*)(x + (rb + l) * 1024);
    float4 v[4]; float s1 = 0.f, s2 = 0.f;
#pragma unroll
    for (int k = 0; k < 4; ++k) {
      v[k] = row[k * 64 + lane];
      s1 += v[k].x + v[k].y + v[k].z + v[k].w;
      s2 += v[k].x * v[k].x + v[k].y * v[k].y + v[k].z * v[k].z + v[k].w * v[k].w;
    }
#pragma unroll
    for (int o = 1; o < 64; o <<= 1) { s1 += __shfl_xor(s1, o); s2 += __shfl_xor(s2, o); }
    const float mu = s1 * (1.f / 1024.f);
    const float rs = rsqrtf(fmaxf(s2 * (1.f / 1024.f) - mu * mu, 0.f) + LN_EPSF);
#pragma unroll
    for (int k = 0; k < 4; ++k) {
      acc[k].x += (v[k].x - mu) * rs * g4[k].x + b4[k].x;
      acc[k].y += (v[k].y - mu) * rs * g4[k].y + b4[k].y;
      acc[k].z += (v[k].z - mu) * rs * g4[k].z + b4[k].z;
      acc[k].w += (v[k].w - mu) * rs * g4[k].w + b4[k].w;
    }
  }
#pragma unroll
  for (int k = 0; k < 4; ++k)
    ((float4*)&part[w][0])[k * 64 + lane] = acc[k];
  __syncthreads();

  float4 s = ((const float4*)&part[0][0])[tid];
#pragma unroll
  for (int w2 = 1; w2 < 4; ++w2) {
    float4 t4 = ((const float4*)&part[0][0])[w2 * 256 + tid];
    s.x += t4.x; s.y += t4.y; s.z += t4.z; s.w += t4.w;
  }
  const float il = 0.5f / (float)len;
  float4 e = ((const float4*)(er + (size_t)b * 1024))[tid];
  const float o0 = 0.5f * e.x + s.x * il;
  const float o1 = 0.5f * e.y + s.y * il;
  const float o2 = 0.5f * e.z + s.z * il;
  const float o3 = 0.5f * e.w + s.w * il;
  float ss = o0 * o0 + o1 * o1 + o2 * o2 + o3 * o3;
#pragma unroll
  for (int o = 1; o < 64; o <<= 1) ss += __shfl_xor(ss, o);
  if (lane == 0) red[w] = ss;
  __syncthreads();
  ss = red[0] + red[1] + red[2] + red[3];
  const float nrm = 1.f / (sqrtf(ss) + 1e-8f);
  ((float4*)(out + (size_t)b * 1024))[tid] = make_float4(o0 * nrm, o1 * nrm, o2 * nrm, o3 * nrm);
}

// ---------------------------------------------------------------------------
extern "C" void kernel_launch(void* const* d_in, const int* in_sizes, int n_in,
                              void* d_out, int out_size, void* d_ws, size_t ws_size,
                              hipStream_t stream) {
  (void)in_sizes; (void)n_in; (void)out_size; (void)ws_size;
  const float* images = (const float*)d_in[0];
  const int*   lens   = (const int*)d_in[1];
  const float* fc1_w = (const float*)d_in[2];
  const float* fc1_b = (const float*)d_in[3];
  const float* bn_g  = (const float*)d_in[4];
  const float* bn_b  = (const float*)d_in[5];
  const float* bn_m  = (const float*)d_in[6];
  const float* bn_v  = (const float*)d_in[7];
  const float* fc2_w = (const float*)d_in[8];
  const float* fc2_b = (const float*)d_in[9];
  const float* in_w  = (const float*)d_in[10];
  const float* in_b  = (const float*)d_in[11];
  const float* out_w = (const float*)d_in[12];
  const float* out_b = (const float*)d_in[13];
  const float* ln1_g = (const float*)d_in[14];
  const float* ln1_b = (const float*)d_in[15];
  const float* ff1_w = (const float*)d_in[16];
  const float* ff1_b = (const float*)d_in[17];
  const float* ff2_w = (const float*)d_in[18];
  const float* ff2_b = (const float*)d_in[19];
  const float* ln2_g = (const float*)d_in[20];
  const float* ln2_b = (const float*)d_in[21];
  float* out = (float*)d_out;

  char* ws = (char*)d_ws;
  const size_t OFF_IMG16 = 0;                          // 67108864 (img16 / x1s / x2s)
  const size_t OFF_FC1W  = 67108864;                   // 2097152
  const size_t OFF_FC2W  = OFF_FC1W + 2097152;         // 1048576
  const size_t OFF_INW   = OFF_FC2W + 1048576;         // 6291456
  const size_t OFF_OUTW  = OFF_INW  + 6291456;         // 2097152
  const size_t OFF_FF1W  = OFF_OUTW + 2097152;         // 2097152
  const size_t OFF_FF2W  = OFF_FF1W + 2097152;         // 2097152
  const size_t OFF_H1    = OFF_FF2W + 2097152;         // 16777216
  const size_t OFF_EMB16 = OFF_H1 + 16777216;          // 33554432
  const size_t OFF_QKV   = OFF_EMB16 + 33554432;       // 101056512 (16448 rows)
  const size_t OFF_CTX   = OFF_QKV + 101056512;        // 33554432
  const size_t OFF_ERES  = OFF_CTX + 33554432;         // 1048576
  const size_t OFF_HDR   = OFF_ERES + 1048576;         // 256
  const size_t OFF_CUM   = OFF_HDR + 256;              // 1024
  const size_t OFF_TOK   = OFF_CUM + 1024;             // 65536

  short* img16  = (short*)(ws + OFF_IMG16);
  short* fc1w16 = (short*)(ws + OFF_FC1W);
  short* fc2w16 = (short*)(ws + OFF_FC2W);
  short* inw16  = (short*)(ws + OFF_INW);
  short* outw16 = (short*)(ws + OFF_OUTW);
  short* ff1w16 = (short*)(ws + OFF_FF1W);
  short* ff2w16 = (short*)(ws + OFF_FF2W);
  short* h1     = (short*)(ws + OFF_H1);
  short* emb16  = (short*)(ws + OFF_EMB16);
  short* qkv16  = (short*)(ws + OFF_QKV);
  short* ctx16  = (short*)(ws + OFF_CTX);
  float* embres = (float*)(ws + OFF_ERES);
  int*   hdr    = (int*)(ws + OFF_HDR);
  int*   cum    = (int*)(ws + OFF_CUM);
  int*   tokmap = (int*)(ws + OFF_TOK);
  float* x1s = (float*)(ws + OFF_IMG16);   // pre-LN1 f32  (img16 dead)
  short* x1h = emb16;                      // post-LN1 bf16 (emb16 dead after out-proj)
  short* ffh = ctx16;                      // ffn hidden    (ctx16 dead)
  float* x2s = (float*)(ws + OFF_IMG16);   // pre-LN2 f32   (x1s dead)

  const dim3 blk(256);
  const size_t SMEM = 131072;

  // compaction metadata
  prefix_kernel<<<1, blk, 0, stream>>>(lens, cum, hdr, tokmap);
  tokmap_kernel<<<256, 64, 0, stream>>>(lens, cum, tokmap);

  // converts (images gathered+compacted)
  cvt_gather_kernel<<<2048, blk, 0, stream>>>(images, tokmap, hdr, img16);
  CvtArgs ca;
  ca.src[0] = fc1_w; ca.dst[0] = fc1w16; ca.n4[0] = 1048576 / 4;
  ca.src[1] = fc2_w; ca.dst[1] = fc2w16; ca.n4[1] = 524288 / 4;
  ca.src[2] = in_w;  ca.dst[2] = inw16;  ca.n4[2] = 3145728 / 4;
  ca.src[3] = out_w; ca.dst[3] = outw16; ca.n4[3] = 1048576 / 4;
  ca.src[4] = ff1_w; ca.dst[4] = ff1w16; ca.n4[4] = 1048576 / 4;
  ca.src[5] = ff2_w; ca.dst[5] = ff2w16; ca.n4[5] = 1048576 / 4;
  cvt6_kernel<<<1024, blk, 0, stream>>>(ca);

  // fc1 + BN + ReLU -> h1 (bf16, compacted)
  gemm_bt_h1<<<dim3(4, 128), blk, 0, stream>>>(
      img16, fc1w16, fc1_b, bn_g, bn_b, bn_m, bn_v, hdr, h1, 16384, 512, 2048);
  // fc2 -> emb16 (compacted)  [128x128 high-occupancy kernel]
  gemm128<EPI_PLAIN><<<dim3(8, 128), blk, 0, stream>>>(
      h1, fc2w16, fc2_b, nullptr, hdr, nullptr, emb16, 1024, 512);
  // top-2 pooling over compacted emb
  topk_kernel<<<256, blk, 0, stream>>>(emb16, lens, cum, embres);
  // qkv projection (256x256 pipelined kernel — fills 2 full passes)
  gemm256<EPI_PLAIN><<<dim3(12, 64), 512, SMEM, stream>>>(
      emb16, inw16, in_b, nullptr, hdr, nullptr, qkv16, 16384, 3072, 1024);
  // attention (compacted rows)
  attn_kernel<<<2048, blk, 0, stream>>>(qkv16, lens, cum, ctx16);
  // out projection + residual(emb16) -> pre-LN1 f32
  gemm128<EPI_RES><<<dim3(8, 128), blk, 0, stream>>>(
      ctx16, outw16, out_b, emb16, hdr, x1s, nullptr, 1024, 1024);
  ln_kernel<<<16384, blk, 0, stream>>>(x1s, ln1_g, ln1_b, hdr, x1h);
  // ffn
  gemm128<EPI_FF1><<<dim3(8, 128), blk, 0, stream>>>(
      x1h, ff1w16, ff1_b, nullptr, hdr, nullptr, ffh, 1024, 1024);
  gemm128<EPI_RES><<<dim3(8, 128), blk, 0, stream>>>(
      ffh, ff2w16, ff2_b, x1h, hdr, x2s, nullptr, 1024, 1024);
  // fused LN2 + avg-pool + mix + normalize
  ln2_final_kernel<<<256, blk, 0, stream>>>(x2s, ln2_g, ln2_b, embres, lens, cum, out);
}

// Round 9
// 398.268 us; speedup vs baseline: 1.1215x; 1.1215x over previous
//
#include <hip/hip_runtime.h>
#include <stdint.h>
#include <stddef.h>

// ---------------------------------------------------------------------------
// EncoderImageAggr: bf16-MFMA pipeline for MI355X (gfx950)
// B=256 L=64 IMG_DIM=2048 D=1024 H=8 DH=128. All GEMMs are C = A @ W^T.
// Round 9: round-7 base + gemm128p (pipelined 128x128, 64KB LDS, 2 blocks/CU)
// for fc2/out/ff1/ff2 to eliminate the 132-blocks-on-256-CUs idle problem.
// qkv keeps the proven 256x256 pipelined kernel. prefix+tokmap merged;
// weight converts merged into the gather-convert kernel.
// ---------------------------------------------------------------------------

typedef short s16x8 __attribute__((ext_vector_type(8)));
typedef short s16x4 __attribute__((ext_vector_type(4)));
typedef float f32x4 __attribute__((ext_vector_type(4)));

#define LN_EPSF 1e-5f
#define BN_EPSF 1e-5f

__device__ __forceinline__ short f2bf(float f) {
  union { float f; uint32_t u; } x; x.f = f;
  uint32_t r = x.u + 0x7fffu + ((x.u >> 16) & 1u);   // RNE
  return (short)(r >> 16);
}
__device__ __forceinline__ float bf2f(short s) {
  union { uint32_t u; float f; } x; x.u = ((uint32_t)(uint16_t)s) << 16;
  return x.f;
}

typedef const __attribute__((address_space(1))) short glb_s16_t;
typedef __attribute__((address_space(3))) short lds_s16_t;

__device__ __forceinline__ void stage16(const short* g, short* l) {
  __builtin_amdgcn_global_load_lds((glb_s16_t*)g, (lds_s16_t*)l, 16, 0, 0);
}

// involution swizzle for 64B-row LDS slots (measured 0 bank conflicts)
__device__ __forceinline__ int swz(int off) {
  return off ^ (((off >> 7) & 3) << 4);
}

enum { EPI_PLAIN = 0, EPI_FF1 = 3, EPI_RES = 4 };

// ---------------------------------------------------------------------------
// prefix-sum of lens -> cum (exclusive), hdr = {Mc, Mc_pad}; build tokmap
// ---------------------------------------------------------------------------
__global__ __launch_bounds__(256)
void prefix_kernel(const int* __restrict__ lens, int* __restrict__ cum,
                   int* __restrict__ hdr, int* __restrict__ tokmap) {
  __shared__ int wsum[4];
  __shared__ int sc[256];
  __shared__ int mcpad;
  const int tid = threadIdx.x, lane = tid & 63, wave = tid >> 6;
  const int mylen = lens[tid];
  int v = mylen;
#pragma unroll
  for (int o = 1; o < 64; o <<= 1) {
    int t = __shfl_up(v, o);
    if (lane >= o) v += t;
  }
  if (lane == 63) wsum[wave] = v;
  __syncthreads();
  int add = 0;
#pragma unroll
  for (int w2 = 0; w2 < 4; ++w2) if (w2 < wave) add += wsum[w2];
  const int incl = v + add;
  const int excl = incl - mylen;
  cum[tid] = excl;
  sc[tid] = excl;
  if (tid == 255) {
    hdr[0] = incl;                       // Mc
    mcpad  = (incl + 255) & ~255;        // Mc_pad (multiple of 256)
    hdr[1] = mcpad;
  }
  __syncthreads();
  // scatter this batch's token ids
  for (int l = 0; l < mylen; ++l) tokmap[excl + l] = tid * 64 + l;
  // zero the padding tail [Mc, Mc_pad)
  const int mc = sc[255] + lens[255];
  for (int i = mc + tid; i < mcpad; i += 256) tokmap[i] = 0;
}

// ---------------------------------------------------------------------------
// gathered fp32 -> bf16 convert of valid image rows (compacted) + weights
// ---------------------------------------------------------------------------
struct CvtArgs { const float* src[6]; short* dst[6]; int n4[6]; };

__global__ __launch_bounds__(256)
void cvt_gather_kernel(const float* __restrict__ img,
                       const int* __restrict__ tokmap,
                       const int* __restrict__ hdr, short* __restrict__ out,
                       CvtArgs a) {
  const int n4 = hdr[1] << 9;                    // Mc_pad * 512 float4s
  const int stride = gridDim.x * 256;
  for (int i = blockIdx.x * 256 + threadIdx.x; i < n4; i += stride) {
    const int row = i >> 9, col = i & 511;
    float4 v = ((const float4*)img)[(size_t)tokmap[row] * 512 + col];
    s16x4 h; h[0] = f2bf(v.x); h[1] = f2bf(v.y); h[2] = f2bf(v.z); h[3] = f2bf(v.w);
    ((s16x4*)out)[i] = h;
  }
#pragma unroll
  for (int s = 0; s < 6; ++s) {
    const int n = a.n4[s];
    const float4* in = (const float4*)a.src[s];
    s16x4* outp = (s16x4*)a.dst[s];
    for (int i = blockIdx.x * 256 + threadIdx.x; i < n; i += stride) {
      float4 v = in[i];
      s16x4 h; h[0] = f2bf(v.x); h[1] = f2bf(v.y); h[2] = f2bf(v.z); h[3] = f2bf(v.w);
      outp[i] = h;
    }
  }
}

// ---------------------------------------------------------------------------
// 256x256 pipelined GEMM (round-3 schedule) — qkv only. 512 thr, 8 waves
// (2Mx4N), per-wave 128x64. Ring-4 half-slots [256][32]; counted vmcnt(4).
// ---------------------------------------------------------------------------
template<int EPI>
__global__ __launch_bounds__(512, 2)
void gemm256(const short* __restrict__ A, const short* __restrict__ Bw,
             const float* __restrict__ bias, const short* __restrict__ res16,
             const int* __restrict__ hdr,
             float* __restrict__ out32, short* __restrict__ out16,
             int M, int N, int K) {
  extern __shared__ char smem[];                 // 131072 B
  (void)M;
  const int tid  = threadIdx.x;
  const int lane = tid & 63;
  const int w    = tid >> 6;
  const int wr   = w >> 2;
  const int wc   = w & 3;
  const int lrow = lane & 15;
  const int cg   = lane >> 4;
  const int NH   = K >> 5;
  const int gx   = gridDim.x;

  const int p = blockIdx.y * gx + blockIdx.x;
  const int nwork = (hdr[1] >> 8) * gx;
  if (p >= nwork) return;
  const int xcd = p & 7, off = p >> 3;
  const int q = nwork >> 3, r = nwork & 7;
  const int wg = (xcd < r ? xcd * (q + 1) : r * (q + 1) + (xcd - r) * q) + off;
  const int m0 = (wg / gx) * 256;
  const int n0 = (wg % gx) * 256;

  const int ldb = K * 2;
  size_t gA[2], gB[2];
#pragma unroll
  for (int j = 0; j < 2; ++j) {
    const int pp = tid * 16 + j * 8192;
    const int l = swz(pp);
    const int row = l >> 6, colb = l & 63;
    gA[j] = (size_t)(m0 + row) * ldb + colb;
    gB[j] = (size_t)(n0 + row) * ldb + colb;
  }
  const char* Ab = (const char*)A;
  const char* Bb = (const char*)Bw;
  char* ldsA = smem;
  char* ldsB = smem + 65536;
  const int wofs = w * 1024;

  auto stageApart = [&](int i) {
    const int rg = ((i & 3) << 14) + wofs;
    const int ko = i * 64;
    stage16((const short*)(Ab + gA[0] + ko), (short*)(ldsA + rg));
    stage16((const short*)(Ab + gA[1] + ko), (short*)(ldsA + rg + 8192));
  };
  auto stageBpart = [&](int i) {
    const int rg = ((i & 3) << 14) + wofs;
    const int ko = i * 64;
    stage16((const short*)(Bb + gB[0] + ko), (short*)(ldsB + rg));
    stage16((const short*)(Bb + gB[1] + ko), (short*)(ldsB + rg + 8192));
  };

  int offA[8], offB[4];
#pragma unroll
  for (int mf = 0; mf < 8; ++mf)
    offA[mf] = swz((wr * 128 + mf * 16 + lrow) * 64 + cg * 16);
#pragma unroll
  for (int nf = 0; nf < 4; ++nf)
    offB[nf] = swz((wc * 64 + nf * 16 + lrow) * 64 + cg * 16);

  f32x4 acc[8][4] = {};

  stageApart(0); stageBpart(0);
  stageApart(1); stageBpart(1);
  stageApart(2); stageBpart(2);
  asm volatile("s_waitcnt vmcnt(8)" ::: "memory");
  __builtin_amdgcn_s_barrier();
  __builtin_amdgcn_sched_barrier(0);
  s16x8 af_cur[4], bf_cur[4], af_nxt[4], bf_nxt[4], af2[4];
#pragma unroll
  for (int m = 0; m < 4; ++m) af_cur[m] = *(const s16x8*)(ldsA + offA[m]);
#pragma unroll
  for (int n = 0; n < 4; ++n) bf_cur[n] = *(const s16x8*)(ldsB + offB[n]);

  for (int i = 0; i < NH - 1; ++i) {
    const int si  = i & 3;
    const int si1 = (i + 1) & 3;
    const char* pA  = ldsA + (si  << 14);
    const char* pA1 = ldsA + (si1 << 14);
    const char* pB1 = ldsB + (si1 << 14);

    if (i + 2 < NH) { asm volatile("s_waitcnt vmcnt(4)" ::: "memory"); }
    else            { asm volatile("s_waitcnt vmcnt(0)" ::: "memory"); }
    __builtin_amdgcn_s_barrier();
    __builtin_amdgcn_sched_barrier(0);

#pragma unroll
    for (int m = 0; m < 4; ++m) af_nxt[m] = *(const s16x8*)(pA + offA[m + 4]);
#pragma unroll
    for (int n = 0; n < 4; ++n) bf_nxt[n] = *(const s16x8*)(pB1 + offB[n]);
    if (i + 3 < NH) stageApart(i + 3);
    asm volatile("s_waitcnt lgkmcnt(8)" ::: "memory");
    __builtin_amdgcn_sched_barrier(0);
    __builtin_amdgcn_s_setprio(1);
#pragma unroll
    for (int m = 0; m < 4; ++m)
#pragma unroll
      for (int n = 0; n < 4; ++n)
        acc[m][n] = __builtin_amdgcn_mfma_f32_16x16x32_bf16(af_cur[m], bf_cur[n], acc[m][n], 0, 0, 0);
    __builtin_amdgcn_s_setprio(0);

#pragma unroll
    for (int m = 0; m < 4; ++m) af2[m] = *(const s16x8*)(pA1 + offA[m]);
    if (i + 3 < NH) stageBpart(i + 3);
    asm volatile("s_waitcnt lgkmcnt(4)" ::: "memory");
    __builtin_amdgcn_sched_barrier(0);
    __builtin_amdgcn_s_setprio(1);
#pragma unroll
    for (int m = 0; m < 4; ++m)
#pragma unroll
      for (int n = 0; n < 4; ++n)
        acc[m + 4][n] = __builtin_amdgcn_mfma_f32_16x16x32_bf16(af_nxt[m], bf_cur[n], acc[m + 4][n], 0, 0, 0);
    __builtin_amdgcn_s_setprio(0);

#pragma unroll
    for (int m = 0; m < 4; ++m) af_cur[m] = af2[m];
#pragma unroll
    for (int n = 0; n < 4; ++n) bf_cur[n] = bf_nxt[n];
  }

  {
    const char* pA = ldsA + (((NH - 1) & 3) << 14);
    asm volatile("s_waitcnt vmcnt(0)" ::: "memory");
    __builtin_amdgcn_s_barrier();
    __builtin_amdgcn_sched_barrier(0);
#pragma unroll
    for (int m = 0; m < 4; ++m) af_nxt[m] = *(const s16x8*)(pA + offA[m + 4]);
    asm volatile("s_waitcnt lgkmcnt(4)" ::: "memory");
    __builtin_amdgcn_sched_barrier(0);
    __builtin_amdgcn_s_setprio(1);
#pragma unroll
    for (int m = 0; m < 4; ++m)
#pragma unroll
      for (int n = 0; n < 4; ++n)
        acc[m][n] = __builtin_amdgcn_mfma_f32_16x16x32_bf16(af_cur[m], bf_cur[n], acc[m][n], 0, 0, 0);
    __builtin_amdgcn_s_setprio(0);
    asm volatile("s_waitcnt lgkmcnt(0)" ::: "memory");
    __builtin_amdgcn_sched_barrier(0);
    __builtin_amdgcn_s_setprio(1);
#pragma unroll
    for (int m = 0; m < 4; ++m)
#pragma unroll
      for (int n = 0; n < 4; ++n)
        acc[m + 4][n] = __builtin_amdgcn_mfma_f32_16x16x32_bf16(af_nxt[m], bf_cur[n], acc[m + 4][n], 0, 0, 0);
    __builtin_amdgcn_s_setprio(0);
  }

  const int ecol0 = n0 + wc * 64 + lrow;
  float bz[4];
#pragma unroll
  for (int nf = 0; nf < 4; ++nf) bz[nf] = bias[ecol0 + nf * 16];
  const int erow0 = m0 + wr * 128 + (cg << 2);

#pragma unroll
  for (int mf = 0; mf < 8; ++mf) {
#pragma unroll
    for (int nf = 0; nf < 4; ++nf) {
#pragma unroll
      for (int r2 = 0; r2 < 4; ++r2) {
        const int row = erow0 + mf * 16 + r2;
        const size_t idx = (size_t)row * N + (ecol0 + nf * 16);
        const float v = acc[mf][nf][r2] + bz[nf];
        if constexpr (EPI == EPI_PLAIN) {
          out16[idx] = f2bf(v);
        } else if constexpr (EPI == EPI_FF1) {
          out16[idx] = f2bf(fmaxf(v, 0.f));
        } else {
          out32[idx] = v + bf2f(res16[idx]);
        }
      }
    }
  }
}

// ---------------------------------------------------------------------------
// 128x128 PIPELINED GEMM (uniform shrink of gemm256's verified schedule).
// 512 thr, 8 waves (2Mx4N), per-wave 64x32 (acc[4][2]). Ring-4 half-slots
// [128][32] bf16 (8KB) per matrix -> 64KB LDS -> 2 blocks/CU.
// L=2 loads/half-step (1A+1B): prologue vmcnt(4); loop vmcnt(2);
// lgkmcnt(4)/(2). Used for fc2/out/ff1/ff2 (528 live blocks fill the machine).
// ---------------------------------------------------------------------------
template<int EPI>
__global__ __launch_bounds__(512, 4)
void gemm128p(const short* __restrict__ A, const short* __restrict__ Bw,
              const float* __restrict__ bias, const short* __restrict__ res16,
              const int* __restrict__ hdr,
              float* __restrict__ out32, short* __restrict__ out16,
              int N, int K) {
  extern __shared__ char smem[];                 // 65536 B
  const int tid  = threadIdx.x;
  const int lane = tid & 63;
  const int w    = tid >> 6;
  const int wr   = w >> 2;                       // 0..1
  const int wc   = w & 3;                        // 0..3
  const int lrow = lane & 15;
  const int cg   = lane >> 4;
  const int NH   = K >> 5;
  const int gx   = gridDim.x;

  const int p = blockIdx.y * gx + blockIdx.x;
  const int nwork = (hdr[1] >> 7) * gx;          // live blocks (M-tiles of 128)
  if (p >= nwork) return;
  const int xcd = p & 7, off = p >> 3;
  const int q = nwork >> 3, r = nwork & 7;
  const int wg = (xcd < r ? xcd * (q + 1) : r * (q + 1) + (xcd - r) * q) + off;
  const int m0 = (wg / gx) * 128;
  const int n0 = (wg % gx) * 128;

  const int ldb = K * 2;
  size_t gA, gB;
  {
    const int pp = tid * 16;                     // [0, 8192)
    const int l = swz(pp);
    const int row = l >> 6, colb = l & 63;
    gA = (size_t)(m0 + row) * ldb + colb;
    gB = (size_t)(n0 + row) * ldb + colb;
  }
  const char* Ab = (const char*)A;
  const char* Bb = (const char*)Bw;
  char* ldsA = smem;                             // 4 x 8KB
  char* ldsB = smem + 32768;                     // 4 x 8KB
  const int wofs = w * 1024;

  auto stageA = [&](int i) {                     // 1 load/thread
    stage16((const short*)(Ab + gA + i * 64), (short*)(ldsA + ((i & 3) << 13) + wofs));
  };
  auto stageB = [&](int i) {
    stage16((const short*)(Bb + gB + i * 64), (short*)(ldsB + ((i & 3) << 13) + wofs));
  };

  int offA[4], offB[2];
#pragma unroll
  for (int mf = 0; mf < 4; ++mf)
    offA[mf] = swz((wr * 64 + mf * 16 + lrow) * 64 + cg * 16);
#pragma unroll
  for (int nf = 0; nf < 2; ++nf)
    offB[nf] = swz((wc * 32 + nf * 16 + lrow) * 64 + cg * 16);

  f32x4 acc[4][2] = {};

  // prologue: stage H0..H2 (6 loads), confirm H0 (leave H1,H2 = 4)
  stageA(0); stageB(0);
  stageA(1); stageB(1);
  stageA(2); stageB(2);
  asm volatile("s_waitcnt vmcnt(4)" ::: "memory");
  __builtin_amdgcn_s_barrier();
  __builtin_amdgcn_sched_barrier(0);
  s16x8 af_cur[2], bf_cur[2], af_nxt[2], bf_nxt[2], af2[2];
#pragma unroll
  for (int m = 0; m < 2; ++m) af_cur[m] = *(const s16x8*)(ldsA + offA[m]);
#pragma unroll
  for (int n = 0; n < 2; ++n) bf_cur[n] = *(const s16x8*)(ldsB + offB[n]);

  for (int i = 0; i < NH - 1; ++i) {
    const char* pA  = ldsA + ((i & 3) << 13);
    const char* pA1 = ldsA + (((i + 1) & 3) << 13);
    const char* pB1 = ldsB + (((i + 1) & 3) << 13);

    // confirm H_{i+1} (outstanding: H_{i+1}(2) + H_{i+2}(2))
    if (i + 2 < NH) { asm volatile("s_waitcnt vmcnt(2)" ::: "memory"); }
    else            { asm volatile("s_waitcnt vmcnt(0)" ::: "memory"); }
    __builtin_amdgcn_s_barrier();
    __builtin_amdgcn_sched_barrier(0);

    // sub0: read hi-A of Hi + B of H_{i+1}; MFMA lo half
#pragma unroll
    for (int m = 0; m < 2; ++m) af_nxt[m] = *(const s16x8*)(pA + offA[m + 2]);
#pragma unroll
    for (int n = 0; n < 2; ++n) bf_nxt[n] = *(const s16x8*)(pB1 + offB[n]);
    if (i + 3 < NH) stageA(i + 3);
    asm volatile("s_waitcnt lgkmcnt(4)" ::: "memory");
    __builtin_amdgcn_sched_barrier(0);
    __builtin_amdgcn_s_setprio(1);
#pragma unroll
    for (int m = 0; m < 2; ++m)
#pragma unroll
      for (int n = 0; n < 2; ++n)
        acc[m][n] = __builtin_amdgcn_mfma_f32_16x16x32_bf16(af_cur[m], bf_cur[n], acc[m][n], 0, 0, 0);
    __builtin_amdgcn_s_setprio(0);

    // sub1: read lo-A of H_{i+1}; MFMA hi half
#pragma unroll
    for (int m = 0; m < 2; ++m) af2[m] = *(const s16x8*)(pA1 + offA[m]);
    if (i + 3 < NH) stageB(i + 3);
    asm volatile("s_waitcnt lgkmcnt(2)" ::: "memory");
    __builtin_amdgcn_sched_barrier(0);
    __builtin_amdgcn_s_setprio(1);
#pragma unroll
    for (int m = 0; m < 2; ++m)
#pragma unroll
      for (int n = 0; n < 2; ++n)
        acc[m + 2][n] = __builtin_amdgcn_mfma_f32_16x16x32_bf16(af_nxt[m], bf_cur[n], acc[m + 2][n], 0, 0, 0);
    __builtin_amdgcn_s_setprio(0);

#pragma unroll
    for (int m = 0; m < 2; ++m) af_cur[m] = af2[m];
#pragma unroll
    for (int n = 0; n < 2; ++n) bf_cur[n] = bf_nxt[n];
  }

  // peeled last half-step
  {
    const char* pA = ldsA + (((NH - 1) & 3) << 13);
    asm volatile("s_waitcnt vmcnt(0)" ::: "memory");
    __builtin_amdgcn_s_barrier();
    __builtin_amdgcn_sched_barrier(0);
#pragma unroll
    for (int m = 0; m < 2; ++m) af_nxt[m] = *(const s16x8*)(pA + offA[m + 2]);
    asm volatile("s_waitcnt lgkmcnt(2)" ::: "memory");
    __builtin_amdgcn_sched_barrier(0);
    __builtin_amdgcn_s_setprio(1);
#pragma unroll
    for (int m = 0; m < 2; ++m)
#pragma unroll
      for (int n = 0; n < 2; ++n)
        acc[m][n] = __builtin_amdgcn_mfma_f32_16x16x32_bf16(af_cur[m], bf_cur[n], acc[m][n], 0, 0, 0);
    __builtin_amdgcn_s_setprio(0);
    asm volatile("s_waitcnt lgkmcnt(0)" ::: "memory");
    __builtin_amdgcn_sched_barrier(0);
    __builtin_amdgcn_s_setprio(1);
#pragma unroll
    for (int m = 0; m < 2; ++m)
#pragma unroll
      for (int n = 0; n < 2; ++n)
        acc[m + 2][n] = __builtin_amdgcn_mfma_f32_16x16x32_bf16(af_nxt[m], bf_cur[n], acc[m + 2][n], 0, 0, 0);
    __builtin_amdgcn_s_setprio(0);
  }

  // epilogue
  const int ecol0 = n0 + wc * 32 + lrow;
  float bz[2];
#pragma unroll
  for (int nf = 0; nf < 2; ++nf) bz[nf] = bias[ecol0 + nf * 16];
  const int erow0 = m0 + wr * 64 + (cg << 2);

#pragma unroll
  for (int mf = 0; mf < 4; ++mf) {
#pragma unroll
    for (int nf = 0; nf < 2; ++nf) {
#pragma unroll
      for (int r2 = 0; r2 < 4; ++r2) {
        const int row = erow0 + mf * 16 + r2;
        const size_t idx = (size_t)row * N + (ecol0 + nf * 16);
        const float v = acc[mf][nf][r2] + bz[nf];
        if constexpr (EPI == EPI_PLAIN) {
          out16[idx] = f2bf(v);
        } else if constexpr (EPI == EPI_FF1) {
          out16[idx] = f2bf(fmaxf(v, 0.f));
        } else {
          out32[idx] = v + bf2f(res16[idx]);
        }
      }
    }
  }
}

// ---------------------------------------------------------------------------
// 128x128 GEMM for fc1 (fused BN+ReLU epilogue), with compaction early-exit
// ---------------------------------------------------------------------------
__global__ __launch_bounds__(256)
void gemm_bt_h1(const short* __restrict__ A, const short* __restrict__ Bw,
                const float* __restrict__ bias,
                const float* __restrict__ bn_g, const float* __restrict__ bn_b,
                const float* __restrict__ bn_m, const float* __restrict__ bn_v,
                const int* __restrict__ hdr,
                short* __restrict__ out16, int M, int N, int K) {
  __shared__ short As[128 * 32];
  __shared__ short Bs[128 * 32];
  (void)M;
  const int m0 = blockIdx.y * 128;
  if (m0 >= hdr[1]) return;
  const int tid  = threadIdx.x;
  const int lane = tid & 63;
  const int wave = tid >> 6;
  const int n0 = blockIdx.x * 128;
  const int wm = (wave >> 1) * 64;
  const int wn = (wave & 1) * 64;
  const int lrow = lane & 15;
  const int lk8  = (lane >> 4) * 8;

  f32x4 acc[4][4] = {};

  const int srow = wave * 16 + (lane >> 2);
  const int scol = (lane & 3) * 8;
  const short* gA = A  + (size_t)(m0 + srow) * K + scol;
  const short* gB = Bw + (size_t)(n0 + srow) * K + scol;
  short* lA = &As[(wave * 16) * 32];
  short* lB = &Bs[(wave * 16) * 32];
  const size_t half = (size_t)64 * K;

  for (int k0 = 0; k0 < K; k0 += 32) {
    stage16(gA + k0,        lA);
    stage16(gA + half + k0, lA + 64 * 32);
    stage16(gB + k0,        lB);
    stage16(gB + half + k0, lB + 64 * 32);
    __syncthreads();
    s16x8 af[4], bfr[4];
#pragma unroll
    for (int m = 0; m < 4; ++m)
      af[m] = *(const s16x8*)&As[(wm + m * 16 + lrow) * 32 + lk8];
#pragma unroll
    for (int n = 0; n < 4; ++n)
      bfr[n] = *(const s16x8*)&Bs[(wn + n * 16 + lrow) * 32 + lk8];
#pragma unroll
    for (int m = 0; m < 4; ++m)
#pragma unroll
      for (int n = 0; n < 4; ++n)
        acc[m][n] = __builtin_amdgcn_mfma_f32_16x16x32_bf16(af[m], bfr[n], acc[m][n], 0, 0, 0);
    __syncthreads();
  }

  const int erow = m0 + wm + ((lane >> 4) << 2);
  const int ecol = n0 + wn + lrow;
  float sc[4], sh[4];
#pragma unroll
  for (int n = 0; n < 4; ++n) {
    const int c = ecol + n * 16;
    const float s = bn_g[c] * rsqrtf(bn_v[c] + BN_EPSF);
    sc[n] = s;
    sh[n] = (bias[c] - bn_m[c]) * s + bn_b[c];
  }
#pragma unroll
  for (int m = 0; m < 4; ++m)
#pragma unroll
    for (int n = 0; n < 4; ++n)
#pragma unroll
      for (int r = 0; r < 4; ++r) {
        const size_t idx = (size_t)(erow + m * 16 + r) * N + (ecol + n * 16);
        out16[idx] = f2bf(fmaxf(acc[m][n][r] * sc[n] + sh[n], 0.f));
      }
}

// ---------------------------------------------------------------------------
// top-2 mean per (b, d) over compacted bf16 emb rows
// ---------------------------------------------------------------------------
__global__ __launch_bounds__(256)
void topk_kernel(const short* __restrict__ emb16, const int* __restrict__ lens,
                 const int* __restrict__ cum, float* __restrict__ er) {
  const int b = blockIdx.x;
  const int len = lens[b];
  const size_t base = (size_t)cum[b] * 1024;
  const int tid = threadIdx.x;
#pragma unroll
  for (int j = 0; j < 4; ++j) {
    const int d = j * 256 + tid;
    float m1 = -3.0e38f, m2 = -3.0e38f;
    for (int l = 0; l < len; ++l) {
      const float v = bf2f(emb16[base + (size_t)l * 1024 + d]);
      if (v > m1) { m2 = m1; m1 = v; }
      else        { m2 = fmaxf(m2, v); }
    }
    er[(size_t)b * 1024 + d] = 0.5f * (m1 + m2);
  }
}

// ---------------------------------------------------------------------------
// Fused attention on compacted rows: one block per (b,h).
// ---------------------------------------------------------------------------
__global__ __launch_bounds__(256)
void attn_kernel(const short* __restrict__ qkv, const int* __restrict__ lens,
                 const int* __restrict__ cum, short* __restrict__ ctx) {
  __shared__ short Qs[64 * 128];
  __shared__ short Ks[64 * 128];
  __shared__ short Vt[128 * 64];
  const int tid  = threadIdx.x;
  const int lane = tid & 63;
  const int wave = tid >> 6;
  const int b = blockIdx.x >> 3;
  const int h = blockIdx.x & 7;
  const int len = lens[b];
  const int rb  = cum[b];
  const size_t qb = (size_t)rb * 3072 + h * 128;

  {
    const int rr = wave * 4 + (lane >> 4);
    const int cc = (lane & 15) * 8;
#pragma unroll
    for (int r = 0; r < 4; ++r) {
      stage16(qkv + qb +        (size_t)(r * 16 + rr) * 3072 + cc, &Qs[(r * 16 + wave * 4) * 128]);
      stage16(qkv + qb + 1024 + (size_t)(r * 16 + rr) * 3072 + cc, &Ks[(r * 16 + wave * 4) * 128]);
    }
  }
#pragma unroll
  for (int i = 0; i < 2; ++i) {
    const int c  = i * 256 + tid;
    const int lp = c >> 4;
    const int dg = c & 15;
    const short* src = qkv + qb + 2048 + (size_t)(2 * lp) * 3072 + dg * 8;
    s16x8 v0 = *(const s16x8*)src;
    s16x8 v1 = *(const s16x8*)(src + 3072);
    const bool ok0 = (2 * lp)     < len;
    const bool ok1 = (2 * lp + 1) < len;
#pragma unroll
    for (int j = 0; j < 8; ++j) {
      const uint32_t lo = ok0 ? (uint32_t)(uint16_t)v0[j] : 0u;
      const uint32_t hi = ok1 ? (uint32_t)(uint16_t)v1[j] : 0u;
      *(uint32_t*)&Vt[(dg * 8 + j) * 64 + 2 * lp] = lo | (hi << 16);
    }
  }
  __syncthreads();

  const int lrow = lane & 15;
  const int lk8  = (lane >> 4) * 8;

  f32x4 sacc[4] = {};
#pragma unroll
  for (int ks = 0; ks < 4; ++ks) {
    s16x8 aq = *(const s16x8*)&Qs[(wave * 16 + lrow) * 128 + ks * 32 + lk8];
#pragma unroll
    for (int n = 0; n < 4; ++n) {
      s16x8 bk = *(const s16x8*)&Ks[(n * 16 + lrow) * 128 + ks * 32 + lk8];
      sacc[n] = __builtin_amdgcn_mfma_f32_16x16x32_bf16(aq, bk, sacc[n], 0, 0, 0);
    }
  }

  const float scale = 0.08838834764831845f;
#pragma unroll
  for (int r = 0; r < 4; ++r) {
    float sv[4];
    float mx = -1e30f;
#pragma unroll
    for (int n = 0; n < 4; ++n) {
      float v = sacc[n][r] * scale;
      if (n * 16 + lrow >= len) v = -1e30f;
      sv[n] = v;
      mx = fmaxf(mx, v);
    }
    mx = fmaxf(mx, __shfl_xor(mx, 1));
    mx = fmaxf(mx, __shfl_xor(mx, 2));
    mx = fmaxf(mx, __shfl_xor(mx, 4));
    mx = fmaxf(mx, __shfl_xor(mx, 8));
    float pv[4], sum = 0.f;
#pragma unroll
    for (int n = 0; n < 4; ++n) { pv[n] = __expf(sv[n] - mx); sum += pv[n]; }
    sum += __shfl_xor(sum, 1);
    sum += __shfl_xor(sum, 2);
    sum += __shfl_xor(sum, 4);
    sum += __shfl_xor(sum, 8);
    const float inv = 1.f / sum;
    const int prow = wave * 16 + ((lane >> 4) << 2) + r;
#pragma unroll
    for (int n = 0; n < 4; ++n)
      Qs[prow * 128 + n * 16 + lrow] = f2bf(pv[n] * inv);
  }
  __syncthreads();

  f32x4 oacc[8] = {};
#pragma unroll
  for (int ks = 0; ks < 2; ++ks) {
    s16x8 ap = *(const s16x8*)&Qs[(wave * 16 + lrow) * 128 + ks * 32 + lk8];
#pragma unroll
    for (int n = 0; n < 8; ++n) {
      s16x8 bv = *(const s16x8*)&Vt[(n * 16 + lrow) * 64 + ks * 32 + lk8];
      oacc[n] = __builtin_amdgcn_mfma_f32_16x16x32_bf16(ap, bv, oacc[n], 0, 0, 0);
    }
  }
  const size_t ob = (size_t)rb * 1024 + h * 128;
#pragma unroll
  for (int n = 0; n < 8; ++n)
#pragma unroll
    for (int r = 0; r < 4; ++r) {
      const int row = wave * 16 + ((lane >> 4) << 2) + r;
      if (row < len)
        ctx[ob + (size_t)row * 1024 + n * 16 + lrow] = f2bf(oacc[n][r]);
    }
}

// ---------------------------------------------------------------------------
// LayerNorm over 1024 (LN1), one block per compacted row; writes bf16
// ---------------------------------------------------------------------------
__global__ __launch_bounds__(256)
void ln_kernel(const float* __restrict__ x, const float* __restrict__ gg,
               const float* __restrict__ bb, const int* __restrict__ hdr,
               short* __restrict__ y16) {
  if ((int)blockIdx.x >= hdr[1]) return;
  __shared__ float red[8];
  const int tid = threadIdx.x;
  const int lane = tid & 63;
  const int wave = tid >> 6;
  const size_t base = (size_t)blockIdx.x * 1024;
  float4 v = ((const float4*)(x + base))[tid];
  float s1 = v.x + v.y + v.z + v.w;
  float s2 = v.x * v.x + v.y * v.y + v.z * v.z + v.w * v.w;
#pragma unroll
  for (int o = 1; o < 64; o <<= 1) { s1 += __shfl_xor(s1, o); s2 += __shfl_xor(s2, o); }
  if (lane == 0) { red[wave] = s1; red[wave + 4] = s2; }
  __syncthreads();
  s1 = red[0] + red[1] + red[2] + red[3];
  s2 = red[4] + red[5] + red[6] + red[7];
  const float mu  = s1 * (1.f / 1024.f);
  const float var = fmaxf(s2 * (1.f / 1024.f) - mu * mu, 0.f);
  const float rs  = rsqrtf(var + LN_EPSF);
  float4 g4 = ((const float4*)gg)[tid];
  float4 b4 = ((const float4*)bb)[tid];
  s16x4 hh;
  hh[0] = f2bf((v.x - mu) * rs * g4.x + b4.x);
  hh[1] = f2bf((v.y - mu) * rs * g4.y + b4.y);
  hh[2] = f2bf((v.z - mu) * rs * g4.z + b4.z);
  hh[3] = f2bf((v.w - mu) * rs * g4.w + b4.w);
  ((s16x4*)(y16 + base))[tid] = hh;
}

// ---------------------------------------------------------------------------
// fused LN2 + avg-pool over compacted valid tokens + mix + L2 normalize
// ---------------------------------------------------------------------------
__global__ __launch_bounds__(256)
void ln2_final_kernel(const float* __restrict__ x, const float* __restrict__ gg,
                      const float* __restrict__ bb, const float* __restrict__ er,
                      const int* __restrict__ lens, const int* __restrict__ cum,
                      float* __restrict__ out) {
  __shared__ float part[4][1024];
  __shared__ float red[4];
  const int tid = threadIdx.x, lane = tid & 63, w = tid >> 6;
  const int b = blockIdx.x, len = lens[b];
  const size_t rb = (size_t)cum[b];
  float4 g4[4], b4[4];
#pragma unroll
  for (int k = 0; k < 4; ++k) {
    g4[k] = ((const float4*)gg)[k * 64 + lane];
    b4[k] = ((const float4*)bb)[k * 64 + lane];
  }
  float4 acc[4];
#pragma unroll
  for (int k = 0; k < 4; ++k) acc[k] = make_float4(0.f, 0.f, 0.f, 0.f);

  for (int l = w; l < len; l += 4) {
    const float4* row = (const float4*)(x + (rb + l) * 1024);
    float4 v[4]; float s1 = 0.f, s2 = 0.f;
#pragma unroll
    for (int k = 0; k < 4; ++k) {
      v[k] = row[k * 64 + lane];
      s1 += v[k].x + v[k].y + v[k].z + v[k].w;
      s2 += v[k].x * v[k].x + v[k].y * v[k].y + v[k].z * v[k].z + v[k].w * v[k].w;
    }
#pragma unroll
    for (int o = 1; o < 64; o <<= 1) { s1 += __shfl_xor(s1, o); s2 += __shfl_xor(s2, o); }
    const float mu = s1 * (1.f / 1024.f);
    const float rs = rsqrtf(fmaxf(s2 * (1.f / 1024.f) - mu * mu, 0.f) + LN_EPSF);
#pragma unroll
    for (int k = 0; k < 4; ++k) {
      acc[k].x += (v[k].x - mu) * rs * g4[k].x + b4[k].x;
      acc[k].y += (v[k].y - mu) * rs * g4[k].y + b4[k].y;
      acc[k].z += (v[k].z - mu) * rs * g4[k].z + b4[k].z;
      acc[k].w += (v[k].w - mu) * rs * g4[k].w + b4[k].w;
    }
  }
#pragma unroll
  for (int k = 0; k < 4; ++k)
    ((float4*)&part[w][0])[k * 64 + lane] = acc[k];
  __syncthreads();

  float4 s = ((const float4*)&part[0][0])[tid];
#pragma unroll
  for (int w2 = 1; w2 < 4; ++w2) {
    float4 t4 = ((const float4*)&part[0][0])[w2 * 256 + tid];
    s.x += t4.x; s.y += t4.y; s.z += t4.z; s.w += t4.w;
  }
  const float il = 0.5f / (float)len;
  float4 e = ((const float4*)(er + (size_t)b * 1024))[tid];
  const float o0 = 0.5f * e.x + s.x * il;
  const float o1 = 0.5f * e.y + s.y * il;
  const float o2 = 0.5f * e.z + s.z * il;
  const float o3 = 0.5f * e.w + s.w * il;
  float ss = o0 * o0 + o1 * o1 + o2 * o2 + o3 * o3;
#pragma unroll
  for (int o = 1; o < 64; o <<= 1) ss += __shfl_xor(ss, o);
  if (lane == 0) red[w] = ss;
  __syncthreads();
  ss = red[0] + red[1] + red[2] + red[3];
  const float nrm = 1.f / (sqrtf(ss) + 1e-8f);
  ((float4*)(out + (size_t)b * 1024))[tid] = make_float4(o0 * nrm, o1 * nrm, o2 * nrm, o3 * nrm);
}

// ---------------------------------------------------------------------------
extern "C" void kernel_launch(void* const* d_in, const int* in_sizes, int n_in,
                              void* d_out, int out_size, void* d_ws, size_t ws_size,
                              hipStream_t stream) {
  (void)in_sizes; (void)n_in; (void)out_size; (void)ws_size;
  const float* images = (const float*)d_in[0];
  const int*   lens   = (const int*)d_in[1];
  const float* fc1_w = (const float*)d_in[2];
  const float* fc1_b = (const float*)d_in[3];
  const float* bn_g  = (const float*)d_in[4];
  const float* bn_b  = (const float*)d_in[5];
  const float* bn_m  = (const float*)d_in[6];
  const float* bn_v  = (const float*)d_in[7];
  const float* fc2_w = (const float*)d_in[8];
  const float* fc2_b = (const float*)d_in[9];
  const float* in_w  = (const float*)d_in[10];
  const float* in_b  = (const float*)d_in[11];
  const float* out_w = (const float*)d_in[12];
  const float* out_b = (const float*)d_in[13];
  const float* ln1_g = (const float*)d_in[14];
  const float* ln1_b = (const float*)d_in[15];
  const float* ff1_w = (const float*)d_in[16];
  const float* ff1_b = (const float*)d_in[17];
  const float* ff2_w = (const float*)d_in[18];
  const float* ff2_b = (const float*)d_in[19];
  const float* ln2_g = (const float*)d_in[20];
  const float* ln2_b = (const float*)d_in[21];
  float* out = (float*)d_out;

  char* ws = (char*)d_ws;
  const size_t OFF_IMG16 = 0;                          // 67108864 (img16 / x1s / x2s)
  const size_t OFF_FC1W  = 67108864;                   // 2097152
  const size_t OFF_FC2W  = OFF_FC1W + 2097152;         // 1048576
  const size_t OFF_INW   = OFF_FC2W + 1048576;         // 6291456
  const size_t OFF_OUTW  = OFF_INW  + 6291456;         // 2097152
  const size_t OFF_FF1W  = OFF_OUTW + 2097152;         // 2097152
  const size_t OFF_FF2W  = OFF_FF1W + 2097152;         // 2097152
  const size_t OFF_H1    = OFF_FF2W + 2097152;         // 16777216
  const size_t OFF_EMB16 = OFF_H1 + 16777216;          // 33554432
  const size_t OFF_QKV   = OFF_EMB16 + 33554432;       // 101056512 (16448 rows)
  const size_t OFF_CTX   = OFF_QKV + 101056512;        // 33554432
  const size_t OFF_ERES  = OFF_CTX + 33554432;         // 1048576
  const size_t OFF_HDR   = OFF_ERES + 1048576;         // 256
  const size_t OFF_CUM   = OFF_HDR + 256;              // 1024
  const size_t OFF_TOK   = OFF_CUM + 1024;             // 65536

  short* img16  = (short*)(ws + OFF_IMG16);
  short* fc1w16 = (short*)(ws + OFF_FC1W);
  short* fc2w16 = (short*)(ws + OFF_FC2W);
  short* inw16  = (short*)(ws + OFF_INW);
  short* outw16 = (short*)(ws + OFF_OUTW);
  short* ff1w16 = (short*)(ws + OFF_FF1W);
  short* ff2w16 = (short*)(ws + OFF_FF2W);
  short* h1     = (short*)(ws + OFF_H1);
  short* emb16  = (short*)(ws + OFF_EMB16);
  short* qkv16  = (short*)(ws + OFF_QKV);
  short* ctx16  = (short*)(ws + OFF_CTX);
  float* embres = (float*)(ws + OFF_ERES);
  int*   hdr    = (int*)(ws + OFF_HDR);
  int*   cum    = (int*)(ws + OFF_CUM);
  int*   tokmap = (int*)(ws + OFF_TOK);
  float* x1s = (float*)(ws + OFF_IMG16);   // pre-LN1 f32  (img16 dead)
  short* x1h = emb16;                      // post-LN1 bf16 (emb16 dead after out-proj)
  short* ffh = ctx16;                      // ffn hidden    (ctx16 dead)
  float* x2s = (float*)(ws + OFF_IMG16);   // pre-LN2 f32   (x1s dead)

  const dim3 blk(256);
  const size_t SMEM256 = 131072;
  const size_t SMEM128 = 65536;

  // compaction metadata (prefix + tokmap fused)
  prefix_kernel<<<1, blk, 0, stream>>>(lens, cum, hdr, tokmap);

  // converts: gathered images + all six weights in one kernel
  CvtArgs ca;
  ca.src[0] = fc1_w; ca.dst[0] = fc1w16; ca.n4[0] = 1048576 / 4;
  ca.src[1] = fc2_w; ca.dst[1] = fc2w16; ca.n4[1] = 524288 / 4;
  ca.src[2] = in_w;  ca.dst[2] = inw16;  ca.n4[2] = 3145728 / 4;
  ca.src[3] = out_w; ca.dst[3] = outw16; ca.n4[3] = 1048576 / 4;
  ca.src[4] = ff1_w; ca.dst[4] = ff1w16; ca.n4[4] = 1048576 / 4;
  ca.src[5] = ff2_w; ca.dst[5] = ff2w16; ca.n4[5] = 1048576 / 4;
  cvt_gather_kernel<<<2048, blk, 0, stream>>>(images, tokmap, hdr, img16, ca);

  // fc1 + BN + ReLU -> h1 (bf16, compacted)
  gemm_bt_h1<<<dim3(4, 128), blk, 0, stream>>>(
      img16, fc1w16, fc1_b, bn_g, bn_b, bn_m, bn_v, hdr, h1, 16384, 512, 2048);
  // fc2 -> emb16 (compacted)  [128x128 pipelined, 2 blocks/CU]
  gemm128p<EPI_PLAIN><<<dim3(8, 128), 512, SMEM128, stream>>>(
      h1, fc2w16, fc2_b, nullptr, hdr, nullptr, emb16, 1024, 512);
  // top-2 pooling over compacted emb
  topk_kernel<<<256, blk, 0, stream>>>(emb16, lens, cum, embres);
  // qkv projection (256x256 pipelined)
  gemm256<EPI_PLAIN><<<dim3(12, 64), 512, SMEM256, stream>>>(
      emb16, inw16, in_b, nullptr, hdr, nullptr, qkv16, 16384, 3072, 1024);
  // attention (compacted rows)
  attn_kernel<<<2048, blk, 0, stream>>>(qkv16, lens, cum, ctx16);
  // out projection + residual(emb16) -> pre-LN1 f32
  gemm128p<EPI_RES><<<dim3(8, 128), 512, SMEM128, stream>>>(
      ctx16, outw16, out_b, emb16, hdr, x1s, nullptr, 1024, 1024);
  ln_kernel<<<16384, blk, 0, stream>>>(x1s, ln1_g, ln1_b, hdr, x1h);
  // ffn
  gemm128p<EPI_FF1><<<dim3(8, 128), 512, SMEM128, stream>>>(
      x1h, ff1w16, ff1_b, nullptr, hdr, nullptr, ffh, 1024, 1024);
  gemm128p<EPI_RES><<<dim3(8, 128), 512, SMEM128, stream>>>(
      ffh, ff2w16, ff2_b, x1h, hdr, x2s, nullptr, 1024, 1024);
  // fused LN2 + avg-pool + mix + normalize
  ln2_final_kernel<<<256, blk, 0, stream>>>(x2s, ln2_g, ln2_b, embres, lens, cum, out);
}

// Round 10
// 378.659 us; speedup vs baseline: 1.1795x; 1.0518x over previous
//
#include <hip/hip_runtime.h>
#include <stdint.h>
#include <stddef.h>

// ---------------------------------------------------------------------------
// EncoderImageAggr: bf16-MFMA pipeline for MI355X (gfx950)
// B=256 L=64 IMG_DIM=2048 D=1024 H=8 DH=128. All GEMMs are C = A @ W^T.
// Round 10: fc1 moved onto the pipelined gemm128p (EPI_H1 = fused BN+ReLU);
// pre-LN sums stored bf16 (EPI_RES writes bf16, LN1/LN2-final read bf16).
// ---------------------------------------------------------------------------

typedef short s16x8 __attribute__((ext_vector_type(8)));
typedef short s16x4 __attribute__((ext_vector_type(4)));
typedef float f32x4 __attribute__((ext_vector_type(4)));

#define LN_EPSF 1e-5f
#define BN_EPSF 1e-5f

__device__ __forceinline__ short f2bf(float f) {
  union { float f; uint32_t u; } x; x.f = f;
  uint32_t r = x.u + 0x7fffu + ((x.u >> 16) & 1u);   // RNE
  return (short)(r >> 16);
}
__device__ __forceinline__ float bf2f(short s) {
  union { uint32_t u; float f; } x; x.u = ((uint32_t)(uint16_t)s) << 16;
  return x.f;
}

typedef const __attribute__((address_space(1))) short glb_s16_t;
typedef __attribute__((address_space(3))) short lds_s16_t;

__device__ __forceinline__ void stage16(const short* g, short* l) {
  __builtin_amdgcn_global_load_lds((glb_s16_t*)g, (lds_s16_t*)l, 16, 0, 0);
}

// involution swizzle for 64B-row LDS slots (measured 0 bank conflicts)
__device__ __forceinline__ int swz(int off) {
  return off ^ (((off >> 7) & 3) << 4);
}

enum { EPI_PLAIN = 0, EPI_FF1 = 3, EPI_RES = 4, EPI_H1 = 5 };

// ---------------------------------------------------------------------------
// prefix-sum of lens -> cum (exclusive), hdr = {Mc, Mc_pad}; build tokmap
// ---------------------------------------------------------------------------
__global__ __launch_bounds__(256)
void prefix_kernel(const int* __restrict__ lens, int* __restrict__ cum,
                   int* __restrict__ hdr, int* __restrict__ tokmap) {
  __shared__ int wsum[4];
  __shared__ int sc[256];
  __shared__ int mcpad;
  const int tid = threadIdx.x, lane = tid & 63, wave = tid >> 6;
  const int mylen = lens[tid];
  int v = mylen;
#pragma unroll
  for (int o = 1; o < 64; o <<= 1) {
    int t = __shfl_up(v, o);
    if (lane >= o) v += t;
  }
  if (lane == 63) wsum[wave] = v;
  __syncthreads();
  int add = 0;
#pragma unroll
  for (int w2 = 0; w2 < 4; ++w2) if (w2 < wave) add += wsum[w2];
  const int incl = v + add;
  const int excl = incl - mylen;
  cum[tid] = excl;
  sc[tid] = excl;
  if (tid == 255) {
    hdr[0] = incl;                       // Mc
    mcpad  = (incl + 255) & ~255;        // Mc_pad (multiple of 256)
    hdr[1] = mcpad;
  }
  __syncthreads();
  for (int l = 0; l < mylen; ++l) tokmap[excl + l] = tid * 64 + l;
  const int mc = sc[255] + lens[255];
  for (int i = mc + tid; i < mcpad; i += 256) tokmap[i] = 0;
}

// ---------------------------------------------------------------------------
// gathered fp32 -> bf16 convert of valid image rows (compacted) + weights
// ---------------------------------------------------------------------------
struct CvtArgs { const float* src[6]; short* dst[6]; int n4[6]; };

__global__ __launch_bounds__(256)
void cvt_gather_kernel(const float* __restrict__ img,
                       const int* __restrict__ tokmap,
                       const int* __restrict__ hdr, short* __restrict__ out,
                       CvtArgs a) {
  const int n4 = hdr[1] << 9;                    // Mc_pad * 512 float4s
  const int stride = gridDim.x * 256;
  for (int i = blockIdx.x * 256 + threadIdx.x; i < n4; i += stride) {
    const int row = i >> 9, col = i & 511;
    float4 v = ((const float4*)img)[(size_t)tokmap[row] * 512 + col];
    s16x4 h; h[0] = f2bf(v.x); h[1] = f2bf(v.y); h[2] = f2bf(v.z); h[3] = f2bf(v.w);
    ((s16x4*)out)[i] = h;
  }
#pragma unroll
  for (int s = 0; s < 6; ++s) {
    const int n = a.n4[s];
    const float4* in = (const float4*)a.src[s];
    s16x4* outp = (s16x4*)a.dst[s];
    for (int i = blockIdx.x * 256 + threadIdx.x; i < n; i += stride) {
      float4 v = in[i];
      s16x4 h; h[0] = f2bf(v.x); h[1] = f2bf(v.y); h[2] = f2bf(v.z); h[3] = f2bf(v.w);
      outp[i] = h;
    }
  }
}

// ---------------------------------------------------------------------------
// 256x256 pipelined GEMM — qkv only. 512 thr, 8 waves (2Mx4N), per-wave
// 128x64. Ring-4 half-slots [256][32]; counted vmcnt(4); chunked XCD swizzle.
// ---------------------------------------------------------------------------
template<int EPI>
__global__ __launch_bounds__(512, 2)
void gemm256(const short* __restrict__ A, const short* __restrict__ Bw,
             const float* __restrict__ bias, const int* __restrict__ hdr,
             short* __restrict__ out16, int N, int K) {
  extern __shared__ char smem[];                 // 131072 B
  const int tid  = threadIdx.x;
  const int lane = tid & 63;
  const int w    = tid >> 6;
  const int wr   = w >> 2;
  const int wc   = w & 3;
  const int lrow = lane & 15;
  const int cg   = lane >> 4;
  const int NH   = K >> 5;
  const int gx   = gridDim.x;

  const int p = blockIdx.y * gx + blockIdx.x;
  const int nwork = (hdr[1] >> 8) * gx;
  if (p >= nwork) return;
  const int xcd = p & 7, off = p >> 3;
  const int q = nwork >> 3, r = nwork & 7;
  const int wg = (xcd < r ? xcd * (q + 1) : r * (q + 1) + (xcd - r) * q) + off;
  const int m0 = (wg / gx) * 256;
  const int n0 = (wg % gx) * 256;

  const int ldb = K * 2;
  size_t gA[2], gB[2];
#pragma unroll
  for (int j = 0; j < 2; ++j) {
    const int pp = tid * 16 + j * 8192;
    const int l = swz(pp);
    const int row = l >> 6, colb = l & 63;
    gA[j] = (size_t)(m0 + row) * ldb + colb;
    gB[j] = (size_t)(n0 + row) * ldb + colb;
  }
  const char* Ab = (const char*)A;
  const char* Bb = (const char*)Bw;
  char* ldsA = smem;
  char* ldsB = smem + 65536;
  const int wofs = w * 1024;

  auto stageApart = [&](int i) {
    const int rg = ((i & 3) << 14) + wofs;
    const int ko = i * 64;
    stage16((const short*)(Ab + gA[0] + ko), (short*)(ldsA + rg));
    stage16((const short*)(Ab + gA[1] + ko), (short*)(ldsA + rg + 8192));
  };
  auto stageBpart = [&](int i) {
    const int rg = ((i & 3) << 14) + wofs;
    const int ko = i * 64;
    stage16((const short*)(Bb + gB[0] + ko), (short*)(ldsB + rg));
    stage16((const short*)(Bb + gB[1] + ko), (short*)(ldsB + rg + 8192));
  };

  int offA[8], offB[4];
#pragma unroll
  for (int mf = 0; mf < 8; ++mf)
    offA[mf] = swz((wr * 128 + mf * 16 + lrow) * 64 + cg * 16);
#pragma unroll
  for (int nf = 0; nf < 4; ++nf)
    offB[nf] = swz((wc * 64 + nf * 16 + lrow) * 64 + cg * 16);

  f32x4 acc[8][4] = {};

  stageApart(0); stageBpart(0);
  stageApart(1); stageBpart(1);
  stageApart(2); stageBpart(2);
  asm volatile("s_waitcnt vmcnt(8)" ::: "memory");
  __builtin_amdgcn_s_barrier();
  __builtin_amdgcn_sched_barrier(0);
  s16x8 af_cur[4], bf_cur[4], af_nxt[4], bf_nxt[4], af2[4];
#pragma unroll
  for (int m = 0; m < 4; ++m) af_cur[m] = *(const s16x8*)(ldsA + offA[m]);
#pragma unroll
  for (int n = 0; n < 4; ++n) bf_cur[n] = *(const s16x8*)(ldsB + offB[n]);

  for (int i = 0; i < NH - 1; ++i) {
    const int si  = i & 3;
    const int si1 = (i + 1) & 3;
    const char* pA  = ldsA + (si  << 14);
    const char* pA1 = ldsA + (si1 << 14);
    const char* pB1 = ldsB + (si1 << 14);

    if (i + 2 < NH) { asm volatile("s_waitcnt vmcnt(4)" ::: "memory"); }
    else            { asm volatile("s_waitcnt vmcnt(0)" ::: "memory"); }
    __builtin_amdgcn_s_barrier();
    __builtin_amdgcn_sched_barrier(0);

#pragma unroll
    for (int m = 0; m < 4; ++m) af_nxt[m] = *(const s16x8*)(pA + offA[m + 4]);
#pragma unroll
    for (int n = 0; n < 4; ++n) bf_nxt[n] = *(const s16x8*)(pB1 + offB[n]);
    if (i + 3 < NH) stageApart(i + 3);
    asm volatile("s_waitcnt lgkmcnt(8)" ::: "memory");
    __builtin_amdgcn_sched_barrier(0);
    __builtin_amdgcn_s_setprio(1);
#pragma unroll
    for (int m = 0; m < 4; ++m)
#pragma unroll
      for (int n = 0; n < 4; ++n)
        acc[m][n] = __builtin_amdgcn_mfma_f32_16x16x32_bf16(af_cur[m], bf_cur[n], acc[m][n], 0, 0, 0);
    __builtin_amdgcn_s_setprio(0);

#pragma unroll
    for (int m = 0; m < 4; ++m) af2[m] = *(const s16x8*)(pA1 + offA[m]);
    if (i + 3 < NH) stageBpart(i + 3);
    asm volatile("s_waitcnt lgkmcnt(4)" ::: "memory");
    __builtin_amdgcn_sched_barrier(0);
    __builtin_amdgcn_s_setprio(1);
#pragma unroll
    for (int m = 0; m < 4; ++m)
#pragma unroll
      for (int n = 0; n < 4; ++n)
        acc[m + 4][n] = __builtin_amdgcn_mfma_f32_16x16x32_bf16(af_nxt[m], bf_cur[n], acc[m + 4][n], 0, 0, 0);
    __builtin_amdgcn_s_setprio(0);

#pragma unroll
    for (int m = 0; m < 4; ++m) af_cur[m] = af2[m];
#pragma unroll
    for (int n = 0; n < 4; ++n) bf_cur[n] = bf_nxt[n];
  }

  {
    const char* pA = ldsA + (((NH - 1) & 3) << 14);
    asm volatile("s_waitcnt vmcnt(0)" ::: "memory");
    __builtin_amdgcn_s_barrier();
    __builtin_amdgcn_sched_barrier(0);
#pragma unroll
    for (int m = 0; m < 4; ++m) af_nxt[m] = *(const s16x8*)(pA + offA[m + 4]);
    asm volatile("s_waitcnt lgkmcnt(4)" ::: "memory");
    __builtin_amdgcn_sched_barrier(0);
    __builtin_amdgcn_s_setprio(1);
#pragma unroll
    for (int m = 0; m < 4; ++m)
#pragma unroll
      for (int n = 0; n < 4; ++n)
        acc[m][n] = __builtin_amdgcn_mfma_f32_16x16x32_bf16(af_cur[m], bf_cur[n], acc[m][n], 0, 0, 0);
    __builtin_amdgcn_s_setprio(0);
    asm volatile("s_waitcnt lgkmcnt(0)" ::: "memory");
    __builtin_amdgcn_sched_barrier(0);
    __builtin_amdgcn_s_setprio(1);
#pragma unroll
    for (int m = 0; m < 4; ++m)
#pragma unroll
      for (int n = 0; n < 4; ++n)
        acc[m + 4][n] = __builtin_amdgcn_mfma_f32_16x16x32_bf16(af_nxt[m], bf_cur[n], acc[m + 4][n], 0, 0, 0);
    __builtin_amdgcn_s_setprio(0);
  }

  const int ecol0 = n0 + wc * 64 + lrow;
  float bz[4];
#pragma unroll
  for (int nf = 0; nf < 4; ++nf) bz[nf] = bias[ecol0 + nf * 16];
  const int erow0 = m0 + wr * 128 + (cg << 2);

#pragma unroll
  for (int mf = 0; mf < 8; ++mf)
#pragma unroll
    for (int nf = 0; nf < 4; ++nf)
#pragma unroll
      for (int r2 = 0; r2 < 4; ++r2) {
        const int row = erow0 + mf * 16 + r2;
        const size_t idx = (size_t)row * N + (ecol0 + nf * 16);
        out16[idx] = f2bf(acc[mf][nf][r2] + bz[nf]);
      }
}

// ---------------------------------------------------------------------------
// 128x128 PIPELINED GEMM (uniform shrink of gemm256's schedule).
// 512 thr, 8 waves (2Mx4N), per-wave 64x32 (acc[4][2]). Ring-4 half-slots
// [128][32] bf16 (8KB)/matrix -> 64KB LDS -> 2 blocks/CU.
// Epilogues: PLAIN / FF1(ReLU) / RES(+bf16 residual -> bf16) / H1(BN+ReLU).
// ---------------------------------------------------------------------------
template<int EPI>
__global__ __launch_bounds__(512, 4)
void gemm128p(const short* __restrict__ A, const short* __restrict__ Bw,
              const float* __restrict__ bias, const short* __restrict__ res16,
              const float* __restrict__ bnG, const float* __restrict__ bnB,
              const float* __restrict__ bnM, const float* __restrict__ bnV,
              const int* __restrict__ hdr, short* __restrict__ out16,
              int N, int K) {
  extern __shared__ char smem[];                 // 65536 B
  const int tid  = threadIdx.x;
  const int lane = tid & 63;
  const int w    = tid >> 6;
  const int wr   = w >> 2;
  const int wc   = w & 3;
  const int lrow = lane & 15;
  const int cg   = lane >> 4;
  const int NH   = K >> 5;
  const int gx   = gridDim.x;

  const int p = blockIdx.y * gx + blockIdx.x;
  const int nwork = (hdr[1] >> 7) * gx;
  if (p >= nwork) return;
  const int xcd = p & 7, off = p >> 3;
  const int q = nwork >> 3, r = nwork & 7;
  const int wg = (xcd < r ? xcd * (q + 1) : r * (q + 1) + (xcd - r) * q) + off;
  const int m0 = (wg / gx) * 128;
  const int n0 = (wg % gx) * 128;

  const int ldb = K * 2;
  size_t gA, gB;
  {
    const int pp = tid * 16;
    const int l = swz(pp);
    const int row = l >> 6, colb = l & 63;
    gA = (size_t)(m0 + row) * ldb + colb;
    gB = (size_t)(n0 + row) * ldb + colb;
  }
  const char* Ab = (const char*)A;
  const char* Bb = (const char*)Bw;
  char* ldsA = smem;                             // 4 x 8KB
  char* ldsB = smem + 32768;                     // 4 x 8KB
  const int wofs = w * 1024;

  auto stageA = [&](int i) {
    stage16((const short*)(Ab + gA + i * 64), (short*)(ldsA + ((i & 3) << 13) + wofs));
  };
  auto stageB = [&](int i) {
    stage16((const short*)(Bb + gB + i * 64), (short*)(ldsB + ((i & 3) << 13) + wofs));
  };

  int offA[4], offB[2];
#pragma unroll
  for (int mf = 0; mf < 4; ++mf)
    offA[mf] = swz((wr * 64 + mf * 16 + lrow) * 64 + cg * 16);
#pragma unroll
  for (int nf = 0; nf < 2; ++nf)
    offB[nf] = swz((wc * 32 + nf * 16 + lrow) * 64 + cg * 16);

  f32x4 acc[4][2] = {};

  stageA(0); stageB(0);
  stageA(1); stageB(1);
  stageA(2); stageB(2);
  asm volatile("s_waitcnt vmcnt(4)" ::: "memory");
  __builtin_amdgcn_s_barrier();
  __builtin_amdgcn_sched_barrier(0);
  s16x8 af_cur[2], bf_cur[2], af_nxt[2], bf_nxt[2], af2[2];
#pragma unroll
  for (int m = 0; m < 2; ++m) af_cur[m] = *(const s16x8*)(ldsA + offA[m]);
#pragma unroll
  for (int n = 0; n < 2; ++n) bf_cur[n] = *(const s16x8*)(ldsB + offB[n]);

  for (int i = 0; i < NH - 1; ++i) {
    const char* pA  = ldsA + ((i & 3) << 13);
    const char* pA1 = ldsA + (((i + 1) & 3) << 13);
    const char* pB1 = ldsB + (((i + 1) & 3) << 13);

    if (i + 2 < NH) { asm volatile("s_waitcnt vmcnt(2)" ::: "memory"); }
    else            { asm volatile("s_waitcnt vmcnt(0)" ::: "memory"); }
    __builtin_amdgcn_s_barrier();
    __builtin_amdgcn_sched_barrier(0);

#pragma unroll
    for (int m = 0; m < 2; ++m) af_nxt[m] = *(const s16x8*)(pA + offA[m + 2]);
#pragma unroll
    for (int n = 0; n < 2; ++n) bf_nxt[n] = *(const s16x8*)(pB1 + offB[n]);
    if (i + 3 < NH) stageA(i + 3);
    asm volatile("s_waitcnt lgkmcnt(4)" ::: "memory");
    __builtin_amdgcn_sched_barrier(0);
    __builtin_amdgcn_s_setprio(1);
#pragma unroll
    for (int m = 0; m < 2; ++m)
#pragma unroll
      for (int n = 0; n < 2; ++n)
        acc[m][n] = __builtin_amdgcn_mfma_f32_16x16x32_bf16(af_cur[m], bf_cur[n], acc[m][n], 0, 0, 0);
    __builtin_amdgcn_s_setprio(0);

#pragma unroll
    for (int m = 0; m < 2; ++m) af2[m] = *(const s16x8*)(pA1 + offA[m]);
    if (i + 3 < NH) stageB(i + 3);
    asm volatile("s_waitcnt lgkmcnt(2)" ::: "memory");
    __builtin_amdgcn_sched_barrier(0);
    __builtin_amdgcn_s_setprio(1);
#pragma unroll
    for (int m = 0; m < 2; ++m)
#pragma unroll
      for (int n = 0; n < 2; ++n)
        acc[m + 2][n] = __builtin_amdgcn_mfma_f32_16x16x32_bf16(af_nxt[m], bf_cur[n], acc[m + 2][n], 0, 0, 0);
    __builtin_amdgcn_s_setprio(0);

#pragma unroll
    for (int m = 0; m < 2; ++m) af_cur[m] = af2[m];
#pragma unroll
    for (int n = 0; n < 2; ++n) bf_cur[n] = bf_nxt[n];
  }

  {
    const char* pA = ldsA + (((NH - 1) & 3) << 13);
    asm volatile("s_waitcnt vmcnt(0)" ::: "memory");
    __builtin_amdgcn_s_barrier();
    __builtin_amdgcn_sched_barrier(0);
#pragma unroll
    for (int m = 0; m < 2; ++m) af_nxt[m] = *(const s16x8*)(pA + offA[m + 2]);
    asm volatile("s_waitcnt lgkmcnt(2)" ::: "memory");
    __builtin_amdgcn_sched_barrier(0);
    __builtin_amdgcn_s_setprio(1);
#pragma unroll
    for (int m = 0; m < 2; ++m)
#pragma unroll
      for (int n = 0; n < 2; ++n)
        acc[m][n] = __builtin_amdgcn_mfma_f32_16x16x32_bf16(af_cur[m], bf_cur[n], acc[m][n], 0, 0, 0);
    __builtin_amdgcn_s_setprio(0);
    asm volatile("s_waitcnt lgkmcnt(0)" ::: "memory");
    __builtin_amdgcn_sched_barrier(0);
    __builtin_amdgcn_s_setprio(1);
#pragma unroll
    for (int m = 0; m < 2; ++m)
#pragma unroll
      for (int n = 0; n < 2; ++n)
        acc[m + 2][n] = __builtin_amdgcn_mfma_f32_16x16x32_bf16(af_nxt[m], bf_cur[n], acc[m + 2][n], 0, 0, 0);
    __builtin_amdgcn_s_setprio(0);
  }

  // epilogue
  const int ecol0 = n0 + wc * 32 + lrow;
  const int erow0 = m0 + wr * 64 + (cg << 2);
  float bz[2], sc[2], sh[2];
#pragma unroll
  for (int nf = 0; nf < 2; ++nf) {
    const int c = ecol0 + nf * 16;
    if constexpr (EPI == EPI_H1) {
      const float s = bnG[c] * rsqrtf(bnV[c] + BN_EPSF);
      sc[nf] = s;
      sh[nf] = (bias[c] - bnM[c]) * s + bnB[c];
    } else {
      bz[nf] = bias[c];
    }
  }
  (void)bnG; (void)bnB; (void)bnM; (void)bnV;

#pragma unroll
  for (int mf = 0; mf < 4; ++mf) {
#pragma unroll
    for (int nf = 0; nf < 2; ++nf) {
#pragma unroll
      for (int r2 = 0; r2 < 4; ++r2) {
        const int row = erow0 + mf * 16 + r2;
        const size_t idx = (size_t)row * N + (ecol0 + nf * 16);
        if constexpr (EPI == EPI_H1) {
          out16[idx] = f2bf(fmaxf(acc[mf][nf][r2] * sc[nf] + sh[nf], 0.f));
        } else {
          const float v = acc[mf][nf][r2] + bz[nf];
          if constexpr (EPI == EPI_PLAIN) {
            out16[idx] = f2bf(v);
          } else if constexpr (EPI == EPI_FF1) {
            out16[idx] = f2bf(fmaxf(v, 0.f));
          } else {  // EPI_RES: bf16 out = v + bf16 residual
            out16[idx] = f2bf(v + bf2f(res16[idx]));
          }
        }
      }
    }
  }
}

// ---------------------------------------------------------------------------
// top-2 mean per (b, d) over compacted bf16 emb rows
// ---------------------------------------------------------------------------
__global__ __launch_bounds__(256)
void topk_kernel(const short* __restrict__ emb16, const int* __restrict__ lens,
                 const int* __restrict__ cum, float* __restrict__ er) {
  const int b = blockIdx.x;
  const int len = lens[b];
  const size_t base = (size_t)cum[b] * 1024;
  const int tid = threadIdx.x;
#pragma unroll
  for (int j = 0; j < 4; ++j) {
    const int d = j * 256 + tid;
    float m1 = -3.0e38f, m2 = -3.0e38f;
    for (int l = 0; l < len; ++l) {
      const float v = bf2f(emb16[base + (size_t)l * 1024 + d]);
      if (v > m1) { m2 = m1; m1 = v; }
      else        { m2 = fmaxf(m2, v); }
    }
    er[(size_t)b * 1024 + d] = 0.5f * (m1 + m2);
  }
}

// ---------------------------------------------------------------------------
// Fused attention on compacted rows: one block per (b,h).
// ---------------------------------------------------------------------------
__global__ __launch_bounds__(256)
void attn_kernel(const short* __restrict__ qkv, const int* __restrict__ lens,
                 const int* __restrict__ cum, short* __restrict__ ctx) {
  __shared__ short Qs[64 * 128];
  __shared__ short Ks[64 * 128];
  __shared__ short Vt[128 * 64];
  const int tid  = threadIdx.x;
  const int lane = tid & 63;
  const int wave = tid >> 6;
  const int b = blockIdx.x >> 3;
  const int h = blockIdx.x & 7;
  const int len = lens[b];
  const int rb  = cum[b];
  const size_t qb = (size_t)rb * 3072 + h * 128;

  {
    const int rr = wave * 4 + (lane >> 4);
    const int cc = (lane & 15) * 8;
#pragma unroll
    for (int r = 0; r < 4; ++r) {
      stage16(qkv + qb +        (size_t)(r * 16 + rr) * 3072 + cc, &Qs[(r * 16 + wave * 4) * 128]);
      stage16(qkv + qb + 1024 + (size_t)(r * 16 + rr) * 3072 + cc, &Ks[(r * 16 + wave * 4) * 128]);
    }
  }
#pragma unroll
  for (int i = 0; i < 2; ++i) {
    const int c  = i * 256 + tid;
    const int lp = c >> 4;
    const int dg = c & 15;
    const short* src = qkv + qb + 2048 + (size_t)(2 * lp) * 3072 + dg * 8;
    s16x8 v0 = *(const s16x8*)src;
    s16x8 v1 = *(const s16x8*)(src + 3072);
    const bool ok0 = (2 * lp)     < len;
    const bool ok1 = (2 * lp + 1) < len;
#pragma unroll
    for (int j = 0; j < 8; ++j) {
      const uint32_t lo = ok0 ? (uint32_t)(uint16_t)v0[j] : 0u;
      const uint32_t hi = ok1 ? (uint32_t)(uint16_t)v1[j] : 0u;
      *(uint32_t*)&Vt[(dg * 8 + j) * 64 + 2 * lp] = lo | (hi << 16);
    }
  }
  __syncthreads();

  const int lrow = lane & 15;
  const int lk8  = (lane >> 4) * 8;

  f32x4 sacc[4] = {};
#pragma unroll
  for (int ks = 0; ks < 4; ++ks) {
    s16x8 aq = *(const s16x8*)&Qs[(wave * 16 + lrow) * 128 + ks * 32 + lk8];
#pragma unroll
    for (int n = 0; n < 4; ++n) {
      s16x8 bk = *(const s16x8*)&Ks[(n * 16 + lrow) * 128 + ks * 32 + lk8];
      sacc[n] = __builtin_amdgcn_mfma_f32_16x16x32_bf16(aq, bk, sacc[n], 0, 0, 0);
    }
  }

  const float scale = 0.08838834764831845f;
#pragma unroll
  for (int r = 0; r < 4; ++r) {
    float sv[4];
    float mx = -1e30f;
#pragma unroll
    for (int n = 0; n < 4; ++n) {
      float v = sacc[n][r] * scale;
      if (n * 16 + lrow >= len) v = -1e30f;
      sv[n] = v;
      mx = fmaxf(mx, v);
    }
    mx = fmaxf(mx, __shfl_xor(mx, 1));
    mx = fmaxf(mx, __shfl_xor(mx, 2));
    mx = fmaxf(mx, __shfl_xor(mx, 4));
    mx = fmaxf(mx, __shfl_xor(mx, 8));
    float pv[4], sum = 0.f;
#pragma unroll
    for (int n = 0; n < 4; ++n) { pv[n] = __expf(sv[n] - mx); sum += pv[n]; }
    sum += __shfl_xor(sum, 1);
    sum += __shfl_xor(sum, 2);
    sum += __shfl_xor(sum, 4);
    sum += __shfl_xor(sum, 8);
    const float inv = 1.f / sum;
    const int prow = wave * 16 + ((lane >> 4) << 2) + r;
#pragma unroll
    for (int n = 0; n < 4; ++n)
      Qs[prow * 128 + n * 16 + lrow] = f2bf(pv[n] * inv);
  }
  __syncthreads();

  f32x4 oacc[8] = {};
#pragma unroll
  for (int ks = 0; ks < 2; ++ks) {
    s16x8 ap = *(const s16x8*)&Qs[(wave * 16 + lrow) * 128 + ks * 32 + lk8];
#pragma unroll
    for (int n = 0; n < 8; ++n) {
      s16x8 bv = *(const s16x8*)&Vt[(n * 16 + lrow) * 64 + ks * 32 + lk8];
      oacc[n] = __builtin_amdgcn_mfma_f32_16x16x32_bf16(ap, bv, oacc[n], 0, 0, 0);
    }
  }
  const size_t ob = (size_t)rb * 1024 + h * 128;
#pragma unroll
  for (int n = 0; n < 8; ++n)
#pragma unroll
    for (int r = 0; r < 4; ++r) {
      const int row = wave * 16 + ((lane >> 4) << 2) + r;
      if (row < len)
        ctx[ob + (size_t)row * 1024 + n * 16 + lrow] = f2bf(oacc[n][r]);
    }
}

// ---------------------------------------------------------------------------
// LayerNorm over 1024 (LN1): bf16 in, bf16 out; one block per compacted row
// ---------------------------------------------------------------------------
__global__ __launch_bounds__(256)
void ln_kernel(const short* __restrict__ x16, const float* __restrict__ gg,
               const float* __restrict__ bb, const int* __restrict__ hdr,
               short* __restrict__ y16) {
  if ((int)blockIdx.x >= hdr[1]) return;
  __shared__ float red[8];
  const int tid = threadIdx.x;
  const int lane = tid & 63;
  const int wave = tid >> 6;
  const size_t base = (size_t)blockIdx.x * 1024;
  s16x4 hv = ((const s16x4*)(x16 + base))[tid];
  const float v0 = bf2f(hv[0]), v1 = bf2f(hv[1]), v2 = bf2f(hv[2]), v3 = bf2f(hv[3]);
  float s1 = v0 + v1 + v2 + v3;
  float s2 = v0 * v0 + v1 * v1 + v2 * v2 + v3 * v3;
#pragma unroll
  for (int o = 1; o < 64; o <<= 1) { s1 += __shfl_xor(s1, o); s2 += __shfl_xor(s2, o); }
  if (lane == 0) { red[wave] = s1; red[wave + 4] = s2; }
  __syncthreads();
  s1 = red[0] + red[1] + red[2] + red[3];
  s2 = red[4] + red[5] + red[6] + red[7];
  const float mu  = s1 * (1.f / 1024.f);
  const float var = fmaxf(s2 * (1.f / 1024.f) - mu * mu, 0.f);
  const float rs  = rsqrtf(var + LN_EPSF);
  float4 g4 = ((const float4*)gg)[tid];
  float4 b4 = ((const float4*)bb)[tid];
  s16x4 hh;
  hh[0] = f2bf((v0 - mu) * rs * g4.x + b4.x);
  hh[1] = f2bf((v1 - mu) * rs * g4.y + b4.y);
  hh[2] = f2bf((v2 - mu) * rs * g4.z + b4.z);
  hh[3] = f2bf((v3 - mu) * rs * g4.w + b4.w);
  ((s16x4*)(y16 + base))[tid] = hh;
}

// ---------------------------------------------------------------------------
// fused LN2 + avg-pool over compacted valid tokens + mix + L2 normalize
// (bf16 input rows)
// ---------------------------------------------------------------------------
__global__ __launch_bounds__(256)
void ln2_final_kernel(const short* __restrict__ x16, const float* __restrict__ gg,
                      const float* __restrict__ bb, const float* __restrict__ er,
                      const int* __restrict__ lens, const int* __restrict__ cum,
                      float* __restrict__ out) {
  __shared__ float part[4][1024];
  __shared__ float red[4];
  const int tid = threadIdx.x, lane = tid & 63, w = tid >> 6;
  const int b = blockIdx.x, len = lens[b];
  const size_t rb = (size_t)cum[b];
  float4 g4[4], b4[4];
#pragma unroll
  for (int k = 0; k < 4; ++k) {
    g4[k] = ((const float4*)gg)[k * 64 + lane];
    b4[k] = ((const float4*)bb)[k * 64 + lane];
  }
  float4 acc[4];
#pragma unroll
  for (int k = 0; k < 4; ++k) acc[k] = make_float4(0.f, 0.f, 0.f, 0.f);

  for (int l = w; l < len; l += 4) {
    const s16x4* row = (const s16x4*)(x16 + (rb + l) * 1024);
    float4 v[4]; float s1 = 0.f, s2 = 0.f;
#pragma unroll
    for (int k = 0; k < 4; ++k) {
      s16x4 hv = row[k * 64 + lane];
      v[k] = make_float4(bf2f(hv[0]), bf2f(hv[1]), bf2f(hv[2]), bf2f(hv[3]));
      s1 += v[k].x + v[k].y + v[k].z + v[k].w;
      s2 += v[k].x * v[k].x + v[k].y * v[k].y + v[k].z * v[k].z + v[k].w * v[k].w;
    }
#pragma unroll
    for (int o = 1; o < 64; o <<= 1) { s1 += __shfl_xor(s1, o); s2 += __shfl_xor(s2, o); }
    const float mu = s1 * (1.f / 1024.f);
    const float rs = rsqrtf(fmaxf(s2 * (1.f / 1024.f) - mu * mu, 0.f) + LN_EPSF);
#pragma unroll
    for (int k = 0; k < 4; ++k) {
      acc[k].x += (v[k].x - mu) * rs * g4[k].x + b4[k].x;
      acc[k].y += (v[k].y - mu) * rs * g4[k].y + b4[k].y;
      acc[k].z += (v[k].z - mu) * rs * g4[k].z + b4[k].z;
      acc[k].w += (v[k].w - mu) * rs * g4[k].w + b4[k].w;
    }
  }
#pragma unroll
  for (int k = 0; k < 4; ++k)
    ((float4*)&part[w][0])[k * 64 + lane] = acc[k];
  __syncthreads();

  float4 s = ((const float4*)&part[0][0])[tid];
#pragma unroll
  for (int w2 = 1; w2 < 4; ++w2) {
    float4 t4 = ((const float4*)&part[0][0])[w2 * 256 + tid];
    s.x += t4.x; s.y += t4.y; s.z += t4.z; s.w += t4.w;
  }
  const float il = 0.5f / (float)len;
  float4 e = ((const float4*)(er + (size_t)b * 1024))[tid];
  const float o0 = 0.5f * e.x + s.x * il;
  const float o1 = 0.5f * e.y + s.y * il;
  const float o2 = 0.5f * e.z + s.z * il;
  const float o3 = 0.5f * e.w + s.w * il;
  float ss = o0 * o0 + o1 * o1 + o2 * o2 + o3 * o3;
#pragma unroll
  for (int o = 1; o < 64; o <<= 1) ss += __shfl_xor(ss, o);
  if (lane == 0) red[w] = ss;
  __syncthreads();
  ss = red[0] + red[1] + red[2] + red[3];
  const float nrm = 1.f / (sqrtf(ss) + 1e-8f);
  ((float4*)(out + (size_t)b * 1024))[tid] = make_float4(o0 * nrm, o1 * nrm, o2 * nrm, o3 * nrm);
}

// ---------------------------------------------------------------------------
extern "C" void kernel_launch(void* const* d_in, const int* in_sizes, int n_in,
                              void* d_out, int out_size, void* d_ws, size_t ws_size,
                              hipStream_t stream) {
  (void)in_sizes; (void)n_in; (void)out_size; (void)ws_size;
  const float* images = (const float*)d_in[0];
  const int*   lens   = (const int*)d_in[1];
  const float* fc1_w = (const float*)d_in[2];
  const float* fc1_b = (const float*)d_in[3];
  const float* bn_g  = (const float*)d_in[4];
  const float* bn_b  = (const float*)d_in[5];
  const float* bn_m  = (const float*)d_in[6];
  const float* bn_v  = (const float*)d_in[7];
  const float* fc2_w = (const float*)d_in[8];
  const float* fc2_b = (const float*)d_in[9];
  const float* in_w  = (const float*)d_in[10];
  const float* in_b  = (const float*)d_in[11];
  const float* out_w = (const float*)d_in[12];
  const float* out_b = (const float*)d_in[13];
  const float* ln1_g = (const float*)d_in[14];
  const float* ln1_b = (const float*)d_in[15];
  const float* ff1_w = (const float*)d_in[16];
  const float* ff1_b = (const float*)d_in[17];
  const float* ff2_w = (const float*)d_in[18];
  const float* ff2_b = (const float*)d_in[19];
  const float* ln2_g = (const float*)d_in[20];
  const float* ln2_b = (const float*)d_in[21];
  float* out = (float*)d_out;

  char* ws = (char*)d_ws;
  const size_t OFF_IMG16 = 0;                          // 67108864 (img16 / x1sum / x2sum)
  const size_t OFF_FC1W  = 67108864;                   // 2097152
  const size_t OFF_FC2W  = OFF_FC1W + 2097152;         // 1048576
  const size_t OFF_INW   = OFF_FC2W + 1048576;         // 6291456
  const size_t OFF_OUTW  = OFF_INW  + 6291456;         // 2097152
  const size_t OFF_FF1W  = OFF_OUTW + 2097152;         // 2097152
  const size_t OFF_FF2W  = OFF_FF1W + 2097152;         // 2097152
  const size_t OFF_H1    = OFF_FF2W + 2097152;         // 16777216
  const size_t OFF_EMB16 = OFF_H1 + 16777216;          // 33554432
  const size_t OFF_QKV   = OFF_EMB16 + 33554432;       // 101056512 (16448 rows)
  const size_t OFF_CTX   = OFF_QKV + 101056512;        // 33554432
  const size_t OFF_ERES  = OFF_CTX + 33554432;         // 1048576
  const size_t OFF_HDR   = OFF_ERES + 1048576;         // 256
  const size_t OFF_CUM   = OFF_HDR + 256;              // 1024
  const size_t OFF_TOK   = OFF_CUM + 1024;             // 65536

  short* img16  = (short*)(ws + OFF_IMG16);
  short* fc1w16 = (short*)(ws + OFF_FC1W);
  short* fc2w16 = (short*)(ws + OFF_FC2W);
  short* inw16  = (short*)(ws + OFF_INW);
  short* outw16 = (short*)(ws + OFF_OUTW);
  short* ff1w16 = (short*)(ws + OFF_FF1W);
  short* ff2w16 = (short*)(ws + OFF_FF2W);
  short* h1     = (short*)(ws + OFF_H1);
  short* emb16  = (short*)(ws + OFF_EMB16);
  short* qkv16  = (short*)(ws + OFF_QKV);
  short* ctx16  = (short*)(ws + OFF_CTX);
  float* embres = (float*)(ws + OFF_ERES);
  int*   hdr    = (int*)(ws + OFF_HDR);
  int*   cum    = (int*)(ws + OFF_CUM);
  int*   tokmap = (int*)(ws + OFF_TOK);
  short* x1sum = (short*)(ws + OFF_IMG16);  // pre-LN1 bf16 (img16 dead)
  short* x1h   = emb16;                     // post-LN1 bf16 (emb16 dead after out-proj)
  short* ffh   = ctx16;                     // ffn hidden    (ctx16 dead)
  short* x2sum = (short*)(ws + OFF_IMG16);  // pre-LN2 bf16  (x1sum dead)

  const dim3 blk(256);
  const size_t SMEM256 = 131072;
  const size_t SMEM128 = 65536;

  // compaction metadata (prefix + tokmap fused)
  prefix_kernel<<<1, blk, 0, stream>>>(lens, cum, hdr, tokmap);

  // converts: gathered images + all six weights in one kernel
  CvtArgs ca;
  ca.src[0] = fc1_w; ca.dst[0] = fc1w16; ca.n4[0] = 1048576 / 4;
  ca.src[1] = fc2_w; ca.dst[1] = fc2w16; ca.n4[1] = 524288 / 4;
  ca.src[2] = in_w;  ca.dst[2] = inw16;  ca.n4[2] = 3145728 / 4;
  ca.src[3] = out_w; ca.dst[3] = outw16; ca.n4[3] = 1048576 / 4;
  ca.src[4] = ff1_w; ca.dst[4] = ff1w16; ca.n4[4] = 1048576 / 4;
  ca.src[5] = ff2_w; ca.dst[5] = ff2w16; ca.n4[5] = 1048576 / 4;
  cvt_gather_kernel<<<2048, blk, 0, stream>>>(images, tokmap, hdr, img16, ca);

  // fc1 + BN + ReLU -> h1 (bf16, compacted)  [pipelined 128x128]
  gemm128p<EPI_H1><<<dim3(4, 128), 512, SMEM128, stream>>>(
      img16, fc1w16, fc1_b, nullptr, bn_g, bn_b, bn_m, bn_v, hdr, h1, 512, 2048);
  // fc2 -> emb16 (compacted)
  gemm128p<EPI_PLAIN><<<dim3(8, 128), 512, SMEM128, stream>>>(
      h1, fc2w16, fc2_b, nullptr, nullptr, nullptr, nullptr, nullptr, hdr, emb16, 1024, 512);
  // top-2 pooling over compacted emb
  topk_kernel<<<256, blk, 0, stream>>>(emb16, lens, cum, embres);
  // qkv projection (256x256 pipelined)
  gemm256<EPI_PLAIN><<<dim3(12, 64), 512, SMEM256, stream>>>(
      emb16, inw16, in_b, hdr, qkv16, 3072, 1024);
  // attention (compacted rows)
  attn_kernel<<<2048, blk, 0, stream>>>(qkv16, lens, cum, ctx16);
  // out projection + residual(emb16) -> pre-LN1 bf16
  gemm128p<EPI_RES><<<dim3(8, 128), 512, SMEM128, stream>>>(
      ctx16, outw16, out_b, emb16, nullptr, nullptr, nullptr, nullptr, hdr, x1sum, 1024, 1024);
  ln_kernel<<<16384, blk, 0, stream>>>(x1sum, ln1_g, ln1_b, hdr, x1h);
  // ffn
  gemm128p<EPI_FF1><<<dim3(8, 128), 512, SMEM128, stream>>>(
      x1h, ff1w16, ff1_b, nullptr, nullptr, nullptr, nullptr, nullptr, hdr, ffh, 1024, 1024);
  gemm128p<EPI_RES><<<dim3(8, 128), 512, SMEM128, stream>>>(
      ffh, ff2w16, ff2_b, x1h, nullptr, nullptr, nullptr, nullptr, hdr, x2sum, 1024, 1024);
  // fused LN2 + avg-pool + mix + normalize
  ln2_final_kernel<<<256, blk, 0, stream>>>(x2sum, ln2_g, ln2_b, embres, lens, cum, out);
}

// Round 11
// 344.098 us; speedup vs baseline: 1.2980x; 1.1004x over previous
//
#include <hip/hip_runtime.h>
#include <stdint.h>
#include <stddef.h>

// ---------------------------------------------------------------------------
// EncoderImageAggr: bf16-MFMA pipeline for MI355X (gfx950)
// B=256 L=64 IMG_DIM=2048 D=1024 H=8 DH=128. All GEMMs are C = A @ W^T.
// Round 11: ALL GEMMs on the pipelined 128x128 kernel (2 blocks/CU) — qkv's
// 396-block/2-pass quantization on the 256x256 kernel replaced by a smooth
// 1584-block stream. topk vectorized (s16x4, one pass). gemm256 deleted.
// ---------------------------------------------------------------------------

typedef short s16x8 __attribute__((ext_vector_type(8)));
typedef short s16x4 __attribute__((ext_vector_type(4)));
typedef float f32x4 __attribute__((ext_vector_type(4)));

#define LN_EPSF 1e-5f
#define BN_EPSF 1e-5f

__device__ __forceinline__ short f2bf(float f) {
  union { float f; uint32_t u; } x; x.f = f;
  uint32_t r = x.u + 0x7fffu + ((x.u >> 16) & 1u);   // RNE
  return (short)(r >> 16);
}
__device__ __forceinline__ float bf2f(short s) {
  union { uint32_t u; float f; } x; x.u = ((uint32_t)(uint16_t)s) << 16;
  return x.f;
}

typedef const __attribute__((address_space(1))) short glb_s16_t;
typedef __attribute__((address_space(3))) short lds_s16_t;

__device__ __forceinline__ void stage16(const short* g, short* l) {
  __builtin_amdgcn_global_load_lds((glb_s16_t*)g, (lds_s16_t*)l, 16, 0, 0);
}

// involution swizzle for 64B-row LDS slots (measured 0 bank conflicts)
__device__ __forceinline__ int swz(int off) {
  return off ^ (((off >> 7) & 3) << 4);
}

enum { EPI_PLAIN = 0, EPI_FF1 = 3, EPI_RES = 4, EPI_H1 = 5 };

// ---------------------------------------------------------------------------
// prefix-sum of lens -> cum (exclusive), hdr = {Mc, Mc_pad}; build tokmap
// ---------------------------------------------------------------------------
__global__ __launch_bounds__(256)
void prefix_kernel(const int* __restrict__ lens, int* __restrict__ cum,
                   int* __restrict__ hdr, int* __restrict__ tokmap) {
  __shared__ int wsum[4];
  __shared__ int sc[256];
  __shared__ int mcpad;
  const int tid = threadIdx.x, lane = tid & 63, wave = tid >> 6;
  const int mylen = lens[tid];
  int v = mylen;
#pragma unroll
  for (int o = 1; o < 64; o <<= 1) {
    int t = __shfl_up(v, o);
    if (lane >= o) v += t;
  }
  if (lane == 63) wsum[wave] = v;
  __syncthreads();
  int add = 0;
#pragma unroll
  for (int w2 = 0; w2 < 4; ++w2) if (w2 < wave) add += wsum[w2];
  const int incl = v + add;
  const int excl = incl - mylen;
  cum[tid] = excl;
  sc[tid] = excl;
  if (tid == 255) {
    hdr[0] = incl;                       // Mc
    mcpad  = (incl + 255) & ~255;        // Mc_pad (multiple of 256)
    hdr[1] = mcpad;
  }
  __syncthreads();
  for (int l = 0; l < mylen; ++l) tokmap[excl + l] = tid * 64 + l;
  const int mc = sc[255] + lens[255];
  for (int i = mc + tid; i < mcpad; i += 256) tokmap[i] = 0;
}

// ---------------------------------------------------------------------------
// gathered fp32 -> bf16 convert of valid image rows (compacted) + weights
// ---------------------------------------------------------------------------
struct CvtArgs { const float* src[6]; short* dst[6]; int n4[6]; };

__global__ __launch_bounds__(256)
void cvt_gather_kernel(const float* __restrict__ img,
                       const int* __restrict__ tokmap,
                       const int* __restrict__ hdr, short* __restrict__ out,
                       CvtArgs a) {
  const int n4 = hdr[1] << 9;                    // Mc_pad * 512 float4s
  const int stride = gridDim.x * 256;
  for (int i = blockIdx.x * 256 + threadIdx.x; i < n4; i += stride) {
    const int row = i >> 9, col = i & 511;
    float4 v = ((const float4*)img)[(size_t)tokmap[row] * 512 + col];
    s16x4 h; h[0] = f2bf(v.x); h[1] = f2bf(v.y); h[2] = f2bf(v.z); h[3] = f2bf(v.w);
    ((s16x4*)out)[i] = h;
  }
#pragma unroll
  for (int s = 0; s < 6; ++s) {
    const int n = a.n4[s];
    const float4* in = (const float4*)a.src[s];
    s16x4* outp = (s16x4*)a.dst[s];
    for (int i = blockIdx.x * 256 + threadIdx.x; i < n; i += stride) {
      float4 v = in[i];
      s16x4 h; h[0] = f2bf(v.x); h[1] = f2bf(v.y); h[2] = f2bf(v.z); h[3] = f2bf(v.w);
      outp[i] = h;
    }
  }
}

// ---------------------------------------------------------------------------
// 128x128 PIPELINED GEMM — all five GEMMs. 512 thr, 8 waves (2Mx4N),
// per-wave 64x32 (acc[4][2]). Ring-4 half-slots [128][32] bf16 (8KB)/matrix
// -> 64KB LDS -> 2 blocks/CU. Counted vmcnt(2)/half-step; chunked XCD swizzle
// over the live block range.
// Epilogues: PLAIN / FF1(ReLU) / RES(+bf16 residual -> bf16) / H1(BN+ReLU).
// ---------------------------------------------------------------------------
template<int EPI>
__global__ __launch_bounds__(512, 4)
void gemm128p(const short* __restrict__ A, const short* __restrict__ Bw,
              const float* __restrict__ bias, const short* __restrict__ res16,
              const float* __restrict__ bnG, const float* __restrict__ bnB,
              const float* __restrict__ bnM, const float* __restrict__ bnV,
              const int* __restrict__ hdr, short* __restrict__ out16,
              int N, int K) {
  extern __shared__ char smem[];                 // 65536 B
  const int tid  = threadIdx.x;
  const int lane = tid & 63;
  const int w    = tid >> 6;
  const int wr   = w >> 2;
  const int wc   = w & 3;
  const int lrow = lane & 15;
  const int cg   = lane >> 4;
  const int NH   = K >> 5;
  const int gx   = gridDim.x;

  const int p = blockIdx.y * gx + blockIdx.x;
  const int nwork = (hdr[1] >> 7) * gx;
  if (p >= nwork) return;
  const int xcd = p & 7, off = p >> 3;
  const int q = nwork >> 3, r = nwork & 7;
  const int wg = (xcd < r ? xcd * (q + 1) : r * (q + 1) + (xcd - r) * q) + off;
  const int m0 = (wg / gx) * 128;
  const int n0 = (wg % gx) * 128;

  const int ldb = K * 2;
  size_t gA, gB;
  {
    const int pp = tid * 16;
    const int l = swz(pp);
    const int row = l >> 6, colb = l & 63;
    gA = (size_t)(m0 + row) * ldb + colb;
    gB = (size_t)(n0 + row) * ldb + colb;
  }
  const char* Ab = (const char*)A;
  const char* Bb = (const char*)Bw;
  char* ldsA = smem;                             // 4 x 8KB
  char* ldsB = smem + 32768;                     // 4 x 8KB
  const int wofs = w * 1024;

  auto stageA = [&](int i) {
    stage16((const short*)(Ab + gA + i * 64), (short*)(ldsA + ((i & 3) << 13) + wofs));
  };
  auto stageB = [&](int i) {
    stage16((const short*)(Bb + gB + i * 64), (short*)(ldsB + ((i & 3) << 13) + wofs));
  };

  int offA[4], offB[2];
#pragma unroll
  for (int mf = 0; mf < 4; ++mf)
    offA[mf] = swz((wr * 64 + mf * 16 + lrow) * 64 + cg * 16);
#pragma unroll
  for (int nf = 0; nf < 2; ++nf)
    offB[nf] = swz((wc * 32 + nf * 16 + lrow) * 64 + cg * 16);

  f32x4 acc[4][2] = {};

  stageA(0); stageB(0);
  stageA(1); stageB(1);
  stageA(2); stageB(2);
  asm volatile("s_waitcnt vmcnt(4)" ::: "memory");
  __builtin_amdgcn_s_barrier();
  __builtin_amdgcn_sched_barrier(0);
  s16x8 af_cur[2], bf_cur[2], af_nxt[2], bf_nxt[2], af2[2];
#pragma unroll
  for (int m = 0; m < 2; ++m) af_cur[m] = *(const s16x8*)(ldsA + offA[m]);
#pragma unroll
  for (int n = 0; n < 2; ++n) bf_cur[n] = *(const s16x8*)(ldsB + offB[n]);

  for (int i = 0; i < NH - 1; ++i) {
    const char* pA  = ldsA + ((i & 3) << 13);
    const char* pA1 = ldsA + (((i + 1) & 3) << 13);
    const char* pB1 = ldsB + (((i + 1) & 3) << 13);

    if (i + 2 < NH) { asm volatile("s_waitcnt vmcnt(2)" ::: "memory"); }
    else            { asm volatile("s_waitcnt vmcnt(0)" ::: "memory"); }
    __builtin_amdgcn_s_barrier();
    __builtin_amdgcn_sched_barrier(0);

#pragma unroll
    for (int m = 0; m < 2; ++m) af_nxt[m] = *(const s16x8*)(pA + offA[m + 2]);
#pragma unroll
    for (int n = 0; n < 2; ++n) bf_nxt[n] = *(const s16x8*)(pB1 + offB[n]);
    if (i + 3 < NH) stageA(i + 3);
    asm volatile("s_waitcnt lgkmcnt(4)" ::: "memory");
    __builtin_amdgcn_sched_barrier(0);
    __builtin_amdgcn_s_setprio(1);
#pragma unroll
    for (int m = 0; m < 2; ++m)
#pragma unroll
      for (int n = 0; n < 2; ++n)
        acc[m][n] = __builtin_amdgcn_mfma_f32_16x16x32_bf16(af_cur[m], bf_cur[n], acc[m][n], 0, 0, 0);
    __builtin_amdgcn_s_setprio(0);

#pragma unroll
    for (int m = 0; m < 2; ++m) af2[m] = *(const s16x8*)(pA1 + offA[m]);
    if (i + 3 < NH) stageB(i + 3);
    asm volatile("s_waitcnt lgkmcnt(2)" ::: "memory");
    __builtin_amdgcn_sched_barrier(0);
    __builtin_amdgcn_s_setprio(1);
#pragma unroll
    for (int m = 0; m < 2; ++m)
#pragma unroll
      for (int n = 0; n < 2; ++n)
        acc[m + 2][n] = __builtin_amdgcn_mfma_f32_16x16x32_bf16(af_nxt[m], bf_cur[n], acc[m + 2][n], 0, 0, 0);
    __builtin_amdgcn_s_setprio(0);

#pragma unroll
    for (int m = 0; m < 2; ++m) af_cur[m] = af2[m];
#pragma unroll
    for (int n = 0; n < 2; ++n) bf_cur[n] = bf_nxt[n];
  }

  {
    const char* pA = ldsA + (((NH - 1) & 3) << 13);
    asm volatile("s_waitcnt vmcnt(0)" ::: "memory");
    __builtin_amdgcn_s_barrier();
    __builtin_amdgcn_sched_barrier(0);
#pragma unroll
    for (int m = 0; m < 2; ++m) af_nxt[m] = *(const s16x8*)(pA + offA[m + 2]);
    asm volatile("s_waitcnt lgkmcnt(2)" ::: "memory");
    __builtin_amdgcn_sched_barrier(0);
    __builtin_amdgcn_s_setprio(1);
#pragma unroll
    for (int m = 0; m < 2; ++m)
#pragma unroll
      for (int n = 0; n < 2; ++n)
        acc[m][n] = __builtin_amdgcn_mfma_f32_16x16x32_bf16(af_cur[m], bf_cur[n], acc[m][n], 0, 0, 0);
    __builtin_amdgcn_s_setprio(0);
    asm volatile("s_waitcnt lgkmcnt(0)" ::: "memory");
    __builtin_amdgcn_sched_barrier(0);
    __builtin_amdgcn_s_setprio(1);
#pragma unroll
    for (int m = 0; m < 2; ++m)
#pragma unroll
      for (int n = 0; n < 2; ++n)
        acc[m + 2][n] = __builtin_amdgcn_mfma_f32_16x16x32_bf16(af_nxt[m], bf_cur[n], acc[m + 2][n], 0, 0, 0);
    __builtin_amdgcn_s_setprio(0);
  }

  // epilogue
  const int ecol0 = n0 + wc * 32 + lrow;
  const int erow0 = m0 + wr * 64 + (cg << 2);
  float bz[2], sc[2], sh[2];
#pragma unroll
  for (int nf = 0; nf < 2; ++nf) {
    const int c = ecol0 + nf * 16;
    if constexpr (EPI == EPI_H1) {
      const float s = bnG[c] * rsqrtf(bnV[c] + BN_EPSF);
      sc[nf] = s;
      sh[nf] = (bias[c] - bnM[c]) * s + bnB[c];
    } else {
      bz[nf] = bias[c];
    }
  }
  (void)bnG; (void)bnB; (void)bnM; (void)bnV;

#pragma unroll
  for (int mf = 0; mf < 4; ++mf) {
#pragma unroll
    for (int nf = 0; nf < 2; ++nf) {
#pragma unroll
      for (int r2 = 0; r2 < 4; ++r2) {
        const int row = erow0 + mf * 16 + r2;
        const size_t idx = (size_t)row * N + (ecol0 + nf * 16);
        if constexpr (EPI == EPI_H1) {
          out16[idx] = f2bf(fmaxf(acc[mf][nf][r2] * sc[nf] + sh[nf], 0.f));
        } else {
          const float v = acc[mf][nf][r2] + bz[nf];
          if constexpr (EPI == EPI_PLAIN) {
            out16[idx] = f2bf(v);
          } else if constexpr (EPI == EPI_FF1) {
            out16[idx] = f2bf(fmaxf(v, 0.f));
          } else {  // EPI_RES: bf16 out = v + bf16 residual
            out16[idx] = f2bf(v + bf2f(res16[idx]));
          }
        }
      }
    }
  }
}

// ---------------------------------------------------------------------------
// top-2 mean per (b, d): thread owns 4 contiguous cols, one s16x4 load/row
// ---------------------------------------------------------------------------
__global__ __launch_bounds__(256)
void topk_kernel(const short* __restrict__ emb16, const int* __restrict__ lens,
                 const int* __restrict__ cum, float* __restrict__ er) {
  const int b = blockIdx.x;
  const int len = lens[b];
  const size_t base = (size_t)cum[b] * 1024;
  const int d0 = threadIdx.x * 4;
  float m1[4], m2[4];
#pragma unroll
  for (int k = 0; k < 4; ++k) { m1[k] = -3.0e38f; m2[k] = -3.0e38f; }
  for (int l = 0; l < len; ++l) {
    s16x4 hv = *(const s16x4*)&emb16[base + (size_t)l * 1024 + d0];
#pragma unroll
    for (int k = 0; k < 4; ++k) {
      const float v = bf2f(hv[k]);
      if (v > m1[k]) { m2[k] = m1[k]; m1[k] = v; }
      else           { m2[k] = fmaxf(m2[k], v); }
    }
  }
  f32x4 res;
#pragma unroll
  for (int k = 0; k < 4; ++k) res[k] = 0.5f * (m1[k] + m2[k]);
  *(f32x4*)&er[(size_t)b * 1024 + d0] = res;
}

// ---------------------------------------------------------------------------
// Fused attention on compacted rows: one block per (b,h).
// ---------------------------------------------------------------------------
__global__ __launch_bounds__(256)
void attn_kernel(const short* __restrict__ qkv, const int* __restrict__ lens,
                 const int* __restrict__ cum, short* __restrict__ ctx) {
  __shared__ short Qs[64 * 128];
  __shared__ short Ks[64 * 128];
  __shared__ short Vt[128 * 64];
  const int tid  = threadIdx.x;
  const int lane = tid & 63;
  const int wave = tid >> 6;
  const int b = blockIdx.x >> 3;
  const int h = blockIdx.x & 7;
  const int len = lens[b];
  const int rb  = cum[b];
  const size_t qb = (size_t)rb * 3072 + h * 128;

  {
    const int rr = wave * 4 + (lane >> 4);
    const int cc = (lane & 15) * 8;
#pragma unroll
    for (int r = 0; r < 4; ++r) {
      stage16(qkv + qb +        (size_t)(r * 16 + rr) * 3072 + cc, &Qs[(r * 16 + wave * 4) * 128]);
      stage16(qkv + qb + 1024 + (size_t)(r * 16 + rr) * 3072 + cc, &Ks[(r * 16 + wave * 4) * 128]);
    }
  }
#pragma unroll
  for (int i = 0; i < 2; ++i) {
    const int c  = i * 256 + tid;
    const int lp = c >> 4;
    const int dg = c & 15;
    const short* src = qkv + qb + 2048 + (size_t)(2 * lp) * 3072 + dg * 8;
    s16x8 v0 = *(const s16x8*)src;
    s16x8 v1 = *(const s16x8*)(src + 3072);
    const bool ok0 = (2 * lp)     < len;
    const bool ok1 = (2 * lp + 1) < len;
#pragma unroll
    for (int j = 0; j < 8; ++j) {
      const uint32_t lo = ok0 ? (uint32_t)(uint16_t)v0[j] : 0u;
      const uint32_t hi = ok1 ? (uint32_t)(uint16_t)v1[j] : 0u;
      *(uint32_t*)&Vt[(dg * 8 + j) * 64 + 2 * lp] = lo | (hi << 16);
    }
  }
  __syncthreads();

  const int lrow = lane & 15;
  const int lk8  = (lane >> 4) * 8;

  f32x4 sacc[4] = {};
#pragma unroll
  for (int ks = 0; ks < 4; ++ks) {
    s16x8 aq = *(const s16x8*)&Qs[(wave * 16 + lrow) * 128 + ks * 32 + lk8];
#pragma unroll
    for (int n = 0; n < 4; ++n) {
      s16x8 bk = *(const s16x8*)&Ks[(n * 16 + lrow) * 128 + ks * 32 + lk8];
      sacc[n] = __builtin_amdgcn_mfma_f32_16x16x32_bf16(aq, bk, sacc[n], 0, 0, 0);
    }
  }

  const float scale = 0.08838834764831845f;
#pragma unroll
  for (int r = 0; r < 4; ++r) {
    float sv[4];
    float mx = -1e30f;
#pragma unroll
    for (int n = 0; n < 4; ++n) {
      float v = sacc[n][r] * scale;
      if (n * 16 + lrow >= len) v = -1e30f;
      sv[n] = v;
      mx = fmaxf(mx, v);
    }
    mx = fmaxf(mx, __shfl_xor(mx, 1));
    mx = fmaxf(mx, __shfl_xor(mx, 2));
    mx = fmaxf(mx, __shfl_xor(mx, 4));
    mx = fmaxf(mx, __shfl_xor(mx, 8));
    float pv[4], sum = 0.f;
#pragma unroll
    for (int n = 0; n < 4; ++n) { pv[n] = __expf(sv[n] - mx); sum += pv[n]; }
    sum += __shfl_xor(sum, 1);
    sum += __shfl_xor(sum, 2);
    sum += __shfl_xor(sum, 4);
    sum += __shfl_xor(sum, 8);
    const float inv = 1.f / sum;
    const int prow = wave * 16 + ((lane >> 4) << 2) + r;
#pragma unroll
    for (int n = 0; n < 4; ++n)
      Qs[prow * 128 + n * 16 + lrow] = f2bf(pv[n] * inv);
  }
  __syncthreads();

  f32x4 oacc[8] = {};
#pragma unroll
  for (int ks = 0; ks < 2; ++ks) {
    s16x8 ap = *(const s16x8*)&Qs[(wave * 16 + lrow) * 128 + ks * 32 + lk8];
#pragma unroll
    for (int n = 0; n < 8; ++n) {
      s16x8 bv = *(const s16x8*)&Vt[(n * 16 + lrow) * 64 + ks * 32 + lk8];
      oacc[n] = __builtin_amdgcn_mfma_f32_16x16x32_bf16(ap, bv, oacc[n], 0, 0, 0);
    }
  }
  const size_t ob = (size_t)rb * 1024 + h * 128;
#pragma unroll
  for (int n = 0; n < 8; ++n)
#pragma unroll
    for (int r = 0; r < 4; ++r) {
      const int row = wave * 16 + ((lane >> 4) << 2) + r;
      if (row < len)
        ctx[ob + (size_t)row * 1024 + n * 16 + lrow] = f2bf(oacc[n][r]);
    }
}

// ---------------------------------------------------------------------------
// LayerNorm over 1024 (LN1): bf16 in, bf16 out; one block per compacted row
// ---------------------------------------------------------------------------
__global__ __launch_bounds__(256)
void ln_kernel(const short* __restrict__ x16, const float* __restrict__ gg,
               const float* __restrict__ bb, const int* __restrict__ hdr,
               short* __restrict__ y16) {
  if ((int)blockIdx.x >= hdr[1]) return;
  __shared__ float red[8];
  const int tid = threadIdx.x;
  const int lane = tid & 63;
  const int wave = tid >> 6;
  const size_t base = (size_t)blockIdx.x * 1024;
  s16x4 hv = ((const s16x4*)(x16 + base))[tid];
  const float v0 = bf2f(hv[0]), v1 = bf2f(hv[1]), v2 = bf2f(hv[2]), v3 = bf2f(hv[3]);
  float s1 = v0 + v1 + v2 + v3;
  float s2 = v0 * v0 + v1 * v1 + v2 * v2 + v3 * v3;
#pragma unroll
  for (int o = 1; o < 64; o <<= 1) { s1 += __shfl_xor(s1, o); s2 += __shfl_xor(s2, o); }
  if (lane == 0) { red[wave] = s1; red[wave + 4] = s2; }
  __syncthreads();
  s1 = red[0] + red[1] + red[2] + red[3];
  s2 = red[4] + red[5] + red[6] + red[7];
  const float mu  = s1 * (1.f / 1024.f);
  const float var = fmaxf(s2 * (1.f / 1024.f) - mu * mu, 0.f);
  const float rs  = rsqrtf(var + LN_EPSF);
  float4 g4 = ((const float4*)gg)[tid];
  float4 b4 = ((const float4*)bb)[tid];
  s16x4 hh;
  hh[0] = f2bf((v0 - mu) * rs * g4.x + b4.x);
  hh[1] = f2bf((v1 - mu) * rs * g4.y + b4.y);
  hh[2] = f2bf((v2 - mu) * rs * g4.z + b4.z);
  hh[3] = f2bf((v3 - mu) * rs * g4.w + b4.w);
  ((s16x4*)(y16 + base))[tid] = hh;
}

// ---------------------------------------------------------------------------
// fused LN2 + avg-pool over compacted valid tokens + mix + L2 normalize
// (bf16 input rows)
// ---------------------------------------------------------------------------
__global__ __launch_bounds__(256)
void ln2_final_kernel(const short* __restrict__ x16, const float* __restrict__ gg,
                      const float* __restrict__ bb, const float* __restrict__ er,
                      const int* __restrict__ lens, const int* __restrict__ cum,
                      float* __restrict__ out) {
  __shared__ float part[4][1024];
  __shared__ float red[4];
  const int tid = threadIdx.x, lane = tid & 63, w = tid >> 6;
  const int b = blockIdx.x, len = lens[b];
  const size_t rb = (size_t)cum[b];
  float4 g4[4], b4[4];
#pragma unroll
  for (int k = 0; k < 4; ++k) {
    g4[k] = ((const float4*)gg)[k * 64 + lane];
    b4[k] = ((const float4*)bb)[k * 64 + lane];
  }
  float4 acc[4];
#pragma unroll
  for (int k = 0; k < 4; ++k) acc[k] = make_float4(0.f, 0.f, 0.f, 0.f);

  for (int l = w; l < len; l += 4) {
    const s16x4* row = (const s16x4*)(x16 + (rb + l) * 1024);
    float4 v[4]; float s1 = 0.f, s2 = 0.f;
#pragma unroll
    for (int k = 0; k < 4; ++k) {
      s16x4 hv = row[k * 64 + lane];
      v[k] = make_float4(bf2f(hv[0]), bf2f(hv[1]), bf2f(hv[2]), bf2f(hv[3]));
      s1 += v[k].x + v[k].y + v[k].z + v[k].w;
      s2 += v[k].x * v[k].x + v[k].y * v[k].y + v[k].z * v[k].z + v[k].w * v[k].w;
    }
#pragma unroll
    for (int o = 1; o < 64; o <<= 1) { s1 += __shfl_xor(s1, o); s2 += __shfl_xor(s2, o); }
    const float mu = s1 * (1.f / 1024.f);
    const float rs = rsqrtf(fmaxf(s2 * (1.f / 1024.f) - mu * mu, 0.f) + LN_EPSF);
#pragma unroll
    for (int k = 0; k < 4; ++k) {
      acc[k].x += (v[k].x - mu) * rs * g4[k].x + b4[k].x;
      acc[k].y += (v[k].y - mu) * rs * g4[k].y + b4[k].y;
      acc[k].z += (v[k].z - mu) * rs * g4[k].z + b4[k].z;
      acc[k].w += (v[k].w - mu) * rs * g4[k].w + b4[k].w;
    }
  }
#pragma unroll
  for (int k = 0; k < 4; ++k)
    ((float4*)&part[w][0])[k * 64 + lane] = acc[k];
  __syncthreads();

  float4 s = ((const float4*)&part[0][0])[tid];
#pragma unroll
  for (int w2 = 1; w2 < 4; ++w2) {
    float4 t4 = ((const float4*)&part[0][0])[w2 * 256 + tid];
    s.x += t4.x; s.y += t4.y; s.z += t4.z; s.w += t4.w;
  }
  const float il = 0.5f / (float)len;
  float4 e = ((const float4*)(er + (size_t)b * 1024))[tid];
  const float o0 = 0.5f * e.x + s.x * il;
  const float o1 = 0.5f * e.y + s.y * il;
  const float o2 = 0.5f * e.z + s.z * il;
  const float o3 = 0.5f * e.w + s.w * il;
  float ss = o0 * o0 + o1 * o1 + o2 * o2 + o3 * o3;
#pragma unroll
  for (int o = 1; o < 64; o <<= 1) ss += __shfl_xor(ss, o);
  if (lane == 0) red[w] = ss;
  __syncthreads();
  ss = red[0] + red[1] + red[2] + red[3];
  const float nrm = 1.f / (sqrtf(ss) + 1e-8f);
  ((float4*)(out + (size_t)b * 1024))[tid] = make_float4(o0 * nrm, o1 * nrm, o2 * nrm, o3 * nrm);
}

// ---------------------------------------------------------------------------
extern "C" void kernel_launch(void* const* d_in, const int* in_sizes, int n_in,
                              void* d_out, int out_size, void* d_ws, size_t ws_size,
                              hipStream_t stream) {
  (void)in_sizes; (void)n_in; (void)out_size; (void)ws_size;
  const float* images = (const float*)d_in[0];
  const int*   lens   = (const int*)d_in[1];
  const float* fc1_w = (const float*)d_in[2];
  const float* fc1_b = (const float*)d_in[3];
  const float* bn_g  = (const float*)d_in[4];
  const float* bn_b  = (const float*)d_in[5];
  const float* bn_m  = (const float*)d_in[6];
  const float* bn_v  = (const float*)d_in[7];
  const float* fc2_w = (const float*)d_in[8];
  const float* fc2_b = (const float*)d_in[9];
  const float* in_w  = (const float*)d_in[10];
  const float* in_b  = (const float*)d_in[11];
  const float* out_w = (const float*)d_in[12];
  const float* out_b = (const float*)d_in[13];
  const float* ln1_g = (const float*)d_in[14];
  const float* ln1_b = (const float*)d_in[15];
  const float* ff1_w = (const float*)d_in[16];
  const float* ff1_b = (const float*)d_in[17];
  const float* ff2_w = (const float*)d_in[18];
  const float* ff2_b = (const float*)d_in[19];
  const float* ln2_g = (const float*)d_in[20];
  const float* ln2_b = (const float*)d_in[21];
  float* out = (float*)d_out;

  char* ws = (char*)d_ws;
  const size_t OFF_IMG16 = 0;                          // 67108864 (img16 / x1sum / x2sum)
  const size_t OFF_FC1W  = 67108864;                   // 2097152
  const size_t OFF_FC2W  = OFF_FC1W + 2097152;         // 1048576
  const size_t OFF_INW   = OFF_FC2W + 1048576;         // 6291456
  const size_t OFF_OUTW  = OFF_INW  + 6291456;         // 2097152
  const size_t OFF_FF1W  = OFF_OUTW + 2097152;         // 2097152
  const size_t OFF_FF2W  = OFF_FF1W + 2097152;         // 2097152
  const size_t OFF_H1    = OFF_FF2W + 2097152;         // 16777216
  const size_t OFF_EMB16 = OFF_H1 + 16777216;          // 33554432
  const size_t OFF_QKV   = OFF_EMB16 + 33554432;       // 101056512 (16448 rows)
  const size_t OFF_CTX   = OFF_QKV + 101056512;        // 33554432
  const size_t OFF_ERES  = OFF_CTX + 33554432;         // 1048576
  const size_t OFF_HDR   = OFF_ERES + 1048576;         // 256
  const size_t OFF_CUM   = OFF_HDR + 256;              // 1024
  const size_t OFF_TOK   = OFF_CUM + 1024;             // 65536

  short* img16  = (short*)(ws + OFF_IMG16);
  short* fc1w16 = (short*)(ws + OFF_FC1W);
  short* fc2w16 = (short*)(ws + OFF_FC2W);
  short* inw16  = (short*)(ws + OFF_INW);
  short* outw16 = (short*)(ws + OFF_OUTW);
  short* ff1w16 = (short*)(ws + OFF_FF1W);
  short* ff2w16 = (short*)(ws + OFF_FF2W);
  short* h1     = (short*)(ws + OFF_H1);
  short* emb16  = (short*)(ws + OFF_EMB16);
  short* qkv16  = (short*)(ws + OFF_QKV);
  short* ctx16  = (short*)(ws + OFF_CTX);
  float* embres = (float*)(ws + OFF_ERES);
  int*   hdr    = (int*)(ws + OFF_HDR);
  int*   cum    = (int*)(ws + OFF_CUM);
  int*   tokmap = (int*)(ws + OFF_TOK);
  short* x1sum = (short*)(ws + OFF_IMG16);  // pre-LN1 bf16 (img16 dead)
  short* x1h   = emb16;                     // post-LN1 bf16 (emb16 dead after out-proj)
  short* ffh   = ctx16;                     // ffn hidden    (ctx16 dead)
  short* x2sum = (short*)(ws + OFF_IMG16);  // pre-LN2 bf16  (x1sum dead)

  const dim3 blk(256);
  const size_t SMEM128 = 65536;

  // compaction metadata (prefix + tokmap fused)
  prefix_kernel<<<1, blk, 0, stream>>>(lens, cum, hdr, tokmap);

  // converts: gathered images + all six weights in one kernel
  CvtArgs ca;
  ca.src[0] = fc1_w; ca.dst[0] = fc1w16; ca.n4[0] = 1048576 / 4;
  ca.src[1] = fc2_w; ca.dst[1] = fc2w16; ca.n4[1] = 524288 / 4;
  ca.src[2] = in_w;  ca.dst[2] = inw16;  ca.n4[2] = 3145728 / 4;
  ca.src[3] = out_w; ca.dst[3] = outw16; ca.n4[3] = 1048576 / 4;
  ca.src[4] = ff1_w; ca.dst[4] = ff1w16; ca.n4[4] = 1048576 / 4;
  ca.src[5] = ff2_w; ca.dst[5] = ff2w16; ca.n4[5] = 1048576 / 4;
  cvt_gather_kernel<<<2048, blk, 0, stream>>>(images, tokmap, hdr, img16, ca);

  // fc1 + BN + ReLU -> h1 (bf16, compacted)
  gemm128p<EPI_H1><<<dim3(4, 128), 512, SMEM128, stream>>>(
      img16, fc1w16, fc1_b, nullptr, bn_g, bn_b, bn_m, bn_v, hdr, h1, 512, 2048);
  // fc2 -> emb16 (compacted)
  gemm128p<EPI_PLAIN><<<dim3(8, 128), 512, SMEM128, stream>>>(
      h1, fc2w16, fc2_b, nullptr, nullptr, nullptr, nullptr, nullptr, hdr, emb16, 1024, 512);
  // top-2 pooling over compacted emb
  topk_kernel<<<256, blk, 0, stream>>>(emb16, lens, cum, embres);
  // qkv projection (128x128 pipelined, ~1584 live blocks at 2/CU)
  gemm128p<EPI_PLAIN><<<dim3(24, 128), 512, SMEM128, stream>>>(
      emb16, inw16, in_b, nullptr, nullptr, nullptr, nullptr, nullptr, hdr, qkv16, 3072, 1024);
  // attention (compacted rows)
  attn_kernel<<<2048, blk, 0, stream>>>(qkv16, lens, cum, ctx16);
  // out projection + residual(emb16) -> pre-LN1 bf16
  gemm128p<EPI_RES><<<dim3(8, 128), 512, SMEM128, stream>>>(
      ctx16, outw16, out_b, emb16, nullptr, nullptr, nullptr, nullptr, hdr, x1sum, 1024, 1024);
  ln_kernel<<<16384, blk, 0, stream>>>(x1sum, ln1_g, ln1_b, hdr, x1h);
  // ffn
  gemm128p<EPI_FF1><<<dim3(8, 128), 512, SMEM128, stream>>>(
      x1h, ff1w16, ff1_b, nullptr, nullptr, nullptr, nullptr, nullptr, hdr, ffh, 1024, 1024);
  gemm128p<EPI_RES><<<dim3(8, 128), 512, SMEM128, stream>>>(
      ffh, ff2w16, ff2_b, x1h, nullptr, nullptr, nullptr, nullptr, hdr, x2sum, 1024, 1024);
  // fused LN2 + avg-pool + mix + normalize
  ln2_final_kernel<<<256, blk, 0, stream>>>(x2sum, ln2_g, ln2_b, embres, lens, cum, out);
}

// Round 12
// 329.039 us; speedup vs baseline: 1.3574x; 1.0458x over previous
//
#include <hip/hip_runtime.h>
#include <stdint.h>
#include <stddef.h>

// ---------------------------------------------------------------------------
// EncoderImageAggr: bf16-MFMA pipeline for MI355X (gfx950)
// B=256 L=64 IMG_DIM=2048 D=1024 H=8 DH=128. All GEMMs are C = A @ W^T.
// Round 12: qkv reverted to gemm256 (measured 75 vs 83 us on gemm128p);
// attention is len-aware (skip dead staging rounds + fully-masked waves);
// LN1 grid-stride.
// ---------------------------------------------------------------------------

typedef short s16x8 __attribute__((ext_vector_type(8)));
typedef short s16x4 __attribute__((ext_vector_type(4)));
typedef float f32x4 __attribute__((ext_vector_type(4)));

#define LN_EPSF 1e-5f
#define BN_EPSF 1e-5f

__device__ __forceinline__ short f2bf(float f) {
  union { float f; uint32_t u; } x; x.f = f;
  uint32_t r = x.u + 0x7fffu + ((x.u >> 16) & 1u);   // RNE
  return (short)(r >> 16);
}
__device__ __forceinline__ float bf2f(short s) {
  union { uint32_t u; float f; } x; x.u = ((uint32_t)(uint16_t)s) << 16;
  return x.f;
}

typedef const __attribute__((address_space(1))) short glb_s16_t;
typedef __attribute__((address_space(3))) short lds_s16_t;

__device__ __forceinline__ void stage16(const short* g, short* l) {
  __builtin_amdgcn_global_load_lds((glb_s16_t*)g, (lds_s16_t*)l, 16, 0, 0);
}

// involution swizzle for 64B-row LDS slots (measured 0 bank conflicts)
__device__ __forceinline__ int swz(int off) {
  return off ^ (((off >> 7) & 3) << 4);
}

enum { EPI_PLAIN = 0, EPI_FF1 = 3, EPI_RES = 4, EPI_H1 = 5 };

// ---------------------------------------------------------------------------
// prefix-sum of lens -> cum (exclusive), hdr = {Mc, Mc_pad}; build tokmap
// ---------------------------------------------------------------------------
__global__ __launch_bounds__(256)
void prefix_kernel(const int* __restrict__ lens, int* __restrict__ cum,
                   int* __restrict__ hdr, int* __restrict__ tokmap) {
  __shared__ int wsum[4];
  __shared__ int sc[256];
  __shared__ int mcpad;
  const int tid = threadIdx.x, lane = tid & 63, wave = tid >> 6;
  const int mylen = lens[tid];
  int v = mylen;
#pragma unroll
  for (int o = 1; o < 64; o <<= 1) {
    int t = __shfl_up(v, o);
    if (lane >= o) v += t;
  }
  if (lane == 63) wsum[wave] = v;
  __syncthreads();
  int add = 0;
#pragma unroll
  for (int w2 = 0; w2 < 4; ++w2) if (w2 < wave) add += wsum[w2];
  const int incl = v + add;
  const int excl = incl - mylen;
  cum[tid] = excl;
  sc[tid] = excl;
  if (tid == 255) {
    hdr[0] = incl;                       // Mc
    mcpad  = (incl + 255) & ~255;        // Mc_pad (multiple of 256)
    hdr[1] = mcpad;
  }
  __syncthreads();
  for (int l = 0; l < mylen; ++l) tokmap[excl + l] = tid * 64 + l;
  const int mc = sc[255] + lens[255];
  for (int i = mc + tid; i < mcpad; i += 256) tokmap[i] = 0;
}

// ---------------------------------------------------------------------------
// gathered fp32 -> bf16 convert of valid image rows (compacted) + weights
// ---------------------------------------------------------------------------
struct CvtArgs { const float* src[6]; short* dst[6]; int n4[6]; };

__global__ __launch_bounds__(256)
void cvt_gather_kernel(const float* __restrict__ img,
                       const int* __restrict__ tokmap,
                       const int* __restrict__ hdr, short* __restrict__ out,
                       CvtArgs a) {
  const int n4 = hdr[1] << 9;                    // Mc_pad * 512 float4s
  const int stride = gridDim.x * 256;
  for (int i = blockIdx.x * 256 + threadIdx.x; i < n4; i += stride) {
    const int row = i >> 9, col = i & 511;
    float4 v = ((const float4*)img)[(size_t)tokmap[row] * 512 + col];
    s16x4 h; h[0] = f2bf(v.x); h[1] = f2bf(v.y); h[2] = f2bf(v.z); h[3] = f2bf(v.w);
    ((s16x4*)out)[i] = h;
  }
#pragma unroll
  for (int s = 0; s < 6; ++s) {
    const int n = a.n4[s];
    const float4* in = (const float4*)a.src[s];
    s16x4* outp = (s16x4*)a.dst[s];
    for (int i = blockIdx.x * 256 + threadIdx.x; i < n; i += stride) {
      float4 v = in[i];
      s16x4 h; h[0] = f2bf(v.x); h[1] = f2bf(v.y); h[2] = f2bf(v.z); h[3] = f2bf(v.w);
      outp[i] = h;
    }
  }
}

// ---------------------------------------------------------------------------
// 256x256 pipelined GEMM — qkv only. 512 thr, 8 waves (2Mx4N), per-wave
// 128x64. Ring-4 half-slots [256][32]; counted vmcnt(4); chunked XCD swizzle.
// ---------------------------------------------------------------------------
__global__ __launch_bounds__(512, 2)
void gemm256(const short* __restrict__ A, const short* __restrict__ Bw,
             const float* __restrict__ bias, const int* __restrict__ hdr,
             short* __restrict__ out16, int N, int K) {
  extern __shared__ char smem[];                 // 131072 B
  const int tid  = threadIdx.x;
  const int lane = tid & 63;
  const int w    = tid >> 6;
  const int wr   = w >> 2;
  const int wc   = w & 3;
  const int lrow = lane & 15;
  const int cg   = lane >> 4;
  const int NH   = K >> 5;
  const int gx   = gridDim.x;

  const int p = blockIdx.y * gx + blockIdx.x;
  const int nwork = (hdr[1] >> 8) * gx;
  if (p >= nwork) return;
  const int xcd = p & 7, off = p >> 3;
  const int q = nwork >> 3, r = nwork & 7;
  const int wg = (xcd < r ? xcd * (q + 1) : r * (q + 1) + (xcd - r) * q) + off;
  const int m0 = (wg / gx) * 256;
  const int n0 = (wg % gx) * 256;

  const int ldb = K * 2;
  size_t gA[2], gB[2];
#pragma unroll
  for (int j = 0; j < 2; ++j) {
    const int pp = tid * 16 + j * 8192;
    const int l = swz(pp);
    const int row = l >> 6, colb = l & 63;
    gA[j] = (size_t)(m0 + row) * ldb + colb;
    gB[j] = (size_t)(n0 + row) * ldb + colb;
  }
  const char* Ab = (const char*)A;
  const char* Bb = (const char*)Bw;
  char* ldsA = smem;
  char* ldsB = smem + 65536;
  const int wofs = w * 1024;

  auto stageApart = [&](int i) {
    const int rg = ((i & 3) << 14) + wofs;
    const int ko = i * 64;
    stage16((const short*)(Ab + gA[0] + ko), (short*)(ldsA + rg));
    stage16((const short*)(Ab + gA[1] + ko), (short*)(ldsA + rg + 8192));
  };
  auto stageBpart = [&](int i) {
    const int rg = ((i & 3) << 14) + wofs;
    const int ko = i * 64;
    stage16((const short*)(Bb + gB[0] + ko), (short*)(ldsB + rg));
    stage16((const short*)(Bb + gB[1] + ko), (short*)(ldsB + rg + 8192));
  };

  int offA[8], offB[4];
#pragma unroll
  for (int mf = 0; mf < 8; ++mf)
    offA[mf] = swz((wr * 128 + mf * 16 + lrow) * 64 + cg * 16);
#pragma unroll
  for (int nf = 0; nf < 4; ++nf)
    offB[nf] = swz((wc * 64 + nf * 16 + lrow) * 64 + cg * 16);

  f32x4 acc[8][4] = {};

  stageApart(0); stageBpart(0);
  stageApart(1); stageBpart(1);
  stageApart(2); stageBpart(2);
  asm volatile("s_waitcnt vmcnt(8)" ::: "memory");
  __builtin_amdgcn_s_barrier();
  __builtin_amdgcn_sched_barrier(0);
  s16x8 af_cur[4], bf_cur[4], af_nxt[4], bf_nxt[4], af2[4];
#pragma unroll
  for (int m = 0; m < 4; ++m) af_cur[m] = *(const s16x8*)(ldsA + offA[m]);
#pragma unroll
  for (int n = 0; n < 4; ++n) bf_cur[n] = *(const s16x8*)(ldsB + offB[n]);

  for (int i = 0; i < NH - 1; ++i) {
    const int si  = i & 3;
    const int si1 = (i + 1) & 3;
    const char* pA  = ldsA + (si  << 14);
    const char* pA1 = ldsA + (si1 << 14);
    const char* pB1 = ldsB + (si1 << 14);

    if (i + 2 < NH) { asm volatile("s_waitcnt vmcnt(4)" ::: "memory"); }
    else            { asm volatile("s_waitcnt vmcnt(0)" ::: "memory"); }
    __builtin_amdgcn_s_barrier();
    __builtin_amdgcn_sched_barrier(0);

#pragma unroll
    for (int m = 0; m < 4; ++m) af_nxt[m] = *(const s16x8*)(pA + offA[m + 4]);
#pragma unroll
    for (int n = 0; n < 4; ++n) bf_nxt[n] = *(const s16x8*)(pB1 + offB[n]);
    if (i + 3 < NH) stageApart(i + 3);
    asm volatile("s_waitcnt lgkmcnt(8)" ::: "memory");
    __builtin_amdgcn_sched_barrier(0);
    __builtin_amdgcn_s_setprio(1);
#pragma unroll
    for (int m = 0; m < 4; ++m)
#pragma unroll
      for (int n = 0; n < 4; ++n)
        acc[m][n] = __builtin_amdgcn_mfma_f32_16x16x32_bf16(af_cur[m], bf_cur[n], acc[m][n], 0, 0, 0);
    __builtin_amdgcn_s_setprio(0);

#pragma unroll
    for (int m = 0; m < 4; ++m) af2[m] = *(const s16x8*)(pA1 + offA[m]);
    if (i + 3 < NH) stageBpart(i + 3);
    asm volatile("s_waitcnt lgkmcnt(4)" ::: "memory");
    __builtin_amdgcn_sched_barrier(0);
    __builtin_amdgcn_s_setprio(1);
#pragma unroll
    for (int m = 0; m < 4; ++m)
#pragma unroll
      for (int n = 0; n < 4; ++n)
        acc[m + 4][n] = __builtin_amdgcn_mfma_f32_16x16x32_bf16(af_nxt[m], bf_cur[n], acc[m + 4][n], 0, 0, 0);
    __builtin_amdgcn_s_setprio(0);

#pragma unroll
    for (int m = 0; m < 4; ++m) af_cur[m] = af2[m];
#pragma unroll
    for (int n = 0; n < 4; ++n) bf_cur[n] = bf_nxt[n];
  }

  {
    const char* pA = ldsA + (((NH - 1) & 3) << 14);
    asm volatile("s_waitcnt vmcnt(0)" ::: "memory");
    __builtin_amdgcn_s_barrier();
    __builtin_amdgcn_sched_barrier(0);
#pragma unroll
    for (int m = 0; m < 4; ++m) af_nxt[m] = *(const s16x8*)(pA + offA[m + 4]);
    asm volatile("s_waitcnt lgkmcnt(4)" ::: "memory");
    __builtin_amdgcn_sched_barrier(0);
    __builtin_amdgcn_s_setprio(1);
#pragma unroll
    for (int m = 0; m < 4; ++m)
#pragma unroll
      for (int n = 0; n < 4; ++n)
        acc[m][n] = __builtin_amdgcn_mfma_f32_16x16x32_bf16(af_cur[m], bf_cur[n], acc[m][n], 0, 0, 0);
    __builtin_amdgcn_s_setprio(0);
    asm volatile("s_waitcnt lgkmcnt(0)" ::: "memory");
    __builtin_amdgcn_sched_barrier(0);
    __builtin_amdgcn_s_setprio(1);
#pragma unroll
    for (int m = 0; m < 4; ++m)
#pragma unroll
      for (int n = 0; n < 4; ++n)
        acc[m + 4][n] = __builtin_amdgcn_mfma_f32_16x16x32_bf16(af_nxt[m], bf_cur[n], acc[m + 4][n], 0, 0, 0);
    __builtin_amdgcn_s_setprio(0);
  }

  const int ecol0 = n0 + wc * 64 + lrow;
  float bz[4];
#pragma unroll
  for (int nf = 0; nf < 4; ++nf) bz[nf] = bias[ecol0 + nf * 16];
  const int erow0 = m0 + wr * 128 + (cg << 2);

#pragma unroll
  for (int mf = 0; mf < 8; ++mf)
#pragma unroll
    for (int nf = 0; nf < 4; ++nf)
#pragma unroll
      for (int r2 = 0; r2 < 4; ++r2) {
        const int row = erow0 + mf * 16 + r2;
        const size_t idx = (size_t)row * N + (ecol0 + nf * 16);
        out16[idx] = f2bf(acc[mf][nf][r2] + bz[nf]);
      }
}

// ---------------------------------------------------------------------------
// 128x128 PIPELINED GEMM — fc1/fc2/out/ff1/ff2. 512 thr, 8 waves (2Mx4N),
// per-wave 64x32 (acc[4][2]). Ring-4 half-slots [128][32] bf16 (8KB)/matrix
// -> 64KB LDS -> 2 blocks/CU. Counted vmcnt(2)/half-step.
// ---------------------------------------------------------------------------
template<int EPI>
__global__ __launch_bounds__(512, 4)
void gemm128p(const short* __restrict__ A, const short* __restrict__ Bw,
              const float* __restrict__ bias, const short* __restrict__ res16,
              const float* __restrict__ bnG, const float* __restrict__ bnB,
              const float* __restrict__ bnM, const float* __restrict__ bnV,
              const int* __restrict__ hdr, short* __restrict__ out16,
              int N, int K) {
  extern __shared__ char smem[];                 // 65536 B
  const int tid  = threadIdx.x;
  const int lane = tid & 63;
  const int w    = tid >> 6;
  const int wr   = w >> 2;
  const int wc   = w & 3;
  const int lrow = lane & 15;
  const int cg   = lane >> 4;
  const int NH   = K >> 5;
  const int gx   = gridDim.x;

  const int p = blockIdx.y * gx + blockIdx.x;
  const int nwork = (hdr[1] >> 7) * gx;
  if (p >= nwork) return;
  const int xcd = p & 7, off = p >> 3;
  const int q = nwork >> 3, r = nwork & 7;
  const int wg = (xcd < r ? xcd * (q + 1) : r * (q + 1) + (xcd - r) * q) + off;
  const int m0 = (wg / gx) * 128;
  const int n0 = (wg % gx) * 128;

  const int ldb = K * 2;
  size_t gA, gB;
  {
    const int pp = tid * 16;
    const int l = swz(pp);
    const int row = l >> 6, colb = l & 63;
    gA = (size_t)(m0 + row) * ldb + colb;
    gB = (size_t)(n0 + row) * ldb + colb;
  }
  const char* Ab = (const char*)A;
  const char* Bb = (const char*)Bw;
  char* ldsA = smem;                             // 4 x 8KB
  char* ldsB = smem + 32768;                     // 4 x 8KB
  const int wofs = w * 1024;

  auto stageA = [&](int i) {
    stage16((const short*)(Ab + gA + i * 64), (short*)(ldsA + ((i & 3) << 13) + wofs));
  };
  auto stageB = [&](int i) {
    stage16((const short*)(Bb + gB + i * 64), (short*)(ldsB + ((i & 3) << 13) + wofs));
  };

  int offA[4], offB[2];
#pragma unroll
  for (int mf = 0; mf < 4; ++mf)
    offA[mf] = swz((wr * 64 + mf * 16 + lrow) * 64 + cg * 16);
#pragma unroll
  for (int nf = 0; nf < 2; ++nf)
    offB[nf] = swz((wc * 32 + nf * 16 + lrow) * 64 + cg * 16);

  f32x4 acc[4][2] = {};

  stageA(0); stageB(0);
  stageA(1); stageB(1);
  stageA(2); stageB(2);
  asm volatile("s_waitcnt vmcnt(4)" ::: "memory");
  __builtin_amdgcn_s_barrier();
  __builtin_amdgcn_sched_barrier(0);
  s16x8 af_cur[2], bf_cur[2], af_nxt[2], bf_nxt[2], af2[2];
#pragma unroll
  for (int m = 0; m < 2; ++m) af_cur[m] = *(const s16x8*)(ldsA + offA[m]);
#pragma unroll
  for (int n = 0; n < 2; ++n) bf_cur[n] = *(const s16x8*)(ldsB + offB[n]);

  for (int i = 0; i < NH - 1; ++i) {
    const char* pA  = ldsA + ((i & 3) << 13);
    const char* pA1 = ldsA + (((i + 1) & 3) << 13);
    const char* pB1 = ldsB + (((i + 1) & 3) << 13);

    if (i + 2 < NH) { asm volatile("s_waitcnt vmcnt(2)" ::: "memory"); }
    else            { asm volatile("s_waitcnt vmcnt(0)" ::: "memory"); }
    __builtin_amdgcn_s_barrier();
    __builtin_amdgcn_sched_barrier(0);

#pragma unroll
    for (int m = 0; m < 2; ++m) af_nxt[m] = *(const s16x8*)(pA + offA[m + 2]);
#pragma unroll
    for (int n = 0; n < 2; ++n) bf_nxt[n] = *(const s16x8*)(pB1 + offB[n]);
    if (i + 3 < NH) stageA(i + 3);
    asm volatile("s_waitcnt lgkmcnt(4)" ::: "memory");
    __builtin_amdgcn_sched_barrier(0);
    __builtin_amdgcn_s_setprio(1);
#pragma unroll
    for (int m = 0; m < 2; ++m)
#pragma unroll
      for (int n = 0; n < 2; ++n)
        acc[m][n] = __builtin_amdgcn_mfma_f32_16x16x32_bf16(af_cur[m], bf_cur[n], acc[m][n], 0, 0, 0);
    __builtin_amdgcn_s_setprio(0);

#pragma unroll
    for (int m = 0; m < 2; ++m) af2[m] = *(const s16x8*)(pA1 + offA[m]);
    if (i + 3 < NH) stageB(i + 3);
    asm volatile("s_waitcnt lgkmcnt(2)" ::: "memory");
    __builtin_amdgcn_sched_barrier(0);
    __builtin_amdgcn_s_setprio(1);
#pragma unroll
    for (int m = 0; m < 2; ++m)
#pragma unroll
      for (int n = 0; n < 2; ++n)
        acc[m + 2][n] = __builtin_amdgcn_mfma_f32_16x16x32_bf16(af_nxt[m], bf_cur[n], acc[m + 2][n], 0, 0, 0);
    __builtin_amdgcn_s_setprio(0);

#pragma unroll
    for (int m = 0; m < 2; ++m) af_cur[m] = af2[m];
#pragma unroll
    for (int n = 0; n < 2; ++n) bf_cur[n] = bf_nxt[n];
  }

  {
    const char* pA = ldsA + (((NH - 1) & 3) << 13);
    asm volatile("s_waitcnt vmcnt(0)" ::: "memory");
    __builtin_amdgcn_s_barrier();
    __builtin_amdgcn_sched_barrier(0);
#pragma unroll
    for (int m = 0; m < 2; ++m) af_nxt[m] = *(const s16x8*)(pA + offA[m + 2]);
    asm volatile("s_waitcnt lgkmcnt(2)" ::: "memory");
    __builtin_amdgcn_sched_barrier(0);
    __builtin_amdgcn_s_setprio(1);
#pragma unroll
    for (int m = 0; m < 2; ++m)
#pragma unroll
      for (int n = 0; n < 2; ++n)
        acc[m][n] = __builtin_amdgcn_mfma_f32_16x16x32_bf16(af_cur[m], bf_cur[n], acc[m][n], 0, 0, 0);
    __builtin_amdgcn_s_setprio(0);
    asm volatile("s_waitcnt lgkmcnt(0)" ::: "memory");
    __builtin_amdgcn_sched_barrier(0);
    __builtin_amdgcn_s_setprio(1);
#pragma unroll
    for (int m = 0; m < 2; ++m)
#pragma unroll
      for (int n = 0; n < 2; ++n)
        acc[m + 2][n] = __builtin_amdgcn_mfma_f32_16x16x32_bf16(af_nxt[m], bf_cur[n], acc[m + 2][n], 0, 0, 0);
    __builtin_amdgcn_s_setprio(0);
  }

  // epilogue
  const int ecol0 = n0 + wc * 32 + lrow;
  const int erow0 = m0 + wr * 64 + (cg << 2);
  float bz[2], sc[2], sh[2];
#pragma unroll
  for (int nf = 0; nf < 2; ++nf) {
    const int c = ecol0 + nf * 16;
    if constexpr (EPI == EPI_H1) {
      const float s = bnG[c] * rsqrtf(bnV[c] + BN_EPSF);
      sc[nf] = s;
      sh[nf] = (bias[c] - bnM[c]) * s + bnB[c];
    } else {
      bz[nf] = bias[c];
    }
  }
  (void)bnG; (void)bnB; (void)bnM; (void)bnV;

#pragma unroll
  for (int mf = 0; mf < 4; ++mf) {
#pragma unroll
    for (int nf = 0; nf < 2; ++nf) {
#pragma unroll
      for (int r2 = 0; r2 < 4; ++r2) {
        const int row = erow0 + mf * 16 + r2;
        const size_t idx = (size_t)row * N + (ecol0 + nf * 16);
        if constexpr (EPI == EPI_H1) {
          out16[idx] = f2bf(fmaxf(acc[mf][nf][r2] * sc[nf] + sh[nf], 0.f));
        } else {
          const float v = acc[mf][nf][r2] + bz[nf];
          if constexpr (EPI == EPI_PLAIN) {
            out16[idx] = f2bf(v);
          } else if constexpr (EPI == EPI_FF1) {
            out16[idx] = f2bf(fmaxf(v, 0.f));
          } else {  // EPI_RES: bf16 out = v + bf16 residual
            out16[idx] = f2bf(v + bf2f(res16[idx]));
          }
        }
      }
    }
  }
}

// ---------------------------------------------------------------------------
// top-2 mean per (b, d): thread owns 4 contiguous cols, one s16x4 load/row
// ---------------------------------------------------------------------------
__global__ __launch_bounds__(256)
void topk_kernel(const short* __restrict__ emb16, const int* __restrict__ lens,
                 const int* __restrict__ cum, float* __restrict__ er) {
  const int b = blockIdx.x;
  const int len = lens[b];
  const size_t base = (size_t)cum[b] * 1024;
  const int d0 = threadIdx.x * 4;
  float m1[4], m2[4];
#pragma unroll
  for (int k = 0; k < 4; ++k) { m1[k] = -3.0e38f; m2[k] = -3.0e38f; }
  for (int l = 0; l < len; ++l) {
    s16x4 hv = *(const s16x4*)&emb16[base + (size_t)l * 1024 + d0];
#pragma unroll
    for (int k = 0; k < 4; ++k) {
      const float v = bf2f(hv[k]);
      if (v > m1[k]) { m2[k] = m1[k]; m1[k] = v; }
      else           { m2[k] = fmaxf(m2[k], v); }
    }
  }
  f32x4 res;
#pragma unroll
  for (int k = 0; k < 4; ++k) res[k] = 0.5f * (m1[k] + m2[k]);
  *(f32x4*)&er[(size_t)b * 1024 + d0] = res;
}

// ---------------------------------------------------------------------------
// Fused attention on compacted rows: one block per (b,h), len-aware:
// dead Q/K staging rounds skipped, V loads predicated (zeros written),
// waves whose 16 output rows are all >= len skip compute (barriers kept).
// ---------------------------------------------------------------------------
__global__ __launch_bounds__(256)
void attn_kernel(const short* __restrict__ qkv, const int* __restrict__ lens,
                 const int* __restrict__ cum, short* __restrict__ ctx) {
  __shared__ short Qs[64 * 128];
  __shared__ short Ks[64 * 128];
  __shared__ short Vt[128 * 64];
  const int tid  = threadIdx.x;
  const int lane = tid & 63;
  const int wave = tid >> 6;
  const int b = blockIdx.x >> 3;
  const int h = blockIdx.x & 7;
  const int len = lens[b];
  const int rb  = cum[b];
  const size_t qb = (size_t)rb * 3072 + h * 128;

  { // stage Q,K rows; skip 4-row groups entirely above len
    const int rr = wave * 4 + (lane >> 4);
    const int cc = (lane & 15) * 8;
#pragma unroll
    for (int r = 0; r < 4; ++r) {
      if (r * 16 + wave * 4 < len) {
        stage16(qkv + qb +        (size_t)(r * 16 + rr) * 3072 + cc, &Qs[(r * 16 + wave * 4) * 128]);
        stage16(qkv + qb + 1024 + (size_t)(r * 16 + rr) * 3072 + cc, &Ks[(r * 16 + wave * 4) * 128]);
      }
    }
  }
#pragma unroll
  for (int i = 0; i < 2; ++i) {
    const int c  = i * 256 + tid;
    const int lp = c >> 4;
    const int dg = c & 15;
    const short* src = qkv + qb + 2048 + (size_t)(2 * lp) * 3072 + dg * 8;
    const bool ok0 = (2 * lp)     < len;
    const bool ok1 = (2 * lp + 1) < len;
    s16x8 v0 = {}, v1 = {};
    if (ok0) v0 = *(const s16x8*)src;
    if (ok1) v1 = *(const s16x8*)(src + 3072);
#pragma unroll
    for (int j = 0; j < 8; ++j) {
      const uint32_t pk = ((uint32_t)(uint16_t)v0[j]) | (((uint32_t)(uint16_t)v1[j]) << 16);
      *(uint32_t*)&Vt[(dg * 8 + j) * 64 + 2 * lp] = pk;
    }
  }
  __syncthreads();

  const int lrow = lane & 15;
  const int lk8  = (lane >> 4) * 8;
  const bool active = (wave * 16) < len;

  if (active) {
    f32x4 sacc[4] = {};
#pragma unroll
    for (int ks = 0; ks < 4; ++ks) {
      s16x8 aq = *(const s16x8*)&Qs[(wave * 16 + lrow) * 128 + ks * 32 + lk8];
#pragma unroll
      for (int n = 0; n < 4; ++n) {
        s16x8 bk = *(const s16x8*)&Ks[(n * 16 + lrow) * 128 + ks * 32 + lk8];
        sacc[n] = __builtin_amdgcn_mfma_f32_16x16x32_bf16(aq, bk, sacc[n], 0, 0, 0);
      }
    }

    const float scale = 0.08838834764831845f;
#pragma unroll
    for (int r = 0; r < 4; ++r) {
      float sv[4];
      float mx = -1e30f;
#pragma unroll
      for (int n = 0; n < 4; ++n) {
        float v = sacc[n][r] * scale;
        if (n * 16 + lrow >= len) v = -1e30f;
        sv[n] = v;
        mx = fmaxf(mx, v);
      }
      mx = fmaxf(mx, __shfl_xor(mx, 1));
      mx = fmaxf(mx, __shfl_xor(mx, 2));
      mx = fmaxf(mx, __shfl_xor(mx, 4));
      mx = fmaxf(mx, __shfl_xor(mx, 8));
      float pv[4], sum = 0.f;
#pragma unroll
      for (int n = 0; n < 4; ++n) { pv[n] = __expf(sv[n] - mx); sum += pv[n]; }
      sum += __shfl_xor(sum, 1);
      sum += __shfl_xor(sum, 2);
      sum += __shfl_xor(sum, 4);
      sum += __shfl_xor(sum, 8);
      const float inv = 1.f / sum;
      const int prow = wave * 16 + ((lane >> 4) << 2) + r;
#pragma unroll
      for (int n = 0; n < 4; ++n)
        Qs[prow * 128 + n * 16 + lrow] = f2bf(pv[n] * inv);
    }
  }
  __syncthreads();

  if (active) {
    f32x4 oacc[8] = {};
#pragma unroll
    for (int ks = 0; ks < 2; ++ks) {
      s16x8 ap = *(const s16x8*)&Qs[(wave * 16 + lrow) * 128 + ks * 32 + lk8];
#pragma unroll
      for (int n = 0; n < 8; ++n) {
        s16x8 bv = *(const s16x8*)&Vt[(n * 16 + lrow) * 64 + ks * 32 + lk8];
        oacc[n] = __builtin_amdgcn_mfma_f32_16x16x32_bf16(ap, bv, oacc[n], 0, 0, 0);
      }
    }
    const size_t ob = (size_t)rb * 1024 + h * 128;
#pragma unroll
    for (int n = 0; n < 8; ++n)
#pragma unroll
      for (int r = 0; r < 4; ++r) {
        const int row = wave * 16 + ((lane >> 4) << 2) + r;
        if (row < len)
          ctx[ob + (size_t)row * 1024 + n * 16 + lrow] = f2bf(oacc[n][r]);
      }
  }
}

// ---------------------------------------------------------------------------
// LayerNorm over 1024 (LN1): bf16 in/out; grid-stride over compacted rows
// ---------------------------------------------------------------------------
__global__ __launch_bounds__(256)
void ln_kernel(const short* __restrict__ x16, const float* __restrict__ gg,
               const float* __restrict__ bb, const int* __restrict__ hdr,
               short* __restrict__ y16) {
  __shared__ float red[8];
  const int tid = threadIdx.x;
  const int lane = tid & 63;
  const int wave = tid >> 6;
  float4 g4 = ((const float4*)gg)[tid];
  float4 b4 = ((const float4*)bb)[tid];
  const int mcpad = hdr[1];
  for (int row = blockIdx.x; row < mcpad; row += gridDim.x) {
    const size_t base = (size_t)row * 1024;
    s16x4 hv = ((const s16x4*)(x16 + base))[tid];
    const float v0 = bf2f(hv[0]), v1 = bf2f(hv[1]), v2 = bf2f(hv[2]), v3 = bf2f(hv[3]);
    float s1 = v0 + v1 + v2 + v3;
    float s2 = v0 * v0 + v1 * v1 + v2 * v2 + v3 * v3;
#pragma unroll
    for (int o = 1; o < 64; o <<= 1) { s1 += __shfl_xor(s1, o); s2 += __shfl_xor(s2, o); }
    if (lane == 0) { red[wave] = s1; red[wave + 4] = s2; }
    __syncthreads();
    s1 = red[0] + red[1] + red[2] + red[3];
    s2 = red[4] + red[5] + red[6] + red[7];
    const float mu  = s1 * (1.f / 1024.f);
    const float var = fmaxf(s2 * (1.f / 1024.f) - mu * mu, 0.f);
    const float rs  = rsqrtf(var + LN_EPSF);
    s16x4 hh;
    hh[0] = f2bf((v0 - mu) * rs * g4.x + b4.x);
    hh[1] = f2bf((v1 - mu) * rs * g4.y + b4.y);
    hh[2] = f2bf((v2 - mu) * rs * g4.z + b4.z);
    hh[3] = f2bf((v3 - mu) * rs * g4.w + b4.w);
    ((s16x4*)(y16 + base))[tid] = hh;
    __syncthreads();
  }
}

// ---------------------------------------------------------------------------
// fused LN2 + avg-pool over compacted valid tokens + mix + L2 normalize
// ---------------------------------------------------------------------------
__global__ __launch_bounds__(256)
void ln2_final_kernel(const short* __restrict__ x16, const float* __restrict__ gg,
                      const float* __restrict__ bb, const float* __restrict__ er,
                      const int* __restrict__ lens, const int* __restrict__ cum,
                      float* __restrict__ out) {
  __shared__ float part[4][1024];
  __shared__ float red[4];
  const int tid = threadIdx.x, lane = tid & 63, w = tid >> 6;
  const int b = blockIdx.x, len = lens[b];
  const size_t rb = (size_t)cum[b];
  float4 g4[4], b4[4];
#pragma unroll
  for (int k = 0; k < 4; ++k) {
    g4[k] = ((const float4*)gg)[k * 64 + lane];
    b4[k] = ((const float4*)bb)[k * 64 + lane];
  }
  float4 acc[4];
#pragma unroll
  for (int k = 0; k < 4; ++k) acc[k] = make_float4(0.f, 0.f, 0.f, 0.f);

  for (int l = w; l < len; l += 4) {
    const s16x4* row = (const s16x4*)(x16 + (rb + l) * 1024);
    float4 v[4]; float s1 = 0.f, s2 = 0.f;
#pragma unroll
    for (int k = 0; k < 4; ++k) {
      s16x4 hv = row[k * 64 + lane];
      v[k] = make_float4(bf2f(hv[0]), bf2f(hv[1]), bf2f(hv[2]), bf2f(hv[3]));
      s1 += v[k].x + v[k].y + v[k].z + v[k].w;
      s2 += v[k].x * v[k].x + v[k].y * v[k].y + v[k].z * v[k].z + v[k].w * v[k].w;
    }
#pragma unroll
    for (int o = 1; o < 64; o <<= 1) { s1 += __shfl_xor(s1, o); s2 += __shfl_xor(s2, o); }
    const float mu = s1 * (1.f / 1024.f);
    const float rs = rsqrtf(fmaxf(s2 * (1.f / 1024.f) - mu * mu, 0.f) + LN_EPSF);
#pragma unroll
    for (int k = 0; k < 4; ++k) {
      acc[k].x += (v[k].x - mu) * rs * g4[k].x + b4[k].x;
      acc[k].y += (v[k].y - mu) * rs * g4[k].y + b4[k].y;
      acc[k].z += (v[k].z - mu) * rs * g4[k].z + b4[k].z;
      acc[k].w += (v[k].w - mu) * rs * g4[k].w + b4[k].w;
    }
  }
#pragma unroll
  for (int k = 0; k < 4; ++k)
    ((float4*)&part[w][0])[k * 64 + lane] = acc[k];
  __syncthreads();

  float4 s = ((const float4*)&part[0][0])[tid];
#pragma unroll
  for (int w2 = 1; w2 < 4; ++w2) {
    float4 t4 = ((const float4*)&part[0][0])[w2 * 256 + tid];
    s.x += t4.x; s.y += t4.y; s.z += t4.z; s.w += t4.w;
  }
  const float il = 0.5f / (float)len;
  float4 e = ((const float4*)(er + (size_t)b * 1024))[tid];
  const float o0 = 0.5f * e.x + s.x * il;
  const float o1 = 0.5f * e.y + s.y * il;
  const float o2 = 0.5f * e.z + s.z * il;
  const float o3 = 0.5f * e.w + s.w * il;
  float ss = o0 * o0 + o1 * o1 + o2 * o2 + o3 * o3;
#pragma unroll
  for (int o = 1; o < 64; o <<= 1) ss += __shfl_xor(ss, o);
  if (lane == 0) red[w] = ss;
  __syncthreads();
  ss = red[0] + red[1] + red[2] + red[3];
  const float nrm = 1.f / (sqrtf(ss) + 1e-8f);
  ((float4*)(out + (size_t)b * 1024))[tid] = make_float4(o0 * nrm, o1 * nrm, o2 * nrm, o3 * nrm);
}

// ---------------------------------------------------------------------------
extern "C" void kernel_launch(void* const* d_in, const int* in_sizes, int n_in,
                              void* d_out, int out_size, void* d_ws, size_t ws_size,
                              hipStream_t stream) {
  (void)in_sizes; (void)n_in; (void)out_size; (void)ws_size;
  const float* images = (const float*)d_in[0];
  const int*   lens   = (const int*)d_in[1];
  const float* fc1_w = (const float*)d_in[2];
  const float* fc1_b = (const float*)d_in[3];
  const float* bn_g  = (const float*)d_in[4];
  const float* bn_b  = (const float*)d_in[5];
  const float* bn_m  = (const float*)d_in[6];
  const float* bn_v  = (const float*)d_in[7];
  const float* fc2_w = (const float*)d_in[8];
  const float* fc2_b = (const float*)d_in[9];
  const float* in_w  = (const float*)d_in[10];
  const float* in_b  = (const float*)d_in[11];
  const float* out_w = (const float*)d_in[12];
  const float* out_b = (const float*)d_in[13];
  const float* ln1_g = (const float*)d_in[14];
  const float* ln1_b = (const float*)d_in[15];
  const float* ff1_w = (const float*)d_in[16];
  const float* ff1_b = (const float*)d_in[17];
  const float* ff2_w = (const float*)d_in[18];
  const float* ff2_b = (const float*)d_in[19];
  const float* ln2_g = (const float*)d_in[20];
  const float* ln2_b = (const float*)d_in[21];
  float* out = (float*)d_out;

  char* ws = (char*)d_ws;
  const size_t OFF_IMG16 = 0;                          // 67108864 (img16 / x1sum / x2sum)
  const size_t OFF_FC1W  = 67108864;                   // 2097152
  const size_t OFF_FC2W  = OFF_FC1W + 2097152;         // 1048576
  const size_t OFF_INW   = OFF_FC2W + 1048576;         // 6291456
  const size_t OFF_OUTW  = OFF_INW  + 6291456;         // 2097152
  const size_t OFF_FF1W  = OFF_OUTW + 2097152;         // 2097152
  const size_t OFF_FF2W  = OFF_FF1W + 2097152;         // 2097152
  const size_t OFF_H1    = OFF_FF2W + 2097152;         // 16777216
  const size_t OFF_EMB16 = OFF_H1 + 16777216;          // 33554432
  const size_t OFF_QKV   = OFF_EMB16 + 33554432;       // 101056512 (16448 rows)
  const size_t OFF_CTX   = OFF_QKV + 101056512;        // 33554432
  const size_t OFF_ERES  = OFF_CTX + 33554432;         // 1048576
  const size_t OFF_HDR   = OFF_ERES + 1048576;         // 256
  const size_t OFF_CUM   = OFF_HDR + 256;              // 1024
  const size_t OFF_TOK   = OFF_CUM + 1024;             // 65536

  short* img16  = (short*)(ws + OFF_IMG16);
  short* fc1w16 = (short*)(ws + OFF_FC1W);
  short* fc2w16 = (short*)(ws + OFF_FC2W);
  short* inw16  = (short*)(ws + OFF_INW);
  short* outw16 = (short*)(ws + OFF_OUTW);
  short* ff1w16 = (short*)(ws + OFF_FF1W);
  short* ff2w16 = (short*)(ws + OFF_FF2W);
  short* h1     = (short*)(ws + OFF_H1);
  short* emb16  = (short*)(ws + OFF_EMB16);
  short* qkv16  = (short*)(ws + OFF_QKV);
  short* ctx16  = (short*)(ws + OFF_CTX);
  float* embres = (float*)(ws + OFF_ERES);
  int*   hdr    = (int*)(ws + OFF_HDR);
  int*   cum    = (int*)(ws + OFF_CUM);
  int*   tokmap = (int*)(ws + OFF_TOK);
  short* x1sum = (short*)(ws + OFF_IMG16);  // pre-LN1 bf16 (img16 dead)
  short* x1h   = emb16;                     // post-LN1 bf16 (emb16 dead after out-proj)
  short* ffh   = ctx16;                     // ffn hidden    (ctx16 dead)
  short* x2sum = (short*)(ws + OFF_IMG16);  // pre-LN2 bf16  (x1sum dead)

  const dim3 blk(256);
  const size_t SMEM256 = 131072;
  const size_t SMEM128 = 65536;

  // compaction metadata (prefix + tokmap fused)
  prefix_kernel<<<1, blk, 0, stream>>>(lens, cum, hdr, tokmap);

  // converts: gathered images + all six weights in one kernel
  CvtArgs ca;
  ca.src[0] = fc1_w; ca.dst[0] = fc1w16; ca.n4[0] = 1048576 / 4;
  ca.src[1] = fc2_w; ca.dst[1] = fc2w16; ca.n4[1] = 524288 / 4;
  ca.src[2] = in_w;  ca.dst[2] = inw16;  ca.n4[2] = 3145728 / 4;
  ca.src[3] = out_w; ca.dst[3] = outw16; ca.n4[3] = 1048576 / 4;
  ca.src[4] = ff1_w; ca.dst[4] = ff1w16; ca.n4[4] = 1048576 / 4;
  ca.src[5] = ff2_w; ca.dst[5] = ff2w16; ca.n4[5] = 1048576 / 4;
  cvt_gather_kernel<<<2048, blk, 0, stream>>>(images, tokmap, hdr, img16, ca);

  // fc1 + BN + ReLU -> h1 (bf16, compacted)
  gemm128p<EPI_H1><<<dim3(4, 128), 512, SMEM128, stream>>>(
      img16, fc1w16, fc1_b, nullptr, bn_g, bn_b, bn_m, bn_v, hdr, h1, 512, 2048);
  // fc2 -> emb16 (compacted)
  gemm128p<EPI_PLAIN><<<dim3(8, 128), 512, SMEM128, stream>>>(
      h1, fc2w16, fc2_b, nullptr, nullptr, nullptr, nullptr, nullptr, hdr, emb16, 1024, 512);
  // top-2 pooling over compacted emb
  topk_kernel<<<256, blk, 0, stream>>>(emb16, lens, cum, embres);
  // qkv projection (256x256 pipelined — measured faster than 128x128 here)
  gemm256<<<dim3(12, 64), 512, SMEM256, stream>>>(
      emb16, inw16, in_b, hdr, qkv16, 3072, 1024);
  // attention (compacted rows, len-aware)
  attn_kernel<<<2048, blk, 0, stream>>>(qkv16, lens, cum, ctx16);
  // out projection + residual(emb16) -> pre-LN1 bf16
  gemm128p<EPI_RES><<<dim3(8, 128), 512, SMEM128, stream>>>(
      ctx16, outw16, out_b, emb16, nullptr, nullptr, nullptr, nullptr, hdr, x1sum, 1024, 1024);
  ln_kernel<<<2048, blk, 0, stream>>>(x1sum, ln1_g, ln1_b, hdr, x1h);
  // ffn
  gemm128p<EPI_FF1><<<dim3(8, 128), 512, SMEM128, stream>>>(
      x1h, ff1w16, ff1_b, nullptr, nullptr, nullptr, nullptr, nullptr, hdr, ffh, 1024, 1024);
  gemm128p<EPI_RES><<<dim3(8, 128), 512, SMEM128, stream>>>(
      ffh, ff2w16, ff2_b, x1h, nullptr, nullptr, nullptr, nullptr, hdr, x2sum, 1024, 1024);
  // fused LN2 + avg-pool + mix + normalize
  ln2_final_kernel<<<256, blk, 0, stream>>>(x2sum, ln2_g, ln2_b, embres, lens, cum, out);
}

// Round 13
// 324.960 us; speedup vs baseline: 1.3745x; 1.0125x over previous
//
#include <hip/hip_runtime.h>
#include <stdint.h>
#include <stddef.h>

// ---------------------------------------------------------------------------
// EncoderImageAggr: bf16-MFMA pipeline for MI355X (gfx950)
// B=256 L=64 IMG_DIM=2048 D=1024 H=8 DH=128. All GEMMs are C = A @ W^T.
// Round 13: topk fused into ln2_final (in-register top-2, no embres buffer);
// x1h relocated to the dead qkv region so emb16 survives to the end.
// ---------------------------------------------------------------------------

typedef short s16x8 __attribute__((ext_vector_type(8)));
typedef short s16x4 __attribute__((ext_vector_type(4)));
typedef float f32x4 __attribute__((ext_vector_type(4)));

#define LN_EPSF 1e-5f
#define BN_EPSF 1e-5f

__device__ __forceinline__ short f2bf(float f) {
  union { float f; uint32_t u; } x; x.f = f;
  uint32_t r = x.u + 0x7fffu + ((x.u >> 16) & 1u);   // RNE
  return (short)(r >> 16);
}
__device__ __forceinline__ float bf2f(short s) {
  union { uint32_t u; float f; } x; x.u = ((uint32_t)(uint16_t)s) << 16;
  return x.f;
}

typedef const __attribute__((address_space(1))) short glb_s16_t;
typedef __attribute__((address_space(3))) short lds_s16_t;

__device__ __forceinline__ void stage16(const short* g, short* l) {
  __builtin_amdgcn_global_load_lds((glb_s16_t*)g, (lds_s16_t*)l, 16, 0, 0);
}

// involution swizzle for 64B-row LDS slots (measured 0 bank conflicts)
__device__ __forceinline__ int swz(int off) {
  return off ^ (((off >> 7) & 3) << 4);
}

enum { EPI_PLAIN = 0, EPI_FF1 = 3, EPI_RES = 4, EPI_H1 = 5 };

// ---------------------------------------------------------------------------
// prefix-sum of lens -> cum (exclusive), hdr = {Mc, Mc_pad}; build tokmap
// ---------------------------------------------------------------------------
__global__ __launch_bounds__(256)
void prefix_kernel(const int* __restrict__ lens, int* __restrict__ cum,
                   int* __restrict__ hdr, int* __restrict__ tokmap) {
  __shared__ int wsum[4];
  __shared__ int sc[256];
  __shared__ int mcpad;
  const int tid = threadIdx.x, lane = tid & 63, wave = tid >> 6;
  const int mylen = lens[tid];
  int v = mylen;
#pragma unroll
  for (int o = 1; o < 64; o <<= 1) {
    int t = __shfl_up(v, o);
    if (lane >= o) v += t;
  }
  if (lane == 63) wsum[wave] = v;
  __syncthreads();
  int add = 0;
#pragma unroll
  for (int w2 = 0; w2 < 4; ++w2) if (w2 < wave) add += wsum[w2];
  const int incl = v + add;
  const int excl = incl - mylen;
  cum[tid] = excl;
  sc[tid] = excl;
  if (tid == 255) {
    hdr[0] = incl;                       // Mc
    mcpad  = (incl + 255) & ~255;        // Mc_pad (multiple of 256)
    hdr[1] = mcpad;
  }
  __syncthreads();
  for (int l = 0; l < mylen; ++l) tokmap[excl + l] = tid * 64 + l;
  const int mc = sc[255] + lens[255];
  for (int i = mc + tid; i < mcpad; i += 256) tokmap[i] = 0;
}

// ---------------------------------------------------------------------------
// gathered fp32 -> bf16 convert of valid image rows (compacted) + weights
// ---------------------------------------------------------------------------
struct CvtArgs { const float* src[6]; short* dst[6]; int n4[6]; };

__global__ __launch_bounds__(256)
void cvt_gather_kernel(const float* __restrict__ img,
                       const int* __restrict__ tokmap,
                       const int* __restrict__ hdr, short* __restrict__ out,
                       CvtArgs a) {
  const int n4 = hdr[1] << 9;                    // Mc_pad * 512 float4s
  const int stride = gridDim.x * 256;
  for (int i = blockIdx.x * 256 + threadIdx.x; i < n4; i += stride) {
    const int row = i >> 9, col = i & 511;
    float4 v = ((const float4*)img)[(size_t)tokmap[row] * 512 + col];
    s16x4 h; h[0] = f2bf(v.x); h[1] = f2bf(v.y); h[2] = f2bf(v.z); h[3] = f2bf(v.w);
    ((s16x4*)out)[i] = h;
  }
#pragma unroll
  for (int s = 0; s < 6; ++s) {
    const int n = a.n4[s];
    const float4* in = (const float4*)a.src[s];
    s16x4* outp = (s16x4*)a.dst[s];
    for (int i = blockIdx.x * 256 + threadIdx.x; i < n; i += stride) {
      float4 v = in[i];
      s16x4 h; h[0] = f2bf(v.x); h[1] = f2bf(v.y); h[2] = f2bf(v.z); h[3] = f2bf(v.w);
      outp[i] = h;
    }
  }
}

// ---------------------------------------------------------------------------
// 256x256 pipelined GEMM — qkv only. 512 thr, 8 waves (2Mx4N), per-wave
// 128x64. Ring-4 half-slots [256][32]; counted vmcnt(4); chunked XCD swizzle.
// ---------------------------------------------------------------------------
__global__ __launch_bounds__(512, 2)
void gemm256(const short* __restrict__ A, const short* __restrict__ Bw,
             const float* __restrict__ bias, const int* __restrict__ hdr,
             short* __restrict__ out16, int N, int K) {
  extern __shared__ char smem[];                 // 131072 B
  const int tid  = threadIdx.x;
  const int lane = tid & 63;
  const int w    = tid >> 6;
  const int wr   = w >> 2;
  const int wc   = w & 3;
  const int lrow = lane & 15;
  const int cg   = lane >> 4;
  const int NH   = K >> 5;
  const int gx   = gridDim.x;

  const int p = blockIdx.y * gx + blockIdx.x;
  const int nwork = (hdr[1] >> 8) * gx;
  if (p >= nwork) return;
  const int xcd = p & 7, off = p >> 3;
  const int q = nwork >> 3, r = nwork & 7;
  const int wg = (xcd < r ? xcd * (q + 1) : r * (q + 1) + (xcd - r) * q) + off;
  const int m0 = (wg / gx) * 256;
  const int n0 = (wg % gx) * 256;

  const int ldb = K * 2;
  size_t gA[2], gB[2];
#pragma unroll
  for (int j = 0; j < 2; ++j) {
    const int pp = tid * 16 + j * 8192;
    const int l = swz(pp);
    const int row = l >> 6, colb = l & 63;
    gA[j] = (size_t)(m0 + row) * ldb + colb;
    gB[j] = (size_t)(n0 + row) * ldb + colb;
  }
  const char* Ab = (const char*)A;
  const char* Bb = (const char*)Bw;
  char* ldsA = smem;
  char* ldsB = smem + 65536;
  const int wofs = w * 1024;

  auto stageApart = [&](int i) {
    const int rg = ((i & 3) << 14) + wofs;
    const int ko = i * 64;
    stage16((const short*)(Ab + gA[0] + ko), (short*)(ldsA + rg));
    stage16((const short*)(Ab + gA[1] + ko), (short*)(ldsA + rg + 8192));
  };
  auto stageBpart = [&](int i) {
    const int rg = ((i & 3) << 14) + wofs;
    const int ko = i * 64;
    stage16((const short*)(Bb + gB[0] + ko), (short*)(ldsB + rg));
    stage16((const short*)(Bb + gB[1] + ko), (short*)(ldsB + rg + 8192));
  };

  int offA[8], offB[4];
#pragma unroll
  for (int mf = 0; mf < 8; ++mf)
    offA[mf] = swz((wr * 128 + mf * 16 + lrow) * 64 + cg * 16);
#pragma unroll
  for (int nf = 0; nf < 4; ++nf)
    offB[nf] = swz((wc * 64 + nf * 16 + lrow) * 64 + cg * 16);

  f32x4 acc[8][4] = {};

  stageApart(0); stageBpart(0);
  stageApart(1); stageBpart(1);
  stageApart(2); stageBpart(2);
  asm volatile("s_waitcnt vmcnt(8)" ::: "memory");
  __builtin_amdgcn_s_barrier();
  __builtin_amdgcn_sched_barrier(0);
  s16x8 af_cur[4], bf_cur[4], af_nxt[4], bf_nxt[4], af2[4];
#pragma unroll
  for (int m = 0; m < 4; ++m) af_cur[m] = *(const s16x8*)(ldsA + offA[m]);
#pragma unroll
  for (int n = 0; n < 4; ++n) bf_cur[n] = *(const s16x8*)(ldsB + offB[n]);

  for (int i = 0; i < NH - 1; ++i) {
    const int si  = i & 3;
    const int si1 = (i + 1) & 3;
    const char* pA  = ldsA + (si  << 14);
    const char* pA1 = ldsA + (si1 << 14);
    const char* pB1 = ldsB + (si1 << 14);

    if (i + 2 < NH) { asm volatile("s_waitcnt vmcnt(4)" ::: "memory"); }
    else            { asm volatile("s_waitcnt vmcnt(0)" ::: "memory"); }
    __builtin_amdgcn_s_barrier();
    __builtin_amdgcn_sched_barrier(0);

#pragma unroll
    for (int m = 0; m < 4; ++m) af_nxt[m] = *(const s16x8*)(pA + offA[m + 4]);
#pragma unroll
    for (int n = 0; n < 4; ++n) bf_nxt[n] = *(const s16x8*)(pB1 + offB[n]);
    if (i + 3 < NH) stageApart(i + 3);
    asm volatile("s_waitcnt lgkmcnt(8)" ::: "memory");
    __builtin_amdgcn_sched_barrier(0);
    __builtin_amdgcn_s_setprio(1);
#pragma unroll
    for (int m = 0; m < 4; ++m)
#pragma unroll
      for (int n = 0; n < 4; ++n)
        acc[m][n] = __builtin_amdgcn_mfma_f32_16x16x32_bf16(af_cur[m], bf_cur[n], acc[m][n], 0, 0, 0);
    __builtin_amdgcn_s_setprio(0);

#pragma unroll
    for (int m = 0; m < 4; ++m) af2[m] = *(const s16x8*)(pA1 + offA[m]);
    if (i + 3 < NH) stageBpart(i + 3);
    asm volatile("s_waitcnt lgkmcnt(4)" ::: "memory");
    __builtin_amdgcn_sched_barrier(0);
    __builtin_amdgcn_s_setprio(1);
#pragma unroll
    for (int m = 0; m < 4; ++m)
#pragma unroll
      for (int n = 0; n < 4; ++n)
        acc[m + 4][n] = __builtin_amdgcn_mfma_f32_16x16x32_bf16(af_nxt[m], bf_cur[n], acc[m + 4][n], 0, 0, 0);
    __builtin_amdgcn_s_setprio(0);

#pragma unroll
    for (int m = 0; m < 4; ++m) af_cur[m] = af2[m];
#pragma unroll
    for (int n = 0; n < 4; ++n) bf_cur[n] = bf_nxt[n];
  }

  {
    const char* pA = ldsA + (((NH - 1) & 3) << 14);
    asm volatile("s_waitcnt vmcnt(0)" ::: "memory");
    __builtin_amdgcn_s_barrier();
    __builtin_amdgcn_sched_barrier(0);
#pragma unroll
    for (int m = 0; m < 4; ++m) af_nxt[m] = *(const s16x8*)(pA + offA[m + 4]);
    asm volatile("s_waitcnt lgkmcnt(4)" ::: "memory");
    __builtin_amdgcn_sched_barrier(0);
    __builtin_amdgcn_s_setprio(1);
#pragma unroll
    for (int m = 0; m < 4; ++m)
#pragma unroll
      for (int n = 0; n < 4; ++n)
        acc[m][n] = __builtin_amdgcn_mfma_f32_16x16x32_bf16(af_cur[m], bf_cur[n], acc[m][n], 0, 0, 0);
    __builtin_amdgcn_s_setprio(0);
    asm volatile("s_waitcnt lgkmcnt(0)" ::: "memory");
    __builtin_amdgcn_sched_barrier(0);
    __builtin_amdgcn_s_setprio(1);
#pragma unroll
    for (int m = 0; m < 4; ++m)
#pragma unroll
      for (int n = 0; n < 4; ++n)
        acc[m + 4][n] = __builtin_amdgcn_mfma_f32_16x16x32_bf16(af_nxt[m], bf_cur[n], acc[m + 4][n], 0, 0, 0);
    __builtin_amdgcn_s_setprio(0);
  }

  const int ecol0 = n0 + wc * 64 + lrow;
  float bz[4];
#pragma unroll
  for (int nf = 0; nf < 4; ++nf) bz[nf] = bias[ecol0 + nf * 16];
  const int erow0 = m0 + wr * 128 + (cg << 2);

#pragma unroll
  for (int mf = 0; mf < 8; ++mf)
#pragma unroll
    for (int nf = 0; nf < 4; ++nf)
#pragma unroll
      for (int r2 = 0; r2 < 4; ++r2) {
        const int row = erow0 + mf * 16 + r2;
        const size_t idx = (size_t)row * N + (ecol0 + nf * 16);
        out16[idx] = f2bf(acc[mf][nf][r2] + bz[nf]);
      }
}

// ---------------------------------------------------------------------------
// 128x128 PIPELINED GEMM — fc1/fc2/out/ff1/ff2. 512 thr, 8 waves (2Mx4N),
// per-wave 64x32 (acc[4][2]). Ring-4 half-slots [128][32] bf16 (8KB)/matrix
// -> 64KB LDS -> 2 blocks/CU. Counted vmcnt(2)/half-step.
// ---------------------------------------------------------------------------
template<int EPI>
__global__ __launch_bounds__(512, 4)
void gemm128p(const short* __restrict__ A, const short* __restrict__ Bw,
              const float* __restrict__ bias, const short* __restrict__ res16,
              const float* __restrict__ bnG, const float* __restrict__ bnB,
              const float* __restrict__ bnM, const float* __restrict__ bnV,
              const int* __restrict__ hdr, short* __restrict__ out16,
              int N, int K) {
  extern __shared__ char smem[];                 // 65536 B
  const int tid  = threadIdx.x;
  const int lane = tid & 63;
  const int w    = tid >> 6;
  const int wr   = w >> 2;
  const int wc   = w & 3;
  const int lrow = lane & 15;
  const int cg   = lane >> 4;
  const int NH   = K >> 5;
  const int gx   = gridDim.x;

  const int p = blockIdx.y * gx + blockIdx.x;
  const int nwork = (hdr[1] >> 7) * gx;
  if (p >= nwork) return;
  const int xcd = p & 7, off = p >> 3;
  const int q = nwork >> 3, r = nwork & 7;
  const int wg = (xcd < r ? xcd * (q + 1) : r * (q + 1) + (xcd - r) * q) + off;
  const int m0 = (wg / gx) * 128;
  const int n0 = (wg % gx) * 128;

  const int ldb = K * 2;
  size_t gA, gB;
  {
    const int pp = tid * 16;
    const int l = swz(pp);
    const int row = l >> 6, colb = l & 63;
    gA = (size_t)(m0 + row) * ldb + colb;
    gB = (size_t)(n0 + row) * ldb + colb;
  }
  const char* Ab = (const char*)A;
  const char* Bb = (const char*)Bw;
  char* ldsA = smem;                             // 4 x 8KB
  char* ldsB = smem + 32768;                     // 4 x 8KB
  const int wofs = w * 1024;

  auto stageA = [&](int i) {
    stage16((const short*)(Ab + gA + i * 64), (short*)(ldsA + ((i & 3) << 13) + wofs));
  };
  auto stageB = [&](int i) {
    stage16((const short*)(Bb + gB + i * 64), (short*)(ldsB + ((i & 3) << 13) + wofs));
  };

  int offA[4], offB[2];
#pragma unroll
  for (int mf = 0; mf < 4; ++mf)
    offA[mf] = swz((wr * 64 + mf * 16 + lrow) * 64 + cg * 16);
#pragma unroll
  for (int nf = 0; nf < 2; ++nf)
    offB[nf] = swz((wc * 32 + nf * 16 + lrow) * 64 + cg * 16);

  f32x4 acc[4][2] = {};

  stageA(0); stageB(0);
  stageA(1); stageB(1);
  stageA(2); stageB(2);
  asm volatile("s_waitcnt vmcnt(4)" ::: "memory");
  __builtin_amdgcn_s_barrier();
  __builtin_amdgcn_sched_barrier(0);
  s16x8 af_cur[2], bf_cur[2], af_nxt[2], bf_nxt[2], af2[2];
#pragma unroll
  for (int m = 0; m < 2; ++m) af_cur[m] = *(const s16x8*)(ldsA + offA[m]);
#pragma unroll
  for (int n = 0; n < 2; ++n) bf_cur[n] = *(const s16x8*)(ldsB + offB[n]);

  for (int i = 0; i < NH - 1; ++i) {
    const char* pA  = ldsA + ((i & 3) << 13);
    const char* pA1 = ldsA + (((i + 1) & 3) << 13);
    const char* pB1 = ldsB + (((i + 1) & 3) << 13);

    if (i + 2 < NH) { asm volatile("s_waitcnt vmcnt(2)" ::: "memory"); }
    else            { asm volatile("s_waitcnt vmcnt(0)" ::: "memory"); }
    __builtin_amdgcn_s_barrier();
    __builtin_amdgcn_sched_barrier(0);

#pragma unroll
    for (int m = 0; m < 2; ++m) af_nxt[m] = *(const s16x8*)(pA + offA[m + 2]);
#pragma unroll
    for (int n = 0; n < 2; ++n) bf_nxt[n] = *(const s16x8*)(pB1 + offB[n]);
    if (i + 3 < NH) stageA(i + 3);
    asm volatile("s_waitcnt lgkmcnt(4)" ::: "memory");
    __builtin_amdgcn_sched_barrier(0);
    __builtin_amdgcn_s_setprio(1);
#pragma unroll
    for (int m = 0; m < 2; ++m)
#pragma unroll
      for (int n = 0; n < 2; ++n)
        acc[m][n] = __builtin_amdgcn_mfma_f32_16x16x32_bf16(af_cur[m], bf_cur[n], acc[m][n], 0, 0, 0);
    __builtin_amdgcn_s_setprio(0);

#pragma unroll
    for (int m = 0; m < 2; ++m) af2[m] = *(const s16x8*)(pA1 + offA[m]);
    if (i + 3 < NH) stageB(i + 3);
    asm volatile("s_waitcnt lgkmcnt(2)" ::: "memory");
    __builtin_amdgcn_sched_barrier(0);
    __builtin_amdgcn_s_setprio(1);
#pragma unroll
    for (int m = 0; m < 2; ++m)
#pragma unroll
      for (int n = 0; n < 2; ++n)
        acc[m + 2][n] = __builtin_amdgcn_mfma_f32_16x16x32_bf16(af_nxt[m], bf_cur[n], acc[m + 2][n], 0, 0, 0);
    __builtin_amdgcn_s_setprio(0);

#pragma unroll
    for (int m = 0; m < 2; ++m) af_cur[m] = af2[m];
#pragma unroll
    for (int n = 0; n < 2; ++n) bf_cur[n] = bf_nxt[n];
  }

  {
    const char* pA = ldsA + (((NH - 1) & 3) << 13);
    asm volatile("s_waitcnt vmcnt(0)" ::: "memory");
    __builtin_amdgcn_s_barrier();
    __builtin_amdgcn_sched_barrier(0);
#pragma unroll
    for (int m = 0; m < 2; ++m) af_nxt[m] = *(const s16x8*)(pA + offA[m + 2]);
    asm volatile("s_waitcnt lgkmcnt(2)" ::: "memory");
    __builtin_amdgcn_sched_barrier(0);
    __builtin_amdgcn_s_setprio(1);
#pragma unroll
    for (int m = 0; m < 2; ++m)
#pragma unroll
      for (int n = 0; n < 2; ++n)
        acc[m][n] = __builtin_amdgcn_mfma_f32_16x16x32_bf16(af_cur[m], bf_cur[n], acc[m][n], 0, 0, 0);
    __builtin_amdgcn_s_setprio(0);
    asm volatile("s_waitcnt lgkmcnt(0)" ::: "memory");
    __builtin_amdgcn_sched_barrier(0);
    __builtin_amdgcn_s_setprio(1);
#pragma unroll
    for (int m = 0; m < 2; ++m)
#pragma unroll
      for (int n = 0; n < 2; ++n)
        acc[m + 2][n] = __builtin_amdgcn_mfma_f32_16x16x32_bf16(af_nxt[m], bf_cur[n], acc[m + 2][n], 0, 0, 0);
    __builtin_amdgcn_s_setprio(0);
  }

  // epilogue
  const int ecol0 = n0 + wc * 32 + lrow;
  const int erow0 = m0 + wr * 64 + (cg << 2);
  float bz[2], sc[2], sh[2];
#pragma unroll
  for (int nf = 0; nf < 2; ++nf) {
    const int c = ecol0 + nf * 16;
    if constexpr (EPI == EPI_H1) {
      const float s = bnG[c] * rsqrtf(bnV[c] + BN_EPSF);
      sc[nf] = s;
      sh[nf] = (bias[c] - bnM[c]) * s + bnB[c];
    } else {
      bz[nf] = bias[c];
    }
  }
  (void)bnG; (void)bnB; (void)bnM; (void)bnV;

#pragma unroll
  for (int mf = 0; mf < 4; ++mf) {
#pragma unroll
    for (int nf = 0; nf < 2; ++nf) {
#pragma unroll
      for (int r2 = 0; r2 < 4; ++r2) {
        const int row = erow0 + mf * 16 + r2;
        const size_t idx = (size_t)row * N + (ecol0 + nf * 16);
        if constexpr (EPI == EPI_H1) {
          out16[idx] = f2bf(fmaxf(acc[mf][nf][r2] * sc[nf] + sh[nf], 0.f));
        } else {
          const float v = acc[mf][nf][r2] + bz[nf];
          if constexpr (EPI == EPI_PLAIN) {
            out16[idx] = f2bf(v);
          } else if constexpr (EPI == EPI_FF1) {
            out16[idx] = f2bf(fmaxf(v, 0.f));
          } else {  // EPI_RES: bf16 out = v + bf16 residual
            out16[idx] = f2bf(v + bf2f(res16[idx]));
          }
        }
      }
    }
  }
}

// ---------------------------------------------------------------------------
// Fused attention on compacted rows: one block per (b,h), len-aware.
// ---------------------------------------------------------------------------
__global__ __launch_bounds__(256)
void attn_kernel(const short* __restrict__ qkv, const int* __restrict__ lens,
                 const int* __restrict__ cum, short* __restrict__ ctx) {
  __shared__ short Qs[64 * 128];
  __shared__ short Ks[64 * 128];
  __shared__ short Vt[128 * 64];
  const int tid  = threadIdx.x;
  const int lane = tid & 63;
  const int wave = tid >> 6;
  const int b = blockIdx.x >> 3;
  const int h = blockIdx.x & 7;
  const int len = lens[b];
  const int rb  = cum[b];
  const size_t qb = (size_t)rb * 3072 + h * 128;

  {
    const int rr = wave * 4 + (lane >> 4);
    const int cc = (lane & 15) * 8;
#pragma unroll
    for (int r = 0; r < 4; ++r) {
      if (r * 16 + wave * 4 < len) {
        stage16(qkv + qb +        (size_t)(r * 16 + rr) * 3072 + cc, &Qs[(r * 16 + wave * 4) * 128]);
        stage16(qkv + qb + 1024 + (size_t)(r * 16 + rr) * 3072 + cc, &Ks[(r * 16 + wave * 4) * 128]);
      }
    }
  }
#pragma unroll
  for (int i = 0; i < 2; ++i) {
    const int c  = i * 256 + tid;
    const int lp = c >> 4;
    const int dg = c & 15;
    const short* src = qkv + qb + 2048 + (size_t)(2 * lp) * 3072 + dg * 8;
    const bool ok0 = (2 * lp)     < len;
    const bool ok1 = (2 * lp + 1) < len;
    s16x8 v0 = {}, v1 = {};
    if (ok0) v0 = *(const s16x8*)src;
    if (ok1) v1 = *(const s16x8*)(src + 3072);
#pragma unroll
    for (int j = 0; j < 8; ++j) {
      const uint32_t pk = ((uint32_t)(uint16_t)v0[j]) | (((uint32_t)(uint16_t)v1[j]) << 16);
      *(uint32_t*)&Vt[(dg * 8 + j) * 64 + 2 * lp] = pk;
    }
  }
  __syncthreads();

  const int lrow = lane & 15;
  const int lk8  = (lane >> 4) * 8;
  const bool active = (wave * 16) < len;

  if (active) {
    f32x4 sacc[4] = {};
#pragma unroll
    for (int ks = 0; ks < 4; ++ks) {
      s16x8 aq = *(const s16x8*)&Qs[(wave * 16 + lrow) * 128 + ks * 32 + lk8];
#pragma unroll
      for (int n = 0; n < 4; ++n) {
        s16x8 bk = *(const s16x8*)&Ks[(n * 16 + lrow) * 128 + ks * 32 + lk8];
        sacc[n] = __builtin_amdgcn_mfma_f32_16x16x32_bf16(aq, bk, sacc[n], 0, 0, 0);
      }
    }

    const float scale = 0.08838834764831845f;
#pragma unroll
    for (int r = 0; r < 4; ++r) {
      float sv[4];
      float mx = -1e30f;
#pragma unroll
      for (int n = 0; n < 4; ++n) {
        float v = sacc[n][r] * scale;
        if (n * 16 + lrow >= len) v = -1e30f;
        sv[n] = v;
        mx = fmaxf(mx, v);
      }
      mx = fmaxf(mx, __shfl_xor(mx, 1));
      mx = fmaxf(mx, __shfl_xor(mx, 2));
      mx = fmaxf(mx, __shfl_xor(mx, 4));
      mx = fmaxf(mx, __shfl_xor(mx, 8));
      float pv[4], sum = 0.f;
#pragma unroll
      for (int n = 0; n < 4; ++n) { pv[n] = __expf(sv[n] - mx); sum += pv[n]; }
      sum += __shfl_xor(sum, 1);
      sum += __shfl_xor(sum, 2);
      sum += __shfl_xor(sum, 4);
      sum += __shfl_xor(sum, 8);
      const float inv = 1.f / sum;
      const int prow = wave * 16 + ((lane >> 4) << 2) + r;
#pragma unroll
      for (int n = 0; n < 4; ++n)
        Qs[prow * 128 + n * 16 + lrow] = f2bf(pv[n] * inv);
    }
  }
  __syncthreads();

  if (active) {
    f32x4 oacc[8] = {};
#pragma unroll
    for (int ks = 0; ks < 2; ++ks) {
      s16x8 ap = *(const s16x8*)&Qs[(wave * 16 + lrow) * 128 + ks * 32 + lk8];
#pragma unroll
      for (int n = 0; n < 8; ++n) {
        s16x8 bv = *(const s16x8*)&Vt[(n * 16 + lrow) * 64 + ks * 32 + lk8];
        oacc[n] = __builtin_amdgcn_mfma_f32_16x16x32_bf16(ap, bv, oacc[n], 0, 0, 0);
      }
    }
    const size_t ob = (size_t)rb * 1024 + h * 128;
#pragma unroll
    for (int n = 0; n < 8; ++n)
#pragma unroll
      for (int r = 0; r < 4; ++r) {
        const int row = wave * 16 + ((lane >> 4) << 2) + r;
        if (row < len)
          ctx[ob + (size_t)row * 1024 + n * 16 + lrow] = f2bf(oacc[n][r]);
      }
  }
}

// ---------------------------------------------------------------------------
// LayerNorm over 1024 (LN1): bf16 in/out; grid-stride over compacted rows
// ---------------------------------------------------------------------------
__global__ __launch_bounds__(256)
void ln_kernel(const short* __restrict__ x16, const float* __restrict__ gg,
               const float* __restrict__ bb, const int* __restrict__ hdr,
               short* __restrict__ y16) {
  __shared__ float red[8];
  const int tid = threadIdx.x;
  const int lane = tid & 63;
  const int wave = tid >> 6;
  float4 g4 = ((const float4*)gg)[tid];
  float4 b4 = ((const float4*)bb)[tid];
  const int mcpad = hdr[1];
  for (int row = blockIdx.x; row < mcpad; row += gridDim.x) {
    const size_t base = (size_t)row * 1024;
    s16x4 hv = ((const s16x4*)(x16 + base))[tid];
    const float v0 = bf2f(hv[0]), v1 = bf2f(hv[1]), v2 = bf2f(hv[2]), v3 = bf2f(hv[3]);
    float s1 = v0 + v1 + v2 + v3;
    float s2 = v0 * v0 + v1 * v1 + v2 * v2 + v3 * v3;
#pragma unroll
    for (int o = 1; o < 64; o <<= 1) { s1 += __shfl_xor(s1, o); s2 += __shfl_xor(s2, o); }
    if (lane == 0) { red[wave] = s1; red[wave + 4] = s2; }
    __syncthreads();
    s1 = red[0] + red[1] + red[2] + red[3];
    s2 = red[4] + red[5] + red[6] + red[7];
    const float mu  = s1 * (1.f / 1024.f);
    const float var = fmaxf(s2 * (1.f / 1024.f) - mu * mu, 0.f);
    const float rs  = rsqrtf(var + LN_EPSF);
    s16x4 hh;
    hh[0] = f2bf((v0 - mu) * rs * g4.x + b4.x);
    hh[1] = f2bf((v1 - mu) * rs * g4.y + b4.y);
    hh[2] = f2bf((v2 - mu) * rs * g4.z + b4.z);
    hh[3] = f2bf((v3 - mu) * rs * g4.w + b4.w);
    ((s16x4*)(y16 + base))[tid] = hh;
    __syncthreads();
  }
}

// ---------------------------------------------------------------------------
// fused: top-2 mean over emb16 + LN2 + avg-pool + 0.5/0.5 mix + L2 normalize.
// One block per batch. Thread owns cols 4*tid..4*tid+3 for both the top-2
// (in-register) and the final mix (pooled part[] layout matches exactly).
// ---------------------------------------------------------------------------
__global__ __launch_bounds__(256)
void final_kernel(const short* __restrict__ x16, const short* __restrict__ emb16,
                  const float* __restrict__ gg, const float* __restrict__ bb,
                  const int* __restrict__ lens, const int* __restrict__ cum,
                  float* __restrict__ out) {
  __shared__ float part[4][1024];
  __shared__ float red[4];
  const int tid = threadIdx.x, lane = tid & 63, w = tid >> 6;
  const int b = blockIdx.x, len = lens[b];
  const size_t rb = (size_t)cum[b];

  // --- top-2 mean over emb16 (cols 4*tid..4*tid+3) ---
  const int d0 = tid * 4;
  float m1[4], m2[4];
#pragma unroll
  for (int k = 0; k < 4; ++k) { m1[k] = -3.0e38f; m2[k] = -3.0e38f; }
  for (int l = 0; l < len; ++l) {
    s16x4 hv = *(const s16x4*)&emb16[(rb + l) * 1024 + d0];
#pragma unroll
    for (int k = 0; k < 4; ++k) {
      const float v = bf2f(hv[k]);
      if (v > m1[k]) { m2[k] = m1[k]; m1[k] = v; }
      else           { m2[k] = fmaxf(m2[k], v); }
    }
  }

  // --- LN2 + avg-pool over x16 ---
  float4 g4[4], b4[4];
#pragma unroll
  for (int k = 0; k < 4; ++k) {
    g4[k] = ((const float4*)gg)[k * 64 + lane];
    b4[k] = ((const float4*)bb)[k * 64 + lane];
  }
  float4 acc[4];
#pragma unroll
  for (int k = 0; k < 4; ++k) acc[k] = make_float4(0.f, 0.f, 0.f, 0.f);

  for (int l = w; l < len; l += 4) {
    const s16x4* row = (const s16x4*)(x16 + (rb + l) * 1024);
    float4 v[4]; float s1 = 0.f, s2 = 0.f;
#pragma unroll
    for (int k = 0; k < 4; ++k) {
      s16x4 hv = row[k * 64 + lane];
      v[k] = make_float4(bf2f(hv[0]), bf2f(hv[1]), bf2f(hv[2]), bf2f(hv[3]));
      s1 += v[k].x + v[k].y + v[k].z + v[k].w;
      s2 += v[k].x * v[k].x + v[k].y * v[k].y + v[k].z * v[k].z + v[k].w * v[k].w;
    }
#pragma unroll
    for (int o = 1; o < 64; o <<= 1) { s1 += __shfl_xor(s1, o); s2 += __shfl_xor(s2, o); }
    const float mu = s1 * (1.f / 1024.f);
    const float rs = rsqrtf(fmaxf(s2 * (1.f / 1024.f) - mu * mu, 0.f) + LN_EPSF);
#pragma unroll
    for (int k = 0; k < 4; ++k) {
      acc[k].x += (v[k].x - mu) * rs * g4[k].x + b4[k].x;
      acc[k].y += (v[k].y - mu) * rs * g4[k].y + b4[k].y;
      acc[k].z += (v[k].z - mu) * rs * g4[k].z + b4[k].z;
      acc[k].w += (v[k].w - mu) * rs * g4[k].w + b4[k].w;
    }
  }
#pragma unroll
  for (int k = 0; k < 4; ++k)
    ((float4*)&part[w][0])[k * 64 + lane] = acc[k];
  __syncthreads();

  // part read at float4-index tid -> cols 4*tid..4*tid+3 (matches top-2 cols)
  float4 s = ((const float4*)&part[0][0])[tid];
#pragma unroll
  for (int w2 = 1; w2 < 4; ++w2) {
    float4 t4 = ((const float4*)&part[0][0])[w2 * 256 + tid];
    s.x += t4.x; s.y += t4.y; s.z += t4.z; s.w += t4.w;
  }
  const float il = 0.5f / (float)len;
  const float o0 = 0.25f * (m1[0] + m2[0]) + s.x * il;
  const float o1 = 0.25f * (m1[1] + m2[1]) + s.y * il;
  const float o2 = 0.25f * (m1[2] + m2[2]) + s.z * il;
  const float o3 = 0.25f * (m1[3] + m2[3]) + s.w * il;
  float ss = o0 * o0 + o1 * o1 + o2 * o2 + o3 * o3;
#pragma unroll
  for (int o = 1; o < 64; o <<= 1) ss += __shfl_xor(ss, o);
  if (lane == 0) red[w] = ss;
  __syncthreads();
  ss = red[0] + red[1] + red[2] + red[3];
  const float nrm = 1.f / (sqrtf(ss) + 1e-8f);
  ((float4*)(out + (size_t)b * 1024))[tid] = make_float4(o0 * nrm, o1 * nrm, o2 * nrm, o3 * nrm);
}

// ---------------------------------------------------------------------------
extern "C" void kernel_launch(void* const* d_in, const int* in_sizes, int n_in,
                              void* d_out, int out_size, void* d_ws, size_t ws_size,
                              hipStream_t stream) {
  (void)in_sizes; (void)n_in; (void)out_size; (void)ws_size;
  const float* images = (const float*)d_in[0];
  const int*   lens   = (const int*)d_in[1];
  const float* fc1_w = (const float*)d_in[2];
  const float* fc1_b = (const float*)d_in[3];
  const float* bn_g  = (const float*)d_in[4];
  const float* bn_b  = (const float*)d_in[5];
  const float* bn_m  = (const float*)d_in[6];
  const float* bn_v  = (const float*)d_in[7];
  const float* fc2_w = (const float*)d_in[8];
  const float* fc2_b = (const float*)d_in[9];
  const float* in_w  = (const float*)d_in[10];
  const float* in_b  = (const float*)d_in[11];
  const float* out_w = (const float*)d_in[12];
  const float* out_b = (const float*)d_in[13];
  const float* ln1_g = (const float*)d_in[14];
  const float* ln1_b = (const float*)d_in[15];
  const float* ff1_w = (const float*)d_in[16];
  const float* ff1_b = (const float*)d_in[17];
  const float* ff2_w = (const float*)d_in[18];
  const float* ff2_b = (const float*)d_in[19];
  const float* ln2_g = (const float*)d_in[20];
  const float* ln2_b = (const float*)d_in[21];
  float* out = (float*)d_out;

  char* ws = (char*)d_ws;
  const size_t OFF_IMG16 = 0;                          // 67108864 (img16 / x1sum / x2sum)
  const size_t OFF_FC1W  = 67108864;                   // 2097152
  const size_t OFF_FC2W  = OFF_FC1W + 2097152;         // 1048576
  const size_t OFF_INW   = OFF_FC2W + 1048576;         // 6291456
  const size_t OFF_OUTW  = OFF_INW  + 6291456;         // 2097152
  const size_t OFF_FF1W  = OFF_OUTW + 2097152;         // 2097152
  const size_t OFF_FF2W  = OFF_FF1W + 2097152;         // 2097152
  const size_t OFF_H1    = OFF_FF2W + 2097152;         // 16777216
  const size_t OFF_EMB16 = OFF_H1 + 16777216;          // 33554432 (alive to end)
  const size_t OFF_QKV   = OFF_EMB16 + 33554432;       // 101056512 (16448 rows)
  const size_t OFF_CTX   = OFF_QKV + 101056512;        // 33554432
  const size_t OFF_HDR   = OFF_CTX + 33554432;         // 256
  const size_t OFF_CUM   = OFF_HDR + 256;              // 1024
  const size_t OFF_TOK   = OFF_CUM + 1024;             // 65536

  short* img16  = (short*)(ws + OFF_IMG16);
  short* fc1w16 = (short*)(ws + OFF_FC1W);
  short* fc2w16 = (short*)(ws + OFF_FC2W);
  short* inw16  = (short*)(ws + OFF_INW);
  short* outw16 = (short*)(ws + OFF_OUTW);
  short* ff1w16 = (short*)(ws + OFF_FF1W);
  short* ff2w16 = (short*)(ws + OFF_FF2W);
  short* h1     = (short*)(ws + OFF_H1);
  short* emb16  = (short*)(ws + OFF_EMB16);
  short* qkv16  = (short*)(ws + OFF_QKV);
  short* ctx16  = (short*)(ws + OFF_CTX);
  int*   hdr    = (int*)(ws + OFF_HDR);
  int*   cum    = (int*)(ws + OFF_CUM);
  int*   tokmap = (int*)(ws + OFF_TOK);
  short* x1sum = (short*)(ws + OFF_IMG16);  // pre-LN1 bf16 (img16 dead)
  short* x1h   = (short*)(ws + OFF_QKV);    // post-LN1 bf16 (qkv16 dead after attn)
  short* ffh   = ctx16;                     // ffn hidden    (ctx16 dead)
  short* x2sum = (short*)(ws + OFF_IMG16);  // pre-LN2 bf16  (x1sum dead)

  const dim3 blk(256);
  const size_t SMEM256 = 131072;
  const size_t SMEM128 = 65536;

  // compaction metadata (prefix + tokmap fused)
  prefix_kernel<<<1, blk, 0, stream>>>(lens, cum, hdr, tokmap);

  // converts: gathered images + all six weights in one kernel
  CvtArgs ca;
  ca.src[0] = fc1_w; ca.dst[0] = fc1w16; ca.n4[0] = 1048576 / 4;
  ca.src[1] = fc2_w; ca.dst[1] = fc2w16; ca.n4[1] = 524288 / 4;
  ca.src[2] = in_w;  ca.dst[2] = inw16;  ca.n4[2] = 3145728 / 4;
  ca.src[3] = out_w; ca.dst[3] = outw16; ca.n4[3] = 1048576 / 4;
  ca.src[4] = ff1_w; ca.dst[4] = ff1w16; ca.n4[4] = 1048576 / 4;
  ca.src[5] = ff2_w; ca.dst[5] = ff2w16; ca.n4[5] = 1048576 / 4;
  cvt_gather_kernel<<<2048, blk, 0, stream>>>(images, tokmap, hdr, img16, ca);

  // fc1 + BN + ReLU -> h1 (bf16, compacted)
  gemm128p<EPI_H1><<<dim3(4, 128), 512, SMEM128, stream>>>(
      img16, fc1w16, fc1_b, nullptr, bn_g, bn_b, bn_m, bn_v, hdr, h1, 512, 2048);
  // fc2 -> emb16 (compacted; alive until final_kernel)
  gemm128p<EPI_PLAIN><<<dim3(8, 128), 512, SMEM128, stream>>>(
      h1, fc2w16, fc2_b, nullptr, nullptr, nullptr, nullptr, nullptr, hdr, emb16, 1024, 512);
  // qkv projection (256x256 pipelined)
  gemm256<<<dim3(12, 64), 512, SMEM256, stream>>>(
      emb16, inw16, in_b, hdr, qkv16, 3072, 1024);
  // attention (compacted rows, len-aware)
  attn_kernel<<<2048, blk, 0, stream>>>(qkv16, lens, cum, ctx16);
  // out projection + residual(emb16) -> pre-LN1 bf16
  gemm128p<EPI_RES><<<dim3(8, 128), 512, SMEM128, stream>>>(
      ctx16, outw16, out_b, emb16, nullptr, nullptr, nullptr, nullptr, hdr, x1sum, 1024, 1024);
  ln_kernel<<<2048, blk, 0, stream>>>(x1sum, ln1_g, ln1_b, hdr, x1h);
  // ffn
  gemm128p<EPI_FF1><<<dim3(8, 128), 512, SMEM128, stream>>>(
      x1h, ff1w16, ff1_b, nullptr, nullptr, nullptr, nullptr, nullptr, hdr, ffh, 1024, 1024);
  gemm128p<EPI_RES><<<dim3(8, 128), 512, SMEM128, stream>>>(
      ffh, ff2w16, ff2_b, x1h, nullptr, nullptr, nullptr, nullptr, hdr, x2sum, 1024, 1024);
  // fused top-2 + LN2 + avg-pool + mix + normalize
  final_kernel<<<256, blk, 0, stream>>>(x2sum, emb16, ln2_g, ln2_b, lens, cum, out);
}